// Round 1
// baseline (10155.612 us; speedup 1.0000x reference)
//
#include <hip/hip_runtime.h>
#include <cstdint>

// ---------------- constants ----------------
#define BSZ 32
#define SEQ 512
#define DM  512
#define NH  8
#define DK  64
#define HS_ 2
#define HD_ 6
#define NL  6
#define MROWS (BSZ*SEQ)          // 16384

typedef unsigned short bf16_t;
typedef __attribute__((ext_vector_type(4))) float f32x4;
typedef __attribute__((ext_vector_type(8))) short bf16x8;

#define DEV static __device__ __forceinline__

DEV float bf2f(bf16_t b) {
  unsigned int u = ((unsigned int)b) << 16;
  float f; __builtin_memcpy(&f, &u, 4); return f;
}
DEV bf16_t f2b(float f) {  // RNE bf16 (finite inputs)
  unsigned int u; __builtin_memcpy(&u, &f, 4);
  unsigned int r = (u + 0x7fffu + ((u >> 16) & 1u)) >> 16;
  return (bf16_t)r;
}
DEV void unp2(unsigned int w, float& a, float& b) {
  unsigned int ua = w << 16, ub = w & 0xffff0000u;
  __builtin_memcpy(&a, &ua, 4); __builtin_memcpy(&b, &ub, 4);
}

DEV void gload_lds16(const bf16_t* g, bf16_t* l) {
  __builtin_amdgcn_global_load_lds(
      (const __attribute__((address_space(1))) void*)g,
      (__attribute__((address_space(3))) void*)l, 16, 0, 0);
}

// ---------------- f32 -> bf16 convert ----------------
__global__ __launch_bounds__(256) void f2b_kernel(const float* __restrict__ in,
                                                  bf16_t* __restrict__ out, int n4) {
  int i = blockIdx.x * 256 + threadIdx.x;
  int stride = gridDim.x * 256;
  for (; i < n4; i += stride) {
    float4 v = reinterpret_cast<const float4*>(in)[i];
    ushort4 o;
    o.x = f2b(v.x); o.y = f2b(v.y); o.z = f2b(v.z); o.w = f2b(v.w);
    reinterpret_cast<ushort4*>(out)[i] = o;
  }
}

// ---------------- MFMA GEMM: Y = A @ W^T + bias ----------------
// A [M,K] bf16 row-major, W [N,K] bf16 row-major. 128x128 tile, BK=32, 4 waves.
template <bool RELU, bool OUTF, bool OUTB>
__global__ __launch_bounds__(256) void gemm_bt(
    const bf16_t* __restrict__ A, const bf16_t* __restrict__ W,
    const float* __restrict__ bias, float* __restrict__ Yf,
    bf16_t* __restrict__ Yb, int M, int N, int K) {
  const int bn = blockIdx.x, bm = blockIdx.y;
  const int tid = threadIdx.x, wid = tid >> 6, lane = tid & 63;
  const int wr = wid >> 1, wc = wid & 1;   // 2x2 wave grid, 64x64 each
  __shared__ __align__(16) bf16_t As[128 * 32];
  __shared__ __align__(16) bf16_t Bs[128 * 32];

  f32x4 acc[4][4];
#pragma unroll
  for (int m = 0; m < 4; ++m)
#pragma unroll
    for (int n = 0; n < 4; ++n) acc[m][n] = f32x4{0.f, 0.f, 0.f, 0.f};

  const int lrow = lane & 15, lko = (lane >> 4) * 8;
  const size_t arow0 = (size_t)bm * 128, brow0 = (size_t)bn * 128;

  for (int k0 = 0; k0 < K; k0 += 32) {
#pragma unroll
    for (int i = 0; i < 2; ++i) {
      int e = (i * 256 + tid) * 8;           // element in [128][32]
      int r = e >> 5, c = e & 31;
      gload_lds16(A + (arow0 + r) * K + k0 + c, &As[(i * 4 + wid) * 512]);
      gload_lds16(W + (brow0 + r) * K + k0 + c, &Bs[(i * 4 + wid) * 512]);
    }
    __syncthreads();
    bf16x8 af[4], bw[4];
#pragma unroll
    for (int m = 0; m < 4; ++m)
      af[m] = *reinterpret_cast<const bf16x8*>(&As[(wr * 64 + m * 16 + lrow) * 32 + lko]);
#pragma unroll
    for (int n = 0; n < 4; ++n)
      bw[n] = *reinterpret_cast<const bf16x8*>(&Bs[(wc * 64 + n * 16 + lrow) * 32 + lko]);
#pragma unroll
    for (int m = 0; m < 4; ++m)
#pragma unroll
      for (int n = 0; n < 4; ++n)
        acc[m][n] = __builtin_amdgcn_mfma_f32_16x16x32_bf16(af[m], bw[n], acc[m][n], 0, 0, 0);
    __syncthreads();
  }

  const int r0 = bm * 128 + wr * 64 + (lane >> 4) * 4;
  const int c0 = bn * 128 + wc * 64 + lrow;
#pragma unroll
  for (int n = 0; n < 4; ++n) {
    const int col = c0 + n * 16;
    const float bc = bias[col];
#pragma unroll
    for (int m = 0; m < 4; ++m) {
#pragma unroll
      for (int j = 0; j < 4; ++j) {
        float v = acc[m][n][j] + bc;
        if (RELU) v = fmaxf(v, 0.f);
        const size_t off = (size_t)(r0 + m * 16 + j) * N + col;
        if (OUTF) Yf[off] = v;
        if (OUTB) Yb[off] = f2b(v);
      }
    }
  }
}

// ---------------- gating: softmax(q @ Wg^T), top-4-of-6 ----------------
// one wave per token; fP = {f[6], Psum[6]} for this layer
__global__ __launch_bounds__(256) void gates_kernel(
    const bf16_t* __restrict__ qb, const float* __restrict__ Wg,
    float* __restrict__ dyn, float* __restrict__ fP) {
  __shared__ float wg_s[HD_ * DM];
  __shared__ float blk[4][12];
  const int tid = threadIdx.x, wid = tid >> 6, lane = tid & 63;
  for (int i = tid; i < HD_ * DM; i += 256) wg_s[i] = Wg[i];
  __syncthreads();
  const int tok = blockIdx.x * 4 + wid;
  const uint4* qr = reinterpret_cast<const uint4*>(qb + (size_t)tok * DM);
  float x[8];
  {
    uint4 u = qr[lane];
    unp2(u.x, x[0], x[1]); unp2(u.y, x[2], x[3]);
    unp2(u.z, x[4], x[5]); unp2(u.w, x[6], x[7]);
  }
  float g[6];
#pragma unroll
  for (int j = 0; j < 6; ++j) {
    float p = 0.f;
#pragma unroll
    for (int e = 0; e < 8; ++e) p = fmaf(x[e], wg_s[j * DM + lane * 8 + e], p);
#pragma unroll
    for (int off = 32; off; off >>= 1) p += __shfl_xor(p, off);
    g[j] = p;
  }
  float mx = g[0];
#pragma unroll
  for (int j = 1; j < 6; ++j) mx = fmaxf(mx, g[j]);
  float se = 0.f;
#pragma unroll
  for (int j = 0; j < 6; ++j) { g[j] = __expf(g[j] - mx); se += g[j]; }
  float inv = 1.f / se;
#pragma unroll
  for (int j = 0; j < 6; ++j) g[j] *= inv;
  // drop the two smallest (ties -> drop larger index; matches stable top_k)
  int d1 = 0;
#pragma unroll
  for (int j = 1; j < 6; ++j)
    if (g[j] < g[d1] || (g[j] == g[d1] && j > d1)) d1 = j;
  int d2 = (d1 == 0) ? 1 : 0;
#pragma unroll
  for (int j = 0; j < 6; ++j) {
    if (j == d1) continue;
    if (g[j] < g[d2] || (g[j] == g[d2] && j > d2)) d2 = j;
  }
  if (lane == 0) {
#pragma unroll
    for (int j = 0; j < 6; ++j) {
      bool drop = (j == d1) || (j == d2);
      dyn[(size_t)tok * 6 + j] = drop ? 0.f : g[j];
      blk[wid][j] = drop ? 0.f : 1.f;
      blk[wid][6 + j] = g[j];
    }
  }
  __syncthreads();
  if (tid < 12) {
    float s = blk[0][tid] + blk[1][tid] + blk[2][tid] + blk[3][tid];
    atomicAdd(&fP[tid], s);
  }
}

// ---------------- routing: mean over s of dyn ----------------
__global__ __launch_bounds__(256) void routing_kernel(const float* __restrict__ dyn,
                                                      float* __restrict__ rdyn) {
  const int j = blockIdx.x, b = blockIdx.y;
  const int tid = threadIdx.x, wid = tid >> 6, lane = tid & 63;
  float s = 0.f;
  for (int si = tid; si < SEQ; si += 256) s += dyn[((size_t)b * SEQ + si) * 6 + j];
#pragma unroll
  for (int off = 32; off; off >>= 1) s += __shfl_xor(s, off);
  __shared__ float red[4];
  if (lane == 0) red[wid] = s;
  __syncthreads();
  if (tid == 0) rdyn[b * 6 + j] = (red[0] + red[1] + red[2] + red[3]) * (1.f / 512.f);
}

// ---------------- attention: one block per (b,h,q-row) ----------------
__global__ __launch_bounds__(256) void attn_kernel(
    const bf16_t* __restrict__ qb, const bf16_t* __restrict__ vb,
    const float* __restrict__ rdyn, bf16_t* __restrict__ ctx, int strict) {
  const int qi = blockIdx.x, h = blockIdx.y, b = blockIdx.z;
  const int tid = threadIdx.x, wid = tid >> 6, lane = tid & 63;
  __shared__ float qs[DK];
  __shared__ float ps[SEQ];
  __shared__ float red[4];
  __shared__ float cpart[4][DK];
  const bf16_t* qh = qb + (size_t)b * SEQ * DM + h * DK;   // row stride DM
  if (tid < DK) qs[tid] = bf2f(qh[(size_t)qi * DM + tid]);
  __syncthreads();

  float sc[2];
#pragma unroll
  for (int t = 0; t < 2; ++t) {
    const int k = tid + t * 256;
    const uint4* kr = reinterpret_cast<const uint4*>(qh + (size_t)k * DM);
    float acc = 0.f;
#pragma unroll
    for (int j = 0; j < 8; ++j) {
      uint4 u = kr[j];
      float a, bb;
      unp2(u.x, a, bb); acc = fmaf(a, qs[j * 8 + 0], acc); acc = fmaf(bb, qs[j * 8 + 1], acc);
      unp2(u.y, a, bb); acc = fmaf(a, qs[j * 8 + 2], acc); acc = fmaf(bb, qs[j * 8 + 3], acc);
      unp2(u.z, a, bb); acc = fmaf(a, qs[j * 8 + 4], acc); acc = fmaf(bb, qs[j * 8 + 5], acc);
      unp2(u.w, a, bb); acc = fmaf(a, qs[j * 8 + 6], acc); acc = fmaf(bb, qs[j * 8 + 7], acc);
    }
    float s = acc * 0.125f;                 // 1/sqrt(64)
    if (qi == 0) s = 0.f;                   // pad-zero row -> uniform over ALL keys
    else if (k > qi - strict) s = -1e30f;   // causal mask
    sc[t] = s;
  }
  // block max
  float m = fmaxf(sc[0], sc[1]);
#pragma unroll
  for (int off = 32; off; off >>= 1) m = fmaxf(m, __shfl_xor(m, off));
  if (lane == 0) red[wid] = m;
  __syncthreads();
  m = fmaxf(fmaxf(red[0], red[1]), fmaxf(red[2], red[3]));
  __syncthreads();   // protect red reuse
  // exp + block sum
  float psum = 0.f;
#pragma unroll
  for (int t = 0; t < 2; ++t) {
    const int k = tid + t * 256;
    float p = (sc[t] < -1e29f) ? 0.f : __expf(sc[t] - m);
    ps[k] = p; psum += p;
  }
#pragma unroll
  for (int off = 32; off; off >>= 1) psum += __shfl_xor(psum, off);
  if (lane == 0) red[wid] = psum;
  __syncthreads();
  const float tot = red[0] + red[1] + red[2] + red[3];
  // PV: thread (c,d): sum over k-chunk c of ps[k]*v[k][d]
  const int d = tid & 63, c = tid >> 6;
  const bf16_t* vh = vb + (size_t)b * SEQ * DM + h * DK + d;
  float acc = 0.f;
  const int k0 = c * 128;
  for (int k = k0; k < k0 + 128; ++k)
    acc = fmaf(bf2f(vh[(size_t)k * DM]), ps[k], acc);
  cpart[c][d] = acc;
  __syncthreads();
  if (tid < DK) {
    const float factor = (h < HS_) ? 1.f : rdyn[b * 6 + (h - HS_)];
    const float o = (cpart[0][tid] + cpart[1][tid] + cpart[2][tid] + cpart[3][tid]) * factor / tot;
    ctx[((size_t)b * SEQ + qi) * DM + h * DK + tid] = f2b(o);
  }
}

// ---------------- add + layernorm ----------------
__global__ __launch_bounds__(256) void add_ln_kernel(
    const float* __restrict__ X, const float* __restrict__ A2,
    const float* __restrict__ gam, const float* __restrict__ bet,
    float* __restrict__ outf, bf16_t* __restrict__ outb) {
  const int row = blockIdx.x, tid = threadIdx.x, wid = tid >> 6, lane = tid & 63;
  const size_t base = (size_t)row * DM;
  float z0 = X[base + tid] + A2[base + tid];
  float z1 = X[base + tid + 256] + A2[base + tid + 256];
  __shared__ float red[4];
  float s = z0 + z1;
#pragma unroll
  for (int off = 32; off; off >>= 1) s += __shfl_xor(s, off);
  if (lane == 0) red[wid] = s;
  __syncthreads();
  const float mean = (red[0] + red[1] + red[2] + red[3]) * (1.f / 512.f);
  __syncthreads();
  const float d0 = z0 - mean, d1 = z1 - mean;
  float ss = d0 * d0 + d1 * d1;
#pragma unroll
  for (int off = 32; off; off >>= 1) ss += __shfl_xor(ss, off);
  if (lane == 0) red[wid] = ss;
  __syncthreads();
  const float var = (red[0] + red[1] + red[2] + red[3]) * (1.f / 512.f);
  const float inv = rsqrtf(var + 1e-5f);
  const float o0 = d0 * inv * gam[tid] + bet[tid];
  const float o1 = d1 * inv * gam[tid + 256] + bet[tid + 256];
  outf[base + tid] = o0;
  outf[base + tid + 256] = o1;
  outb[base + tid] = f2b(o0);
  outb[base + tid + 256] = f2b(o1);
}

// ---------------- balance ----------------
__global__ void balance_kernel(const float* __restrict__ fP, float* __restrict__ out) {
  if (threadIdx.x == 0 && blockIdx.x == 0) {
    float fs = 0.f, pssum = 0.f, P[6];
    for (int j = 0; j < 6; ++j) {
      fs += fP[j];
      P[j] = fP[6 + j] * (1.f / (float)MROWS);
      pssum += P[j];
    }
    float bal = 0.f;
    for (int j = 0; j < 6; ++j)
      bal += (fP[j] / (fs + 1e-5f)) * (P[j] / (pssum + 1e-5f));
    out[0] = bal;
  }
}

// ---------------- host ----------------
extern "C" void kernel_launch(void* const* d_in, const int* in_sizes, int n_in,
                              void* d_out, int out_size, void* d_ws, size_t ws_size,
                              hipStream_t stream) {
  (void)in_sizes; (void)n_in; (void)out_size; (void)ws_size;
  const float* q_embed  = (const float*)d_in[0];
  const float* qa_embed = (const float*)d_in[1];
  const float* Wq  = (const float*)d_in[2];
  const float* bq  = (const float*)d_in[3];
  const float* Wv  = (const float*)d_in[4];
  const float* bv  = (const float*)d_in[5];
  const float* Wg  = (const float*)d_in[6];
  const float* Wo  = (const float*)d_in[7];
  const float* bo  = (const float*)d_in[8];
  const float* ln1g = (const float*)d_in[9];
  const float* ln1b = (const float*)d_in[10];
  const float* W1  = (const float*)d_in[11];
  const float* b1  = (const float*)d_in[12];
  const float* W2  = (const float*)d_in[13];
  const float* b2  = (const float*)d_in[14];
  const float* ln2g = (const float*)d_in[15];
  const float* ln2b = (const float*)d_in[16];

  char* p = (char*)d_ws;
  auto alloc = [&](size_t bytes) -> char* {
    char* r = p; p += (bytes + 255) & ~(size_t)255; return r;
  };
  const size_t WDE = (size_t)NL * DM * DM;   // stacked weight elems
  const size_t AE  = (size_t)MROWS * DM;     // activation elems
  bf16_t* wq_b = (bf16_t*)alloc(WDE * 2);
  bf16_t* wv_b = (bf16_t*)alloc(WDE * 2);
  bf16_t* wo_b = (bf16_t*)alloc(WDE * 2);
  bf16_t* w1_b = (bf16_t*)alloc(WDE * 2);
  bf16_t* w2_b = (bf16_t*)alloc(WDE * 2);
  float* y_f   = (float*)alloc(AE * 4);
  float* x_f   = (float*)alloc(AE * 4);
  float* tmp_f = (float*)alloc(AE * 4);
  float* x1_f  = (float*)alloc(AE * 4);
  bf16_t* y_b   = (bf16_t*)alloc(AE * 2);
  bf16_t* x_b   = (bf16_t*)alloc(AE * 2);
  bf16_t* q_b   = (bf16_t*)alloc(AE * 2);
  bf16_t* v_b   = (bf16_t*)alloc(AE * 2);
  bf16_t* ctx_b = (bf16_t*)alloc(AE * 2);
  bf16_t* x1_b  = (bf16_t*)alloc(AE * 2);
  float* dyn  = (float*)alloc((size_t)MROWS * 6 * 4);
  float* rdyn = (float*)alloc(BSZ * 6 * 4);
  float* fP   = (float*)alloc(NL * 12 * 4);
  bf16_t* ffn1_b = q_b;   // alias: q dead after attention/gates

  hipMemsetAsync(fP, 0, NL * 12 * 4, stream);

  // weights -> bf16
  f2b_kernel<<<1536, 256, 0, stream>>>(Wq, wq_b, (int)(WDE / 4));
  f2b_kernel<<<1536, 256, 0, stream>>>(Wv, wv_b, (int)(WDE / 4));
  f2b_kernel<<<1536, 256, 0, stream>>>(Wo, wo_b, (int)(WDE / 4));
  f2b_kernel<<<1536, 256, 0, stream>>>(W1, w1_b, (int)(WDE / 4));
  f2b_kernel<<<1536, 256, 0, stream>>>(W2, w2_b, (int)(WDE / 4));
  // initial activations -> bf16
  f2b_kernel<<<2048, 256, 0, stream>>>(qa_embed, y_b, (int)(AE / 4));
  f2b_kernel<<<2048, 256, 0, stream>>>(q_embed, x_b, (int)(AE / 4));

  const size_t DD = (size_t)DM * DM;
  dim3 gg(4, 128);   // N/128, M/128

  auto layer = [&](int i, const float* xqf, const bf16_t* xqb, const bf16_t* xvb,
                   float* outf, bf16_t* outb, int strict) {
    gemm_bt<false, false, true><<<gg, 256, 0, stream>>>(
        xqb, wq_b + i * DD, bq + i * DM, nullptr, q_b, MROWS, DM, DM);
    gemm_bt<false, false, true><<<gg, 256, 0, stream>>>(
        xvb, wv_b + i * DD, bv + i * DM, nullptr, v_b, MROWS, DM, DM);
    gates_kernel<<<MROWS / 4, 256, 0, stream>>>(q_b, Wg + (size_t)i * HD_ * DM, dyn, fP + i * 12);
    routing_kernel<<<dim3(6, BSZ), 256, 0, stream>>>(dyn, rdyn);
    attn_kernel<<<dim3(SEQ, NH, BSZ), 256, 0, stream>>>(q_b, v_b, rdyn, ctx_b, strict);
    gemm_bt<false, true, false><<<gg, 256, 0, stream>>>(
        ctx_b, wo_b + i * DD, bo + i * DM, tmp_f, nullptr, MROWS, DM, DM);
    add_ln_kernel<<<MROWS, 256, 0, stream>>>(xqf, tmp_f, ln1g + i * DM, ln1b + i * DM, x1_f, x1_b);
    gemm_bt<true, false, true><<<gg, 256, 0, stream>>>(
        x1_b, w1_b + i * DD, b1 + i * DM, nullptr, ffn1_b, MROWS, DM, DM);
    gemm_bt<false, true, false><<<gg, 256, 0, stream>>>(
        ffn1_b, w2_b + i * DD, b2 + i * DM, tmp_f, nullptr, MROWS, DM, DM);
    add_ln_kernel<<<MROWS, 256, 0, stream>>>(x1_f, tmp_f, ln2g + i * DM, ln2b + i * DM, outf, outb);
  };

  float* outx = (float*)d_out;
  layer(0, qa_embed, y_b, y_b, y_f, y_b, 0);
  layer(1, y_f, y_b, y_b, y_f, y_b, 0);
  layer(2, q_embed, x_b, x_b, x_f, x_b, 0);
  layer(3, x_f, x_b, y_b, x_f, x_b, 1);
  layer(4, x_f, x_b, x_b, x_f, x_b, 0);
  layer(5, x_f, x_b, y_b, outx, x_b, 1);
  balance_kernel<<<1, 64, 0, stream>>>(fP + 5 * 12, outx + (size_t)MROWS * DM);
}

// Round 2
// 1722.540 us; speedup vs baseline: 5.8957x; 5.8957x over previous
//
#include <hip/hip_runtime.h>
#include <cstdint>

// ---------------- constants ----------------
#define BSZ 32
#define SEQ 512
#define DM  512
#define NH  8
#define DK  64
#define HS_ 2
#define HD_ 6
#define NL  6
#define MROWS (BSZ*SEQ)          // 16384

typedef unsigned short bf16_t;
typedef __attribute__((ext_vector_type(4))) float f32x4;
typedef __attribute__((ext_vector_type(8))) short bf16x8;
typedef __attribute__((ext_vector_type(8))) unsigned short u16x8;

#define DEV static __device__ __forceinline__

DEV float bf2f(bf16_t b) {
  unsigned int u = ((unsigned int)b) << 16;
  float f; __builtin_memcpy(&f, &u, 4); return f;
}
DEV bf16_t f2b(float f) {  // RNE bf16 (finite inputs)
  unsigned int u; __builtin_memcpy(&u, &f, 4);
  unsigned int r = (u + 0x7fffu + ((u >> 16) & 1u)) >> 16;
  return (bf16_t)r;
}
DEV void unp2(unsigned int w, float& a, float& b) {
  unsigned int ua = w << 16, ub = w & 0xffff0000u;
  __builtin_memcpy(&a, &ua, 4); __builtin_memcpy(&b, &ub, 4);
}

DEV void gload_lds16(const bf16_t* g, bf16_t* l) {
  __builtin_amdgcn_global_load_lds(
      (const __attribute__((address_space(1))) void*)g,
      (__attribute__((address_space(3))) void*)l, 16, 0, 0);
}

// ---------------- f32 -> bf16 convert ----------------
__global__ __launch_bounds__(256) void f2b_kernel(const float* __restrict__ in,
                                                  bf16_t* __restrict__ out, int n4) {
  int i = blockIdx.x * 256 + threadIdx.x;
  int stride = gridDim.x * 256;
  for (; i < n4; i += stride) {
    float4 v = reinterpret_cast<const float4*>(in)[i];
    ushort4 o;
    o.x = f2b(v.x); o.y = f2b(v.y); o.z = f2b(v.z); o.w = f2b(v.w);
    reinterpret_cast<ushort4*>(out)[i] = o;
  }
}

// ---------------- MFMA GEMM: Y = A @ W^T + bias ----------------
template <bool RELU, bool OUTF, bool OUTB>
__global__ __launch_bounds__(256) void gemm_bt(
    const bf16_t* __restrict__ A, const bf16_t* __restrict__ W,
    const float* __restrict__ bias, float* __restrict__ Yf,
    bf16_t* __restrict__ Yb, int M, int N, int K) {
  const int bn = blockIdx.x, bm = blockIdx.y;
  const int tid = threadIdx.x, wid = tid >> 6, lane = tid & 63;
  const int wr = wid >> 1, wc = wid & 1;   // 2x2 wave grid, 64x64 each
  __shared__ __align__(16) bf16_t As[128 * 32];
  __shared__ __align__(16) bf16_t Bs[128 * 32];

  f32x4 acc[4][4];
#pragma unroll
  for (int m = 0; m < 4; ++m)
#pragma unroll
    for (int n = 0; n < 4; ++n) acc[m][n] = f32x4{0.f, 0.f, 0.f, 0.f};

  const int lrow = lane & 15, lko = (lane >> 4) * 8;
  const size_t arow0 = (size_t)bm * 128, brow0 = (size_t)bn * 128;

  for (int k0 = 0; k0 < K; k0 += 32) {
#pragma unroll
    for (int i = 0; i < 2; ++i) {
      int e = (i * 256 + tid) * 8;           // element in [128][32]
      int r = e >> 5, c = e & 31;
      gload_lds16(A + (arow0 + r) * K + k0 + c, &As[(i * 4 + wid) * 512]);
      gload_lds16(W + (brow0 + r) * K + k0 + c, &Bs[(i * 4 + wid) * 512]);
    }
    __syncthreads();
    bf16x8 af[4], bw[4];
#pragma unroll
    for (int m = 0; m < 4; ++m)
      af[m] = *reinterpret_cast<const bf16x8*>(&As[(wr * 64 + m * 16 + lrow) * 32 + lko]);
#pragma unroll
    for (int n = 0; n < 4; ++n)
      bw[n] = *reinterpret_cast<const bf16x8*>(&Bs[(wc * 64 + n * 16 + lrow) * 32 + lko]);
#pragma unroll
    for (int m = 0; m < 4; ++m)
#pragma unroll
      for (int n = 0; n < 4; ++n)
        acc[m][n] = __builtin_amdgcn_mfma_f32_16x16x32_bf16(af[m], bw[n], acc[m][n], 0, 0, 0);
    __syncthreads();
  }

  const int r0 = bm * 128 + wr * 64 + (lane >> 4) * 4;
  const int c0 = bn * 128 + wc * 64 + lrow;
#pragma unroll
  for (int n = 0; n < 4; ++n) {
    const int col = c0 + n * 16;
    const float bc = bias[col];
#pragma unroll
    for (int m = 0; m < 4; ++m) {
#pragma unroll
      for (int j = 0; j < 4; ++j) {
        float v = acc[m][n][j] + bc;
        if (RELU) v = fmaxf(v, 0.f);
        const size_t off = (size_t)(r0 + m * 16 + j) * N + col;
        if (OUTF) Yf[off] = v;
        if (OUTB) Yb[off] = f2b(v);
      }
    }
  }
}

// ---------------- gating: softmax(q @ Wg^T), top-4-of-6 ----------------
__global__ __launch_bounds__(256) void gates_kernel(
    const bf16_t* __restrict__ qb, const float* __restrict__ Wg,
    float* __restrict__ dyn, float* __restrict__ fP) {
  __shared__ float wg_s[HD_ * DM];
  __shared__ float blk[4][12];
  const int tid = threadIdx.x, wid = tid >> 6, lane = tid & 63;
  for (int i = tid; i < HD_ * DM; i += 256) wg_s[i] = Wg[i];
  __syncthreads();
  const int tok = blockIdx.x * 4 + wid;
  const uint4* qr = reinterpret_cast<const uint4*>(qb + (size_t)tok * DM);
  float x[8];
  {
    uint4 u = qr[lane];
    unp2(u.x, x[0], x[1]); unp2(u.y, x[2], x[3]);
    unp2(u.z, x[4], x[5]); unp2(u.w, x[6], x[7]);
  }
  float g[6];
#pragma unroll
  for (int j = 0; j < 6; ++j) {
    float p = 0.f;
#pragma unroll
    for (int e = 0; e < 8; ++e) p = fmaf(x[e], wg_s[j * DM + lane * 8 + e], p);
#pragma unroll
    for (int off = 32; off; off >>= 1) p += __shfl_xor(p, off);
    g[j] = p;
  }
  float mx = g[0];
#pragma unroll
  for (int j = 1; j < 6; ++j) mx = fmaxf(mx, g[j]);
  float se = 0.f;
#pragma unroll
  for (int j = 0; j < 6; ++j) { g[j] = __expf(g[j] - mx); se += g[j]; }
  float inv = 1.f / se;
#pragma unroll
  for (int j = 0; j < 6; ++j) g[j] *= inv;
  int d1 = 0;
#pragma unroll
  for (int j = 1; j < 6; ++j)
    if (g[j] < g[d1] || (g[j] == g[d1] && j > d1)) d1 = j;
  int d2 = (d1 == 0) ? 1 : 0;
#pragma unroll
  for (int j = 0; j < 6; ++j) {
    if (j == d1) continue;
    if (g[j] < g[d2] || (g[j] == g[d2] && j > d2)) d2 = j;
  }
  if (lane == 0) {
#pragma unroll
    for (int j = 0; j < 6; ++j) {
      bool drop = (j == d1) || (j == d2);
      dyn[(size_t)tok * 6 + j] = drop ? 0.f : g[j];
      blk[wid][j] = drop ? 0.f : 1.f;
      blk[wid][6 + j] = g[j];
    }
  }
  __syncthreads();
  if (tid < 12) {
    float s = blk[0][tid] + blk[1][tid] + blk[2][tid] + blk[3][tid];
    atomicAdd(&fP[tid], s);
  }
}

// ---------------- routing: mean over s of dyn ----------------
__global__ __launch_bounds__(256) void routing_kernel(const float* __restrict__ dyn,
                                                      float* __restrict__ rdyn) {
  const int j = blockIdx.x, b = blockIdx.y;
  const int tid = threadIdx.x, wid = tid >> 6, lane = tid & 63;
  float s = 0.f;
  for (int si = tid; si < SEQ; si += 256) s += dyn[((size_t)b * SEQ + si) * 6 + j];
#pragma unroll
  for (int off = 32; off; off >>= 1) s += __shfl_xor(s, off);
  __shared__ float red[4];
  if (lane == 0) red[wid] = s;
  __syncthreads();
  if (tid == 0) rdyn[b * 6 + j] = (red[0] + red[1] + red[2] + red[3]) * (1.f / 512.f);
}

// ---------------- row-0 quirk: ctx[b,0,h,:] = factor * mean_k V ----------------
__global__ __launch_bounds__(512) void rowzero_kernel(
    const bf16_t* __restrict__ vb, const float* __restrict__ rdyn,
    bf16_t* __restrict__ ctx) {
  const int h = blockIdx.x, b = blockIdx.y;
  const int d = threadIdx.x & 63, kc = threadIdx.x >> 6;   // 8 chunks of 64 rows
  float s = 0.f;
  for (int i = 0; i < 64; ++i) {
    int k = kc * 64 + i;
    s += bf2f(vb[((size_t)(b * SEQ + k)) * DM + h * DK + d]);
  }
  __shared__ float red[8][64];
  red[kc][d] = s;
  __syncthreads();
  if (threadIdx.x < 64) {
    float t = 0.f;
#pragma unroll
    for (int c = 0; c < 8; ++c) t += red[c][threadIdx.x];
    const float factor = (h < HS_) ? 1.f : rdyn[b * 6 + (h - HS_)];
    ctx[((size_t)(b * SEQ)) * DM + h * DK + threadIdx.x] = f2b(t * (1.f / 512.f) * factor);
  }
}

// ---------------- fused flash attention (MFMA) ----------------
// grid (qt=4, h, b), 256 thr. Wave w: 32 q-rows. K-tile=64 keys.
// Swapped QK^T: mfma(A=K, B=Q) -> lane owns one q-row's scores.
__global__ __launch_bounds__(256) void fattn_kernel(
    const bf16_t* __restrict__ qb, const bf16_t* __restrict__ vb,
    const float* __restrict__ rdyn, bf16_t* __restrict__ ctx, int strict) {
  const int qt = blockIdx.x, h = blockIdx.y, b = blockIdx.z;
  const int tid = threadIdx.x, wid = tid >> 6, lane = tid & 63;
  const int c0 = lane & 15, grp = lane >> 4;
  const int l3 = lane >> 3, c3 = lane & 7;
  const int qbase = qt * 128 + wid * 32;

  __shared__ __align__(16) bf16_t Ks[64 * 64];        // swizzled [64k][64ch]
  __shared__ __align__(16) bf16_t Vt[64 * 136];       // transposed, padded [64d][64k+8]
  __shared__ __align__(16) bf16_t Ps[4][32 * 64];     // per-wave P, swizzled

  // Q fragments (B-operand): row = q, k = channel
  bf16x8 qf[2][2];
#pragma unroll
  for (int nt = 0; nt < 2; ++nt)
#pragma unroll
    for (int ks = 0; ks < 2; ++ks)
      qf[nt][ks] = *reinterpret_cast<const bf16x8*>(
          qb + ((size_t)(b * SEQ + qbase + nt * 16 + c0)) * DM + h * DK + ks * 32 + grp * 8);

  f32x4 acc[2][4];
#pragma unroll
  for (int m = 0; m < 2; ++m)
#pragma unroll
    for (int d = 0; d < 4; ++d) acc[m][d] = f32x4{0.f, 0.f, 0.f, 0.f};
  float mreg[2] = {-3e38f, -3e38f};
  float lreg[2] = {0.f, 0.f};

  const int lastk = (qbase + 31 - strict) >> 6;   // last tile this wave needs
  const int ktmax = 2 * qt + 1;                   // last tile any wave in block needs

  for (int kt = 0; kt <= ktmax; ++kt) {
    // ---- stage K tile via global_load_lds, source pre-swizzled ----
#pragma unroll
    for (int i = 0; i < 2; ++i) {
      int row = i * 32 + wid * 8 + l3;
      int blk = c3 ^ l3;
      gload_lds16(qb + ((size_t)(b * SEQ + kt * 64 + row)) * DM + h * DK + blk * 8,
                  Ks + (i * 32 + wid * 8) * 64);
    }
    // ---- stage V transposed (scalar ds writes) ----
#pragma unroll
    for (int j = 0; j < 2; ++j) {
      int kk = wid * 16 + j * 8 + l3;
      u16x8 vv = *reinterpret_cast<const u16x8*>(
          vb + ((size_t)(b * SEQ + kt * 64 + kk)) * DM + h * DK + c3 * 8);
#pragma unroll
      for (int e = 0; e < 8; ++e)
        Vt[(c3 * 8 + e) * 136 + kk] = vv[e];
    }
    __syncthreads();

    if (kt <= lastk) {
      // ---- QK^T (swapped) ----
      const char* KsB = (const char*)Ks;
      bf16x8 kf[4][2];
#pragma unroll
      for (int mt = 0; mt < 4; ++mt)
#pragma unroll
        for (int ks = 0; ks < 2; ++ks)
          kf[mt][ks] = *reinterpret_cast<const bf16x8*>(
              KsB + (mt * 16 + c0) * 128 + 16 * ((4 * ks + grp) ^ (c0 & 7)));
      f32x4 s[4][2];
#pragma unroll
      for (int mt = 0; mt < 4; ++mt)
#pragma unroll
        for (int nt = 0; nt < 2; ++nt) s[mt][nt] = f32x4{0.f, 0.f, 0.f, 0.f};
#pragma unroll
      for (int mt = 0; mt < 4; ++mt)
#pragma unroll
        for (int nt = 0; nt < 2; ++nt)
#pragma unroll
          for (int ks = 0; ks < 2; ++ks)
            s[mt][nt] = __builtin_amdgcn_mfma_f32_16x16x32_bf16(
                kf[mt][ks], qf[nt][ks], s[mt][nt], 0, 0, 0);

      const bool masked = (kt == lastk);
      float sc[2];
#pragma unroll
      for (int nt = 0; nt < 2; ++nt) {
        const int q = qbase + nt * 16 + c0;
#pragma unroll
        for (int mt = 0; mt < 4; ++mt)
#pragma unroll
          for (int j = 0; j < 4; ++j) {
            int k = kt * 64 + mt * 16 + grp * 4 + j;
            float t = s[mt][nt][j] * 0.125f;
            if (masked && (k + strict > q)) t = -1e30f;
            s[mt][nt][j] = t;
          }
        float mx = -3e38f;
#pragma unroll
        for (int mt = 0; mt < 4; ++mt)
#pragma unroll
          for (int j = 0; j < 4; ++j) mx = fmaxf(mx, s[mt][nt][j]);
        mx = fmaxf(mx, __shfl_xor(mx, 16));
        mx = fmaxf(mx, __shfl_xor(mx, 32));
        const float mnew = fmaxf(mreg[nt], mx);
        sc[nt] = __expf(mreg[nt] - mnew);
        mreg[nt] = mnew;
        float ts = 0.f;
#pragma unroll
        for (int mt = 0; mt < 4; ++mt)
#pragma unroll
          for (int j = 0; j < 4; ++j) {
            float pp = __expf(s[mt][nt][j] - mnew);
            s[mt][nt][j] = pp; ts += pp;
          }
        ts += __shfl_xor(ts, 16);
        ts += __shfl_xor(ts, 32);
        lreg[nt] = lreg[nt] * sc[nt] + ts;
      }
      // ---- P -> bf16 -> per-wave LDS (swizzled) ----
      char* PsB = (char*)(&Ps[wid][0]);
#pragma unroll
      for (int nt = 0; nt < 2; ++nt)
#pragma unroll
        for (int mt = 0; mt < 4; ++mt) {
          uint2 w;
          w.x = (unsigned)f2b(s[mt][nt][0]) | ((unsigned)f2b(s[mt][nt][1]) << 16);
          w.y = (unsigned)f2b(s[mt][nt][2]) | ((unsigned)f2b(s[mt][nt][3]) << 16);
          int row = nt * 16 + c0;
          int off = (row * 128 + mt * 32 + grp * 8) ^ ((c0 & 7) << 4);
          *reinterpret_cast<uint2*>(PsB + off) = w;
        }
      // ---- online rescale of ctx ----
#pragma unroll
      for (int mtq = 0; mtq < 2; ++mtq) {
        f32x4 sv;
#pragma unroll
        for (int j = 0; j < 4; ++j) sv[j] = __shfl(sc[mtq], grp * 4 + j);
#pragma unroll
        for (int dt = 0; dt < 4; ++dt) acc[mtq][dt] *= sv;
      }
      // ---- PV ----
      bf16x8 pf[2][2], vf2[4][2];
#pragma unroll
      for (int mtq = 0; mtq < 2; ++mtq)
#pragma unroll
        for (int ks = 0; ks < 2; ++ks)
          pf[mtq][ks] = *reinterpret_cast<const bf16x8*>(
              PsB + (mtq * 16 + c0) * 128 + 16 * ((4 * ks + grp) ^ (c0 & 7)));
#pragma unroll
      for (int dt = 0; dt < 4; ++dt)
#pragma unroll
        for (int ks = 0; ks < 2; ++ks)
          vf2[dt][ks] = *reinterpret_cast<const bf16x8*>(
              (const char*)Vt + (dt * 16 + c0) * 272 + ks * 64 + grp * 16);
#pragma unroll
      for (int mtq = 0; mtq < 2; ++mtq)
#pragma unroll
        for (int dt = 0; dt < 4; ++dt)
#pragma unroll
          for (int ks = 0; ks < 2; ++ks)
            acc[mtq][dt] = __builtin_amdgcn_mfma_f32_16x16x32_bf16(
                pf[mtq][ks], vf2[dt][ks], acc[mtq][dt], 0, 0, 0);
    }
    __syncthreads();
  }

  // ---- epilogue: /l, *routing, store (skip q==0) ----
  const float factor = (h < HS_) ? 1.f : rdyn[b * 6 + (h - HS_)];
#pragma unroll
  for (int mtq = 0; mtq < 2; ++mtq) {
    const float inv = factor / lreg[mtq];
    f32x4 iv;
#pragma unroll
    for (int j = 0; j < 4; ++j) iv[j] = __shfl(inv, grp * 4 + j);
#pragma unroll
    for (int j = 0; j < 4; ++j) {
      const int q = qbase + mtq * 16 + grp * 4 + j;
      if (q == 0) continue;
#pragma unroll
      for (int dt = 0; dt < 4; ++dt)
        ctx[((size_t)(b * SEQ + q)) * DM + h * DK + dt * 16 + c0] =
            f2b(acc[mtq][dt][j] * iv[j]);
    }
  }
}

// ---------------- add + layernorm ----------------
__global__ __launch_bounds__(256) void add_ln_kernel(
    const float* __restrict__ X, const float* __restrict__ A2,
    const float* __restrict__ gam, const float* __restrict__ bet,
    float* __restrict__ outf, bf16_t* __restrict__ outb) {
  const int row = blockIdx.x, tid = threadIdx.x, wid = tid >> 6, lane = tid & 63;
  const size_t base = (size_t)row * DM;
  float z0 = X[base + tid] + A2[base + tid];
  float z1 = X[base + tid + 256] + A2[base + tid + 256];
  __shared__ float red[4];
  float s = z0 + z1;
#pragma unroll
  for (int off = 32; off; off >>= 1) s += __shfl_xor(s, off);
  if (lane == 0) red[wid] = s;
  __syncthreads();
  const float mean = (red[0] + red[1] + red[2] + red[3]) * (1.f / 512.f);
  __syncthreads();
  const float d0 = z0 - mean, d1 = z1 - mean;
  float ss = d0 * d0 + d1 * d1;
#pragma unroll
  for (int off = 32; off; off >>= 1) ss += __shfl_xor(ss, off);
  if (lane == 0) red[wid] = ss;
  __syncthreads();
  const float var = (red[0] + red[1] + red[2] + red[3]) * (1.f / 512.f);
  const float inv = rsqrtf(var + 1e-5f);
  const float o0 = d0 * inv * gam[tid] + bet[tid];
  const float o1 = d1 * inv * gam[tid + 256] + bet[tid + 256];
  outf[base + tid] = o0;
  outf[base + tid + 256] = o1;
  outb[base + tid] = f2b(o0);
  outb[base + tid + 256] = f2b(o1);
}

// ---------------- balance ----------------
__global__ void balance_kernel(const float* __restrict__ fP, float* __restrict__ out) {
  if (threadIdx.x == 0 && blockIdx.x == 0) {
    float fs = 0.f, pssum = 0.f, P[6];
    for (int j = 0; j < 6; ++j) {
      fs += fP[j];
      P[j] = fP[6 + j] * (1.f / (float)MROWS);
      pssum += P[j];
    }
    float bal = 0.f;
    for (int j = 0; j < 6; ++j)
      bal += (fP[j] / (fs + 1e-5f)) * (P[j] / (pssum + 1e-5f));
    out[0] = bal;
  }
}

// ---------------- host ----------------
extern "C" void kernel_launch(void* const* d_in, const int* in_sizes, int n_in,
                              void* d_out, int out_size, void* d_ws, size_t ws_size,
                              hipStream_t stream) {
  (void)in_sizes; (void)n_in; (void)out_size; (void)ws_size;
  const float* q_embed  = (const float*)d_in[0];
  const float* qa_embed = (const float*)d_in[1];
  const float* Wq  = (const float*)d_in[2];
  const float* bq  = (const float*)d_in[3];
  const float* Wv  = (const float*)d_in[4];
  const float* bv  = (const float*)d_in[5];
  const float* Wg  = (const float*)d_in[6];
  const float* Wo  = (const float*)d_in[7];
  const float* bo  = (const float*)d_in[8];
  const float* ln1g = (const float*)d_in[9];
  const float* ln1b = (const float*)d_in[10];
  const float* W1  = (const float*)d_in[11];
  const float* b1  = (const float*)d_in[12];
  const float* W2  = (const float*)d_in[13];
  const float* b2  = (const float*)d_in[14];
  const float* ln2g = (const float*)d_in[15];
  const float* ln2b = (const float*)d_in[16];

  char* p = (char*)d_ws;
  auto alloc = [&](size_t bytes) -> char* {
    char* r = p; p += (bytes + 255) & ~(size_t)255; return r;
  };
  const size_t WDE = (size_t)NL * DM * DM;   // stacked weight elems
  const size_t AE  = (size_t)MROWS * DM;     // activation elems
  bf16_t* wq_b = (bf16_t*)alloc(WDE * 2);
  bf16_t* wv_b = (bf16_t*)alloc(WDE * 2);
  bf16_t* wo_b = (bf16_t*)alloc(WDE * 2);
  bf16_t* w1_b = (bf16_t*)alloc(WDE * 2);
  bf16_t* w2_b = (bf16_t*)alloc(WDE * 2);
  float* y_f   = (float*)alloc(AE * 4);
  float* x_f   = (float*)alloc(AE * 4);
  float* tmp_f = (float*)alloc(AE * 4);
  float* x1_f  = (float*)alloc(AE * 4);
  bf16_t* y_b   = (bf16_t*)alloc(AE * 2);
  bf16_t* x_b   = (bf16_t*)alloc(AE * 2);
  bf16_t* q_b   = (bf16_t*)alloc(AE * 2);
  bf16_t* v_b   = (bf16_t*)alloc(AE * 2);
  bf16_t* ctx_b = (bf16_t*)alloc(AE * 2);
  bf16_t* x1_b  = (bf16_t*)alloc(AE * 2);
  float* dyn  = (float*)alloc((size_t)MROWS * 6 * 4);
  float* rdyn = (float*)alloc(BSZ * 6 * 4);
  float* fP   = (float*)alloc(NL * 12 * 4);
  bf16_t* ffn1_b = q_b;   // alias: q dead after attention/gates

  hipMemsetAsync(fP, 0, NL * 12 * 4, stream);

  // weights -> bf16
  f2b_kernel<<<1536, 256, 0, stream>>>(Wq, wq_b, (int)(WDE / 4));
  f2b_kernel<<<1536, 256, 0, stream>>>(Wv, wv_b, (int)(WDE / 4));
  f2b_kernel<<<1536, 256, 0, stream>>>(Wo, wo_b, (int)(WDE / 4));
  f2b_kernel<<<1536, 256, 0, stream>>>(W1, w1_b, (int)(WDE / 4));
  f2b_kernel<<<1536, 256, 0, stream>>>(W2, w2_b, (int)(WDE / 4));
  // initial activations -> bf16
  f2b_kernel<<<2048, 256, 0, stream>>>(qa_embed, y_b, (int)(AE / 4));
  f2b_kernel<<<2048, 256, 0, stream>>>(q_embed, x_b, (int)(AE / 4));

  const size_t DD = (size_t)DM * DM;
  dim3 gg(4, 128);   // N/128, M/128

  auto layer = [&](int i, const float* xqf, const bf16_t* xqb, const bf16_t* xvb,
                   float* outf, bf16_t* outb, int strict) {
    gemm_bt<false, false, true><<<gg, 256, 0, stream>>>(
        xqb, wq_b + i * DD, bq + i * DM, nullptr, q_b, MROWS, DM, DM);
    gemm_bt<false, false, true><<<gg, 256, 0, stream>>>(
        xvb, wv_b + i * DD, bv + i * DM, nullptr, v_b, MROWS, DM, DM);
    gates_kernel<<<MROWS / 4, 256, 0, stream>>>(q_b, Wg + (size_t)i * HD_ * DM, dyn, fP + i * 12);
    routing_kernel<<<dim3(6, BSZ), 256, 0, stream>>>(dyn, rdyn);
    rowzero_kernel<<<dim3(NH, BSZ), 512, 0, stream>>>(v_b, rdyn, ctx_b);
    fattn_kernel<<<dim3(4, NH, BSZ), 256, 0, stream>>>(q_b, v_b, rdyn, ctx_b, strict);
    gemm_bt<false, true, false><<<gg, 256, 0, stream>>>(
        ctx_b, wo_b + i * DD, bo + i * DM, tmp_f, nullptr, MROWS, DM, DM);
    add_ln_kernel<<<MROWS, 256, 0, stream>>>(xqf, tmp_f, ln1g + i * DM, ln1b + i * DM, x1_f, x1_b);
    gemm_bt<true, false, true><<<gg, 256, 0, stream>>>(
        x1_b, w1_b + i * DD, b1 + i * DM, nullptr, ffn1_b, MROWS, DM, DM);
    gemm_bt<false, true, false><<<gg, 256, 0, stream>>>(
        ffn1_b, w2_b + i * DD, b2 + i * DM, tmp_f, nullptr, MROWS, DM, DM);
    add_ln_kernel<<<MROWS, 256, 0, stream>>>(x1_f, tmp_f, ln2g + i * DM, ln2b + i * DM, outf, outb);
  };

  float* outx = (float*)d_out;
  layer(0, qa_embed, y_b, y_b, y_f, y_b, 0);
  layer(1, y_f, y_b, y_b, y_f, y_b, 0);
  layer(2, q_embed, x_b, x_b, x_f, x_b, 0);
  layer(3, x_f, x_b, y_b, x_f, x_b, 1);
  layer(4, x_f, x_b, x_b, x_f, x_b, 0);
  layer(5, x_f, x_b, y_b, outx, x_b, 1);
  balance_kernel<<<1, 64, 0, stream>>>(fP + 5 * 12, outx + (size_t)MROWS * DM);
}

// Round 3
// 1398.287 us; speedup vs baseline: 7.2629x; 1.2319x over previous
//
#include <hip/hip_runtime.h>
#include <cstdint>

// ---------------- constants ----------------
#define BSZ 32
#define SEQ 512
#define DM  512
#define NH  8
#define DK  64
#define HS_ 2
#define HD_ 6
#define NL  6
#define MROWS (BSZ*SEQ)          // 16384
#define QVLD 1024                // row stride of merged q|v buffer

typedef unsigned short bf16_t;
typedef __attribute__((ext_vector_type(4))) float f32x4;
typedef __attribute__((ext_vector_type(8))) short bf16x8;
typedef __attribute__((ext_vector_type(8))) unsigned short u16x8;

#define DEV static __device__ __forceinline__

DEV float bf2f(bf16_t b) {
  unsigned int u = ((unsigned int)b) << 16;
  float f; __builtin_memcpy(&f, &u, 4); return f;
}
DEV bf16_t f2b(float f) {  // RNE bf16 (finite inputs)
  unsigned int u; __builtin_memcpy(&u, &f, 4);
  unsigned int r = (u + 0x7fffu + ((u >> 16) & 1u)) >> 16;
  return (bf16_t)r;
}
DEV void unp2(unsigned int w, float& a, float& b) {
  unsigned int ua = w << 16, ub = w & 0xffff0000u;
  __builtin_memcpy(&a, &ua, 4); __builtin_memcpy(&b, &ub, 4);
}

DEV void gload_lds16(const bf16_t* g, bf16_t* l) {
  __builtin_amdgcn_global_load_lds(
      (const __attribute__((address_space(1))) void*)g,
      (__attribute__((address_space(3))) void*)l, 16, 0, 0);
}

// ---------------- f32 -> bf16 convert ----------------
__global__ __launch_bounds__(256) void f2b_kernel(const float* __restrict__ in,
                                                  bf16_t* __restrict__ out, int n4) {
  int i = blockIdx.x * 256 + threadIdx.x;
  int stride = gridDim.x * 256;
  for (; i < n4; i += stride) {
    float4 v = reinterpret_cast<const float4*>(in)[i];
    ushort4 o;
    o.x = f2b(v.x); o.y = f2b(v.y); o.z = f2b(v.z); o.w = f2b(v.w);
    reinterpret_cast<ushort4*>(out)[i] = o;
  }
}

// ---------------- MFMA GEMM: Y = A @ W^T + bias ----------------
// A [M,512] bf16. W split at N=512: rows [0,512) from W0, [512,...) from W1.
// grid (Ntiles, M/128). 128x128 tile, BK=32, 4 waves.
template <bool RELU, bool OUTF, bool OUTB>
__global__ __launch_bounds__(256) void gemm_bt(
    const bf16_t* __restrict__ A, const bf16_t* __restrict__ W0,
    const bf16_t* __restrict__ W1, const float* __restrict__ b0,
    const float* __restrict__ b1, float* __restrict__ Yf,
    bf16_t* __restrict__ Yb, int ldy) {
  const int K = 512;
  const int bn = blockIdx.x, bm = blockIdx.y;
  const int tid = threadIdx.x, wid = tid >> 6, lane = tid & 63;
  const int wr = wid >> 1, wc = wid & 1;   // 2x2 wave grid, 64x64 each
  __shared__ __align__(16) bf16_t As[128 * 32];
  __shared__ __align__(16) bf16_t Bs[128 * 32];

  const bool hi = (bn * 128) >= 512;
  const bf16_t* Wsel = hi ? (W1 - (size_t)512 * K) : W0;
  const float* bsel = hi ? (b1 - 512) : b0;

  f32x4 acc[4][4];
#pragma unroll
  for (int m = 0; m < 4; ++m)
#pragma unroll
    for (int n = 0; n < 4; ++n) acc[m][n] = f32x4{0.f, 0.f, 0.f, 0.f};

  const int lrow = lane & 15, lko = (lane >> 4) * 8;
  const size_t arow0 = (size_t)bm * 128, brow0 = (size_t)bn * 128;

  for (int k0 = 0; k0 < K; k0 += 32) {
#pragma unroll
    for (int i = 0; i < 2; ++i) {
      int e = (i * 256 + tid) * 8;           // element in [128][32]
      int r = e >> 5, c = e & 31;
      gload_lds16(A + (arow0 + r) * K + k0 + c, &As[(i * 4 + wid) * 512]);
      gload_lds16(Wsel + (brow0 + r) * K + k0 + c, &Bs[(i * 4 + wid) * 512]);
    }
    __syncthreads();
    bf16x8 af[4], bw[4];
#pragma unroll
    for (int m = 0; m < 4; ++m)
      af[m] = *reinterpret_cast<const bf16x8*>(&As[(wr * 64 + m * 16 + lrow) * 32 + lko]);
#pragma unroll
    for (int n = 0; n < 4; ++n)
      bw[n] = *reinterpret_cast<const bf16x8*>(&Bs[(wc * 64 + n * 16 + lrow) * 32 + lko]);
    __builtin_amdgcn_s_setprio(1);
#pragma unroll
    for (int m = 0; m < 4; ++m)
#pragma unroll
      for (int n = 0; n < 4; ++n)
        acc[m][n] = __builtin_amdgcn_mfma_f32_16x16x32_bf16(af[m], bw[n], acc[m][n], 0, 0, 0);
    __builtin_amdgcn_s_setprio(0);
    __syncthreads();
  }

  const int r0 = bm * 128 + wr * 64 + (lane >> 4) * 4;
  const int c0 = bn * 128 + wc * 64 + lrow;
#pragma unroll
  for (int n = 0; n < 4; ++n) {
    const int col = c0 + n * 16;
    const float bc = bsel[col];
#pragma unroll
    for (int m = 0; m < 4; ++m) {
#pragma unroll
      for (int j = 0; j < 4; ++j) {
        float v = acc[m][n][j] + bc;
        if (RELU) v = fmaxf(v, 0.f);
        const size_t off = (size_t)(r0 + m * 16 + j) * ldy + col;
        if (OUTF) Yf[off] = v;
        if (OUTB) Yb[off] = f2b(v);
      }
    }
  }
}

// ---------------- gating: softmax(q @ Wg^T), top-4-of-6, fused routing ----------------
// 64 tokens/block (4 waves x 16). Accumulates fP (f,Psum) and rdyn (routing mean) via atomics.
__global__ __launch_bounds__(256) void gates_kernel(
    const bf16_t* __restrict__ qv, const float* __restrict__ Wg,
    float* __restrict__ rdyn, float* __restrict__ fP) {
  __shared__ float wg_s[HD_ * DM];
  __shared__ float blk[4][18];
  const int tid = threadIdx.x, wid = tid >> 6, lane = tid & 63;
  for (int i = tid; i < HD_ * DM / 4; i += 256)
    reinterpret_cast<float4*>(wg_s)[i] = reinterpret_cast<const float4*>(Wg)[i];
  __syncthreads();
  const int bb = blockIdx.x >> 3;
  const int t0 = (blockIdx.x & 7) * 64 + wid * 16;
  float fs[6] = {0, 0, 0, 0, 0, 0}, ps[6] = {0, 0, 0, 0, 0, 0}, rs[6] = {0, 0, 0, 0, 0, 0};
  for (int it = 0; it < 16; ++it) {
    const int tok = bb * SEQ + t0 + it;
    uint4 u = reinterpret_cast<const uint4*>(qv + (size_t)tok * QVLD)[lane];
    float x[8];
    unp2(u.x, x[0], x[1]); unp2(u.y, x[2], x[3]);
    unp2(u.z, x[4], x[5]); unp2(u.w, x[6], x[7]);
    float g[6];
#pragma unroll
    for (int j = 0; j < 6; ++j) {
      float p = 0.f;
#pragma unroll
      for (int e = 0; e < 8; ++e) p = fmaf(x[e], wg_s[j * DM + lane * 8 + e], p);
#pragma unroll
      for (int off = 32; off; off >>= 1) p += __shfl_xor(p, off);
      g[j] = p;
    }
    float mx = g[0];
#pragma unroll
    for (int j = 1; j < 6; ++j) mx = fmaxf(mx, g[j]);
    float se = 0.f;
#pragma unroll
    for (int j = 0; j < 6; ++j) { g[j] = __expf(g[j] - mx); se += g[j]; }
    float inv = 1.f / se;
#pragma unroll
    for (int j = 0; j < 6; ++j) g[j] *= inv;
    int d1 = 0;
#pragma unroll
    for (int j = 1; j < 6; ++j)
      if (g[j] < g[d1] || (g[j] == g[d1] && j > d1)) d1 = j;
    int d2 = (d1 == 0) ? 1 : 0;
#pragma unroll
    for (int j = 0; j < 6; ++j) {
      if (j == d1) continue;
      if (g[j] < g[d2] || (g[j] == g[d2] && j > d2)) d2 = j;
    }
#pragma unroll
    for (int j = 0; j < 6; ++j) {
      const bool drop = (j == d1) || (j == d2);
      fs[j] += drop ? 0.f : 1.f;
      ps[j] += g[j];
      rs[j] += drop ? 0.f : g[j];
    }
  }
  if (lane == 0) {
#pragma unroll
    for (int j = 0; j < 6; ++j) {
      blk[wid][j] = fs[j]; blk[wid][6 + j] = ps[j]; blk[wid][12 + j] = rs[j];
    }
  }
  __syncthreads();
  if (tid < 18) {
    float s = blk[0][tid] + blk[1][tid] + blk[2][tid] + blk[3][tid];
    if (tid < 12) atomicAdd(&fP[tid], s);
    else atomicAdd(&rdyn[bb * 6 + (tid - 12)], s * (1.f / 512.f));
  }
}

// ---------------- row-0 quirk: ctx[b,0,h,:] = factor * mean_k V ----------------
__global__ __launch_bounds__(512) void rowzero_kernel(
    const bf16_t* __restrict__ qv, const float* __restrict__ rdyn,
    bf16_t* __restrict__ ctx) {
  const int h = blockIdx.x, b = blockIdx.y;
  const int d = threadIdx.x & 63, kc = threadIdx.x >> 6;   // 8 chunks of 64 rows
  const bf16_t* vb = qv + 512;
  float s = 0.f;
  for (int i = 0; i < 64; ++i) {
    int k = kc * 64 + i;
    s += bf2f(vb[((size_t)(b * SEQ + k)) * QVLD + h * DK + d]);
  }
  __shared__ float red[8][64];
  red[kc][d] = s;
  __syncthreads();
  if (threadIdx.x < 64) {
    float t = 0.f;
#pragma unroll
    for (int c = 0; c < 8; ++c) t += red[c][threadIdx.x];
    const float factor = (h < HS_) ? 1.f : rdyn[b * 6 + (h - HS_)];
    ctx[((size_t)(b * SEQ)) * DM + h * DK + threadIdx.x] = f2b(t * (1.f / 512.f) * factor);
  }
}

// ---------------- fused flash attention (MFMA) ----------------
// grid (qt=4, h, b), 256 thr. Wave w: 32 q-rows. K-tile=64 keys.
// Swapped QK^T: mfma(A=K, B=Q) -> lane owns one q-row's scores.
__global__ __launch_bounds__(256) void fattn_kernel(
    const bf16_t* __restrict__ qv, const float* __restrict__ rdyn,
    bf16_t* __restrict__ ctx, int strict) {
  const int qt = blockIdx.x, h = blockIdx.y, b = blockIdx.z;
  const int tid = threadIdx.x, wid = tid >> 6, lane = tid & 63;
  const int c0 = lane & 15, grp = lane >> 4;
  const int l3 = lane >> 3, c3 = lane & 7;
  const int qbase = qt * 128 + wid * 32;

  __shared__ __align__(16) bf16_t Ks[64 * 64];        // swizzled [64k][64ch]
  __shared__ __align__(16) bf16_t Vt[64 * 72];        // transposed [64d][64k+8pad]
  __shared__ __align__(16) bf16_t Ps[4][32 * 64];     // per-wave P, swizzled

  const bf16_t* qp = qv;          // q half, row stride QVLD
  const bf16_t* vp = qv + 512;    // v half

  // Q fragments (B-operand): row = q, k = channel
  bf16x8 qf[2][2];
#pragma unroll
  for (int nt = 0; nt < 2; ++nt)
#pragma unroll
    for (int ks = 0; ks < 2; ++ks)
      qf[nt][ks] = *reinterpret_cast<const bf16x8*>(
          qp + ((size_t)(b * SEQ + qbase + nt * 16 + c0)) * QVLD + h * DK + ks * 32 + grp * 8);

  f32x4 acc[2][4];
#pragma unroll
  for (int m = 0; m < 2; ++m)
#pragma unroll
    for (int d = 0; d < 4; ++d) acc[m][d] = f32x4{0.f, 0.f, 0.f, 0.f};
  float mreg[2] = {-3e38f, -3e38f};
  float lreg[2] = {0.f, 0.f};

  const int lastk = (qbase + 31 - strict) >> 6;   // last tile this wave needs
  const int ktmax = 2 * qt + 1;                   // last tile any wave in block needs

  for (int kt = 0; kt <= ktmax; ++kt) {
    // ---- stage K tile via global_load_lds, source pre-swizzled ----
#pragma unroll
    for (int i = 0; i < 2; ++i) {
      int row = i * 32 + wid * 8 + l3;
      int blk = c3 ^ l3;
      gload_lds16(qp + ((size_t)(b * SEQ + kt * 64 + row)) * QVLD + h * DK + blk * 8,
                  Ks + (i * 32 + wid * 8) * 64);
    }
    // ---- stage V transposed; lane-permute (l3^c3) to break write bank conflicts ----
#pragma unroll
    for (int j = 0; j < 2; ++j) {
      int kk = wid * 16 + j * 8 + (l3 ^ c3);
      u16x8 vv = *reinterpret_cast<const u16x8*>(
          vp + ((size_t)(b * SEQ + kt * 64 + kk)) * QVLD + h * DK + c3 * 8);
#pragma unroll
      for (int e = 0; e < 8; ++e)
        Vt[(c3 * 8 + e) * 72 + kk] = vv[e];
    }
    __syncthreads();

    if (kt <= lastk) {
      // ---- QK^T (swapped) ----
      const char* KsB = (const char*)Ks;
      bf16x8 kf[4][2];
#pragma unroll
      for (int mt = 0; mt < 4; ++mt)
#pragma unroll
        for (int ks = 0; ks < 2; ++ks)
          kf[mt][ks] = *reinterpret_cast<const bf16x8*>(
              KsB + (mt * 16 + c0) * 128 + 16 * ((4 * ks + grp) ^ (c0 & 7)));
      f32x4 s[4][2];
#pragma unroll
      for (int mt = 0; mt < 4; ++mt)
#pragma unroll
        for (int nt = 0; nt < 2; ++nt) s[mt][nt] = f32x4{0.f, 0.f, 0.f, 0.f};
      __builtin_amdgcn_s_setprio(1);
#pragma unroll
      for (int mt = 0; mt < 4; ++mt)
#pragma unroll
        for (int nt = 0; nt < 2; ++nt)
#pragma unroll
          for (int ks = 0; ks < 2; ++ks)
            s[mt][nt] = __builtin_amdgcn_mfma_f32_16x16x32_bf16(
                kf[mt][ks], qf[nt][ks], s[mt][nt], 0, 0, 0);
      __builtin_amdgcn_s_setprio(0);

      const bool masked = (kt == lastk);
      float sc[2];
#pragma unroll
      for (int nt = 0; nt < 2; ++nt) {
        const int q = qbase + nt * 16 + c0;
#pragma unroll
        for (int mt = 0; mt < 4; ++mt)
#pragma unroll
          for (int j = 0; j < 4; ++j) {
            int k = kt * 64 + mt * 16 + grp * 4 + j;
            float t = s[mt][nt][j] * 0.125f;
            if (masked && (k + strict > q)) t = -1e30f;
            s[mt][nt][j] = t;
          }
        float mx = -3e38f;
#pragma unroll
        for (int mt = 0; mt < 4; ++mt)
#pragma unroll
          for (int j = 0; j < 4; ++j) mx = fmaxf(mx, s[mt][nt][j]);
        mx = fmaxf(mx, __shfl_xor(mx, 16));
        mx = fmaxf(mx, __shfl_xor(mx, 32));
        const float mnew = fmaxf(mreg[nt], mx);
        sc[nt] = __expf(mreg[nt] - mnew);
        mreg[nt] = mnew;
        float ts = 0.f;
#pragma unroll
        for (int mt = 0; mt < 4; ++mt)
#pragma unroll
          for (int j = 0; j < 4; ++j) {
            float pp = __expf(s[mt][nt][j] - mnew);
            s[mt][nt][j] = pp; ts += pp;
          }
        ts += __shfl_xor(ts, 16);
        ts += __shfl_xor(ts, 32);
        lreg[nt] = lreg[nt] * sc[nt] + ts;
      }
      // ---- P -> bf16 -> per-wave LDS (swizzled) ----
      char* PsB = (char*)(&Ps[wid][0]);
#pragma unroll
      for (int nt = 0; nt < 2; ++nt)
#pragma unroll
        for (int mt = 0; mt < 4; ++mt) {
          uint2 w;
          w.x = (unsigned)f2b(s[mt][nt][0]) | ((unsigned)f2b(s[mt][nt][1]) << 16);
          w.y = (unsigned)f2b(s[mt][nt][2]) | ((unsigned)f2b(s[mt][nt][3]) << 16);
          int row = nt * 16 + c0;
          int off = (row * 128 + mt * 32 + grp * 8) ^ ((c0 & 7) << 4);
          *reinterpret_cast<uint2*>(PsB + off) = w;
        }
      // ---- online rescale of ctx ----
#pragma unroll
      for (int mtq = 0; mtq < 2; ++mtq) {
        f32x4 sv;
#pragma unroll
        for (int j = 0; j < 4; ++j) sv[j] = __shfl(sc[mtq], grp * 4 + j);
#pragma unroll
        for (int dt = 0; dt < 4; ++dt) acc[mtq][dt] *= sv;
      }
      // ---- PV ----
      bf16x8 pf[2][2], vf2[4][2];
#pragma unroll
      for (int mtq = 0; mtq < 2; ++mtq)
#pragma unroll
        for (int ks = 0; ks < 2; ++ks)
          pf[mtq][ks] = *reinterpret_cast<const bf16x8*>(
              PsB + (mtq * 16 + c0) * 128 + 16 * ((4 * ks + grp) ^ (c0 & 7)));
#pragma unroll
      for (int dt = 0; dt < 4; ++dt)
#pragma unroll
        for (int ks = 0; ks < 2; ++ks)
          vf2[dt][ks] = *reinterpret_cast<const bf16x8*>(
              (const char*)Vt + (dt * 16 + c0) * 144 + ks * 64 + grp * 16);
      __builtin_amdgcn_s_setprio(1);
#pragma unroll
      for (int mtq = 0; mtq < 2; ++mtq)
#pragma unroll
        for (int dt = 0; dt < 4; ++dt)
#pragma unroll
          for (int ks = 0; ks < 2; ++ks)
            acc[mtq][dt] = __builtin_amdgcn_mfma_f32_16x16x32_bf16(
                pf[mtq][ks], vf2[dt][ks], acc[mtq][dt], 0, 0, 0);
      __builtin_amdgcn_s_setprio(0);
    }
    __syncthreads();
  }

  // ---- epilogue: /l, *routing, store (skip q==0) ----
  const float factor = (h < HS_) ? 1.f : rdyn[b * 6 + (h - HS_)];
#pragma unroll
  for (int mtq = 0; mtq < 2; ++mtq) {
    const float inv = factor / lreg[mtq];
    f32x4 iv;
#pragma unroll
    for (int j = 0; j < 4; ++j) iv[j] = __shfl(inv, grp * 4 + j);
#pragma unroll
    for (int j = 0; j < 4; ++j) {
      const int q = qbase + mtq * 16 + grp * 4 + j;
      if (q == 0) continue;
#pragma unroll
      for (int dt = 0; dt < 4; ++dt)
        ctx[((size_t)(b * SEQ + q)) * DM + h * DK + dt * 16 + c0] =
            f2b(acc[mtq][dt][j] * iv[j]);
    }
  }
}

// ---------------- add + layernorm (residual f32, delta bf16) ----------------
__global__ __launch_bounds__(256) void add_ln_kernel(
    const float* __restrict__ X, const bf16_t* __restrict__ A2,
    const float* __restrict__ gam, const float* __restrict__ bet,
    float* __restrict__ outf, bf16_t* __restrict__ outb) {
  const int row = blockIdx.x, tid = threadIdx.x, wid = tid >> 6, lane = tid & 63;
  const size_t base = (size_t)row * DM;
  float z0 = X[base + tid] + bf2f(A2[base + tid]);
  float z1 = X[base + tid + 256] + bf2f(A2[base + tid + 256]);
  __shared__ float red[4];
  float s = z0 + z1;
#pragma unroll
  for (int off = 32; off; off >>= 1) s += __shfl_xor(s, off);
  if (lane == 0) red[wid] = s;
  __syncthreads();
  const float mean = (red[0] + red[1] + red[2] + red[3]) * (1.f / 512.f);
  __syncthreads();
  const float d0 = z0 - mean, d1 = z1 - mean;
  float ss = d0 * d0 + d1 * d1;
#pragma unroll
  for (int off = 32; off; off >>= 1) ss += __shfl_xor(ss, off);
  if (lane == 0) red[wid] = ss;
  __syncthreads();
  const float var = (red[0] + red[1] + red[2] + red[3]) * (1.f / 512.f);
  const float inv = rsqrtf(var + 1e-5f);
  const float o0 = d0 * inv * gam[tid] + bet[tid];
  const float o1 = d1 * inv * gam[tid + 256] + bet[tid + 256];
  outf[base + tid] = o0;
  outf[base + tid + 256] = o1;
  outb[base + tid] = f2b(o0);
  outb[base + tid + 256] = f2b(o1);
}

// ---------------- balance ----------------
__global__ void balance_kernel(const float* __restrict__ fP, float* __restrict__ out) {
  if (threadIdx.x == 0 && blockIdx.x == 0) {
    float fs = 0.f, pssum = 0.f, P[6];
    for (int j = 0; j < 6; ++j) {
      fs += fP[j];
      P[j] = fP[6 + j] * (1.f / (float)MROWS);
      pssum += P[j];
    }
    float bal = 0.f;
    for (int j = 0; j < 6; ++j)
      bal += (fP[j] / (fs + 1e-5f)) * (P[j] / (pssum + 1e-5f));
    out[0] = bal;
  }
}

// ---------------- host ----------------
extern "C" void kernel_launch(void* const* d_in, const int* in_sizes, int n_in,
                              void* d_out, int out_size, void* d_ws, size_t ws_size,
                              hipStream_t stream) {
  (void)in_sizes; (void)n_in; (void)out_size; (void)ws_size;
  const float* q_embed  = (const float*)d_in[0];
  const float* qa_embed = (const float*)d_in[1];
  const float* Wq  = (const float*)d_in[2];
  const float* bq  = (const float*)d_in[3];
  const float* Wv  = (const float*)d_in[4];
  const float* bv  = (const float*)d_in[5];
  const float* Wg  = (const float*)d_in[6];
  const float* Wo  = (const float*)d_in[7];
  const float* bo  = (const float*)d_in[8];
  const float* ln1g = (const float*)d_in[9];
  const float* ln1b = (const float*)d_in[10];
  const float* W1  = (const float*)d_in[11];
  const float* b1  = (const float*)d_in[12];
  const float* W2  = (const float*)d_in[13];
  const float* b2  = (const float*)d_in[14];
  const float* ln2g = (const float*)d_in[15];
  const float* ln2b = (const float*)d_in[16];

  char* p = (char*)d_ws;
  auto alloc = [&](size_t bytes) -> char* {
    char* r = p; p += (bytes + 255) & ~(size_t)255; return r;
  };
  const size_t WDE = (size_t)NL * DM * DM;   // stacked weight elems
  const size_t AE  = (size_t)MROWS * DM;     // activation elems
  bf16_t* wq_b = (bf16_t*)alloc(WDE * 2);
  bf16_t* wv_b = (bf16_t*)alloc(WDE * 2);
  bf16_t* wo_b = (bf16_t*)alloc(WDE * 2);
  bf16_t* w1_b = (bf16_t*)alloc(WDE * 2);
  bf16_t* w2_b = (bf16_t*)alloc(WDE * 2);
  float* y_f   = (float*)alloc(AE * 4);
  float* x_f   = (float*)alloc(AE * 4);
  float* x1_f  = (float*)alloc(AE * 4);
  bf16_t* y_b   = (bf16_t*)alloc(AE * 2);
  bf16_t* x_b   = (bf16_t*)alloc(AE * 2);
  bf16_t* qv_b  = (bf16_t*)alloc((size_t)MROWS * QVLD * 2);  // q|v merged
  bf16_t* ctx_b = (bf16_t*)alloc(AE * 2);
  bf16_t* x1_b  = (bf16_t*)alloc(AE * 2);
  bf16_t* tmp_b = (bf16_t*)alloc(AE * 2);
  bf16_t* ffn1_b = (bf16_t*)alloc(AE * 2);
  float* rdyn = (float*)alloc(BSZ * 6 * 4);
  float* fP   = (float*)alloc(NL * 12 * 4);

  hipMemsetAsync(fP, 0, NL * 12 * 4, stream);

  // weights -> bf16
  f2b_kernel<<<1536, 256, 0, stream>>>(Wq, wq_b, (int)(WDE / 4));
  f2b_kernel<<<1536, 256, 0, stream>>>(Wv, wv_b, (int)(WDE / 4));
  f2b_kernel<<<1536, 256, 0, stream>>>(Wo, wo_b, (int)(WDE / 4));
  f2b_kernel<<<1536, 256, 0, stream>>>(W1, w1_b, (int)(WDE / 4));
  f2b_kernel<<<1536, 256, 0, stream>>>(W2, w2_b, (int)(WDE / 4));
  // initial activations -> bf16
  f2b_kernel<<<2048, 256, 0, stream>>>(qa_embed, y_b, (int)(AE / 4));
  f2b_kernel<<<2048, 256, 0, stream>>>(q_embed, x_b, (int)(AE / 4));

  const size_t DD = (size_t)DM * DM;
  dim3 g512(4, 128), g1024(8, 128);

  auto layer = [&](int i, const float* xqf, const bf16_t* xqb, const bf16_t* xvb,
                   float* outf, bf16_t* outb, int strict) {
    hipMemsetAsync(rdyn, 0, BSZ * 6 * 4, stream);
    if (xqb == xvb) {
      // merged q|v projection: N=1024
      gemm_bt<false, false, true><<<g1024, 256, 0, stream>>>(
          xqb, wq_b + i * DD, wv_b + i * DD, bq + i * DM, bv + i * DM,
          nullptr, qv_b, QVLD);
    } else {
      gemm_bt<false, false, true><<<g512, 256, 0, stream>>>(
          xqb, wq_b + i * DD, wq_b + i * DD, bq + i * DM, bq + i * DM,
          nullptr, qv_b, QVLD);
      gemm_bt<false, false, true><<<g512, 256, 0, stream>>>(
          xvb, wv_b + i * DD, wv_b + i * DD, bv + i * DM, bv + i * DM,
          nullptr, qv_b + 512, QVLD);
    }
    gates_kernel<<<MROWS / 64, 256, 0, stream>>>(qv_b, Wg + (size_t)i * HD_ * DM, rdyn, fP + i * 12);
    rowzero_kernel<<<dim3(NH, BSZ), 512, 0, stream>>>(qv_b, rdyn, ctx_b);
    fattn_kernel<<<dim3(4, NH, BSZ), 256, 0, stream>>>(qv_b, rdyn, ctx_b, strict);
    gemm_bt<false, false, true><<<g512, 256, 0, stream>>>(
        ctx_b, wo_b + i * DD, wo_b + i * DD, bo + i * DM, bo + i * DM,
        nullptr, tmp_b, DM);
    add_ln_kernel<<<MROWS, 256, 0, stream>>>(xqf, tmp_b, ln1g + i * DM, ln1b + i * DM, x1_f, x1_b);
    gemm_bt<true, false, true><<<g512, 256, 0, stream>>>(
        x1_b, w1_b + i * DD, w1_b + i * DD, b1 + i * DM, b1 + i * DM,
        nullptr, ffn1_b, DM);
    gemm_bt<false, false, true><<<g512, 256, 0, stream>>>(
        ffn1_b, w2_b + i * DD, w2_b + i * DD, b2 + i * DM, b2 + i * DM,
        nullptr, tmp_b, DM);
    add_ln_kernel<<<MROWS, 256, 0, stream>>>(x1_f, tmp_b, ln2g + i * DM, ln2b + i * DM, outf, outb);
  };

  float* outx = (float*)d_out;
  layer(0, qa_embed, y_b, y_b, y_f, y_b, 0);
  layer(1, y_f, y_b, y_b, y_f, y_b, 0);
  layer(2, q_embed, x_b, x_b, x_f, x_b, 0);
  layer(3, x_f, x_b, y_b, x_f, x_b, 1);
  layer(4, x_f, x_b, x_b, x_f, x_b, 0);
  layer(5, x_f, x_b, y_b, outx, x_b, 1);
  balance_kernel<<<1, 64, 0, stream>>>(fP + 5 * 12, outx + (size_t)MROWS * DM);
}

// Round 4
// 1285.958 us; speedup vs baseline: 7.8973x; 1.0874x over previous
//
#include <hip/hip_runtime.h>
#include <cstdint>

// ---------------- constants ----------------
#define BSZ 32
#define SEQ 512
#define DM  512
#define NH  8
#define DK  64
#define HS_ 2
#define HD_ 6
#define NL  6
#define MROWS (BSZ*SEQ)          // 16384
#define QVLD 1024                // row stride of merged q|v buffer

typedef unsigned short bf16_t;
typedef __attribute__((ext_vector_type(4))) float f32x4;
typedef __attribute__((ext_vector_type(8))) short bf16x8;
typedef __attribute__((ext_vector_type(8))) unsigned short u16x8;

#define DEV static __device__ __forceinline__

DEV float bf2f(bf16_t b) {
  unsigned int u = ((unsigned int)b) << 16;
  float f; __builtin_memcpy(&f, &u, 4); return f;
}
DEV bf16_t f2b(float f) {  // RNE bf16 (finite inputs)
  unsigned int u; __builtin_memcpy(&u, &f, 4);
  unsigned int r = (u + 0x7fffu + ((u >> 16) & 1u)) >> 16;
  return (bf16_t)r;
}
DEV void unp2(unsigned int w, float& a, float& b) {
  unsigned int ua = w << 16, ub = w & 0xffff0000u;
  __builtin_memcpy(&a, &ua, 4); __builtin_memcpy(&b, &ub, 4);
}

DEV void gload_lds16(const bf16_t* g, bf16_t* l) {
  __builtin_amdgcn_global_load_lds(
      (const __attribute__((address_space(1))) void*)g,
      (__attribute__((address_space(3))) void*)l, 16, 0, 0);
}

// ---------------- f32 -> bf16 convert ----------------
__global__ __launch_bounds__(256) void f2b_kernel(const float* __restrict__ in,
                                                  bf16_t* __restrict__ out, int n4) {
  int i = blockIdx.x * 256 + threadIdx.x;
  int stride = gridDim.x * 256;
  for (; i < n4; i += stride) {
    float4 v = reinterpret_cast<const float4*>(in)[i];
    ushort4 o;
    o.x = f2b(v.x); o.y = f2b(v.y); o.z = f2b(v.z); o.w = f2b(v.w);
    reinterpret_cast<ushort4*>(out)[i] = o;
  }
}

// ---------------- MFMA GEMM: Y = A @ W^T + bias ----------------
// A [M,512] bf16. W split at N=512: rows [0,512) from W0, [512,...) from W1.
// grid (Ntiles, M/128). 128x128 tile, BK=32, 4 waves.
template <bool RELU, bool OUTF, bool OUTB>
__global__ __launch_bounds__(256) void gemm_bt(
    const bf16_t* __restrict__ A, const bf16_t* __restrict__ W0,
    const bf16_t* __restrict__ W1, const float* __restrict__ b0,
    const float* __restrict__ b1, float* __restrict__ Yf,
    bf16_t* __restrict__ Yb, int ldy) {
  const int K = 512;
  const int bn = blockIdx.x, bm = blockIdx.y;
  const int tid = threadIdx.x, wid = tid >> 6, lane = tid & 63;
  const int wr = wid >> 1, wc = wid & 1;   // 2x2 wave grid, 64x64 each
  __shared__ __align__(16) bf16_t As[128 * 32];
  __shared__ __align__(16) bf16_t Bs[128 * 32];

  const bool hi = (bn * 128) >= 512;
  const bf16_t* Wsel = hi ? (W1 - (size_t)512 * K) : W0;
  const float* bsel = hi ? (b1 - 512) : b0;

  f32x4 acc[4][4];
#pragma unroll
  for (int m = 0; m < 4; ++m)
#pragma unroll
    for (int n = 0; n < 4; ++n) acc[m][n] = f32x4{0.f, 0.f, 0.f, 0.f};

  const int lrow = lane & 15, lko = (lane >> 4) * 8;
  const size_t arow0 = (size_t)bm * 128, brow0 = (size_t)bn * 128;

  for (int k0 = 0; k0 < K; k0 += 32) {
#pragma unroll
    for (int i = 0; i < 2; ++i) {
      int e = (i * 256 + tid) * 8;           // element in [128][32]
      int r = e >> 5, c = e & 31;
      gload_lds16(A + (arow0 + r) * K + k0 + c, &As[(i * 4 + wid) * 512]);
      gload_lds16(Wsel + (brow0 + r) * K + k0 + c, &Bs[(i * 4 + wid) * 512]);
    }
    __syncthreads();
    bf16x8 af[4], bw[4];
#pragma unroll
    for (int m = 0; m < 4; ++m)
      af[m] = *reinterpret_cast<const bf16x8*>(&As[(wr * 64 + m * 16 + lrow) * 32 + lko]);
#pragma unroll
    for (int n = 0; n < 4; ++n)
      bw[n] = *reinterpret_cast<const bf16x8*>(&Bs[(wc * 64 + n * 16 + lrow) * 32 + lko]);
    __builtin_amdgcn_s_setprio(1);
#pragma unroll
    for (int m = 0; m < 4; ++m)
#pragma unroll
      for (int n = 0; n < 4; ++n)
        acc[m][n] = __builtin_amdgcn_mfma_f32_16x16x32_bf16(af[m], bw[n], acc[m][n], 0, 0, 0);
    __builtin_amdgcn_s_setprio(0);
    __syncthreads();
  }

  const int r0 = bm * 128 + wr * 64 + (lane >> 4) * 4;
  const int c0 = bn * 128 + wc * 64 + lrow;
#pragma unroll
  for (int n = 0; n < 4; ++n) {
    const int col = c0 + n * 16;
    const float bc = bsel[col];
#pragma unroll
    for (int m = 0; m < 4; ++m) {
#pragma unroll
      for (int j = 0; j < 4; ++j) {
        float v = acc[m][n][j] + bc;
        if (RELU) v = fmaxf(v, 0.f);
        const size_t off = (size_t)(r0 + m * 16 + j) * ldy + col;
        if (OUTF) Yf[off] = v;
        if (OUTB) Yb[off] = f2b(v);
      }
    }
  }
}

// ---------------- gating: softmax(q @ Wg^T), top-4-of-6, fused routing ----------------
// 64 tokens/block (4 waves x 16). Accumulates fP (f,Psum) and rdyn (routing mean) via atomics.
__global__ __launch_bounds__(256) void gates_kernel(
    const bf16_t* __restrict__ qv, const float* __restrict__ Wg,
    float* __restrict__ rdyn, float* __restrict__ fP) {
  __shared__ float wg_s[HD_ * DM];
  __shared__ float blk[4][18];
  const int tid = threadIdx.x, wid = tid >> 6, lane = tid & 63;
  for (int i = tid; i < HD_ * DM / 4; i += 256)
    reinterpret_cast<float4*>(wg_s)[i] = reinterpret_cast<const float4*>(Wg)[i];
  __syncthreads();
  const int bb = blockIdx.x >> 3;
  const int t0 = (blockIdx.x & 7) * 64 + wid * 16;
  float fs[6] = {0, 0, 0, 0, 0, 0}, ps[6] = {0, 0, 0, 0, 0, 0}, rs[6] = {0, 0, 0, 0, 0, 0};
  for (int it = 0; it < 16; ++it) {
    const int tok = bb * SEQ + t0 + it;
    uint4 u = reinterpret_cast<const uint4*>(qv + (size_t)tok * QVLD)[lane];
    float x[8];
    unp2(u.x, x[0], x[1]); unp2(u.y, x[2], x[3]);
    unp2(u.z, x[4], x[5]); unp2(u.w, x[6], x[7]);
    float g[6];
#pragma unroll
    for (int j = 0; j < 6; ++j) {
      float p = 0.f;
#pragma unroll
      for (int e = 0; e < 8; ++e) p = fmaf(x[e], wg_s[j * DM + lane * 8 + e], p);
#pragma unroll
      for (int off = 32; off; off >>= 1) p += __shfl_xor(p, off);
      g[j] = p;
    }
    float mx = g[0];
#pragma unroll
    for (int j = 1; j < 6; ++j) mx = fmaxf(mx, g[j]);
    float se = 0.f;
#pragma unroll
    for (int j = 0; j < 6; ++j) { g[j] = __expf(g[j] - mx); se += g[j]; }
    float inv = 1.f / se;
#pragma unroll
    for (int j = 0; j < 6; ++j) g[j] *= inv;
    int d1 = 0;
#pragma unroll
    for (int j = 1; j < 6; ++j)
      if (g[j] < g[d1] || (g[j] == g[d1] && j > d1)) d1 = j;
    int d2 = (d1 == 0) ? 1 : 0;
#pragma unroll
    for (int j = 0; j < 6; ++j) {
      if (j == d1) continue;
      if (g[j] < g[d2] || (g[j] == g[d2] && j > d2)) d2 = j;
    }
#pragma unroll
    for (int j = 0; j < 6; ++j) {
      const bool drop = (j == d1) || (j == d2);
      fs[j] += drop ? 0.f : 1.f;
      ps[j] += g[j];
      rs[j] += drop ? 0.f : g[j];
    }
  }
  if (lane == 0) {
#pragma unroll
    for (int j = 0; j < 6; ++j) {
      blk[wid][j] = fs[j]; blk[wid][6 + j] = ps[j]; blk[wid][12 + j] = rs[j];
    }
  }
  __syncthreads();
  if (tid < 18) {
    float s = blk[0][tid] + blk[1][tid] + blk[2][tid] + blk[3][tid];
    if (tid < 12) atomicAdd(&fP[tid], s);
    else atomicAdd(&rdyn[bb * 6 + (tid - 12)], s * (1.f / 512.f));
  }
}

// ---------------- row-0 quirk: ctx[b,0,h,:] = factor * mean_k V ----------------
__global__ __launch_bounds__(256) void rowzero_kernel(
    const bf16_t* __restrict__ qv, const float* __restrict__ rdyn,
    bf16_t* __restrict__ ctx) {
  const int h = blockIdx.x, b = blockIdx.y;
  const int tid = threadIdx.x;
  const int c8 = tid & 7;        // col block (8 elems)
  const int rc = tid >> 3;       // row chunk 0..31 (16 rows each)
  const bf16_t* vb = qv + 512 + ((size_t)(b * SEQ)) * QVLD + h * DK + c8 * 8;
  float s[8] = {0, 0, 0, 0, 0, 0, 0, 0};
  for (int i = 0; i < 16; ++i) {
    u16x8 vv = *reinterpret_cast<const u16x8*>(vb + (size_t)(rc * 16 + i) * QVLD);
#pragma unroll
    for (int e = 0; e < 8; ++e) s[e] += bf2f(vv[e]);
  }
  __shared__ float red[64][33];
#pragma unroll
  for (int e = 0; e < 8; ++e) red[c8 * 8 + e][rc] = s[e];
  __syncthreads();
  if (tid < 64) {
    float t = 0.f;
#pragma unroll
    for (int c = 0; c < 32; ++c) t += red[tid][c];
    const float factor = (h < HS_) ? 1.f : rdyn[b * 6 + (h - HS_)];
    ctx[((size_t)(b * SEQ)) * DM + h * DK + tid] = f2b(t * (1.f / 512.f) * factor);
  }
}

// ---------------- fused flash attention (MFMA) ----------------
// grid (2, h, b), 256 thr. Block bx does q-tiles {bx, 3-bx} (balanced: 10 k-tiles each).
// Wave w: 32 q-rows of the current q-tile. K-tile=64 keys.
// Swapped QK^T: mfma(A=K, B=Q) -> lane owns one q-row's scores.
__global__ __launch_bounds__(256) void fattn_kernel(
    const bf16_t* __restrict__ qv, const float* __restrict__ rdyn,
    bf16_t* __restrict__ ctx, int strict) {
  const int bx = blockIdx.x, h = blockIdx.y, b = blockIdx.z;
  const int tid = threadIdx.x, wid = tid >> 6, lane = tid & 63;
  const int c0 = lane & 15, grp = lane >> 4;
  const int l3 = lane >> 3, c3 = lane & 7;
  const int kidx = lane & 31, dhalf = lane >> 5;

  __shared__ __align__(16) bf16_t Ks[64 * 64];        // swizzled [64k][64ch]
  __shared__ __align__(16) bf16_t Vt[64 * 72];        // transposed [64d][64k+8pad]
  __shared__ __align__(16) bf16_t Ps[4][32 * 64];     // per-wave P, swizzled

  const bf16_t* qp = qv;          // q half, row stride QVLD
  const bf16_t* vp = qv + 512;    // v half
  const float factor = (h < HS_) ? 1.f : rdyn[b * 6 + (h - HS_)];

  for (int ph = 0; ph < 2; ++ph) {
    const int qt = ph ? 3 - bx : bx;
    const int qbase = qt * 128 + wid * 32;

    // Q fragments (B-operand): row = q, k = channel
    bf16x8 qf[2][2];
#pragma unroll
    for (int nt = 0; nt < 2; ++nt)
#pragma unroll
      for (int ks = 0; ks < 2; ++ks)
        qf[nt][ks] = *reinterpret_cast<const bf16x8*>(
            qp + ((size_t)(b * SEQ + qbase + nt * 16 + c0)) * QVLD + h * DK + ks * 32 + grp * 8);

    f32x4 acc[2][4];
#pragma unroll
    for (int m = 0; m < 2; ++m)
#pragma unroll
      for (int d = 0; d < 4; ++d) acc[m][d] = f32x4{0.f, 0.f, 0.f, 0.f};
    float mreg[2] = {-3e38f, -3e38f};
    float lreg[2] = {0.f, 0.f};

    const int lastk = (qbase + 31 - strict) >> 6;   // last tile this wave needs
    const int ktmax = 2 * qt + 1;                   // last tile any wave needs

    for (int kt = 0; kt <= ktmax; ++kt) {
      // ---- stage K tile via global_load_lds, source pre-swizzled ----
#pragma unroll
      for (int i = 0; i < 2; ++i) {
        int row = i * 32 + wid * 8 + l3;
        int blk = c3 ^ l3;
        gload_lds16(qp + ((size_t)(b * SEQ + kt * 64 + row)) * QVLD + h * DK + blk * 8,
                    Ks + (i * 32 + wid * 8) * 64);
      }
      // ---- stage V transposed: lane owns 2 kk-cols x 4 d-rows, 4B writes ----
      // bank = (16*dhalf + kidx + 36e) mod 32 -> 2-way (free)
#pragma unroll
      for (int j = 0; j < 2; ++j) {
        const int p = wid * 2 + j;
        const int d0 = p * 8 + dhalf * 4;
        const bf16_t* src = vp + ((size_t)(b * SEQ + kt * 64 + 2 * kidx)) * QVLD + h * DK + d0;
        ushort4 lo = *reinterpret_cast<const ushort4*>(src);
        ushort4 hv = *reinterpret_cast<const ushort4*>(src + QVLD);
        *reinterpret_cast<unsigned*>(&Vt[(d0 + 0) * 72 + 2 * kidx]) = (unsigned)lo.x | ((unsigned)hv.x << 16);
        *reinterpret_cast<unsigned*>(&Vt[(d0 + 1) * 72 + 2 * kidx]) = (unsigned)lo.y | ((unsigned)hv.y << 16);
        *reinterpret_cast<unsigned*>(&Vt[(d0 + 2) * 72 + 2 * kidx]) = (unsigned)lo.z | ((unsigned)hv.z << 16);
        *reinterpret_cast<unsigned*>(&Vt[(d0 + 3) * 72 + 2 * kidx]) = (unsigned)lo.w | ((unsigned)hv.w << 16);
      }
      __syncthreads();

      if (kt <= lastk) {
        // ---- QK^T (swapped) ----
        const char* KsB = (const char*)Ks;
        bf16x8 kf[4][2];
#pragma unroll
        for (int mt = 0; mt < 4; ++mt)
#pragma unroll
          for (int ks = 0; ks < 2; ++ks)
            kf[mt][ks] = *reinterpret_cast<const bf16x8*>(
                KsB + (mt * 16 + c0) * 128 + 16 * ((4 * ks + grp) ^ (c0 & 7)));
        f32x4 s[4][2];
#pragma unroll
        for (int mt = 0; mt < 4; ++mt)
#pragma unroll
          for (int nt = 0; nt < 2; ++nt) s[mt][nt] = f32x4{0.f, 0.f, 0.f, 0.f};
        __builtin_amdgcn_s_setprio(1);
#pragma unroll
        for (int mt = 0; mt < 4; ++mt)
#pragma unroll
          for (int nt = 0; nt < 2; ++nt)
#pragma unroll
            for (int ks = 0; ks < 2; ++ks)
              s[mt][nt] = __builtin_amdgcn_mfma_f32_16x16x32_bf16(
                  kf[mt][ks], qf[nt][ks], s[mt][nt], 0, 0, 0);
        __builtin_amdgcn_s_setprio(0);

        const bool masked = (kt == lastk);
        float sc[2];
#pragma unroll
        for (int nt = 0; nt < 2; ++nt) {
          const int q = qbase + nt * 16 + c0;
#pragma unroll
          for (int mt = 0; mt < 4; ++mt)
#pragma unroll
            for (int j = 0; j < 4; ++j) {
              int k = kt * 64 + mt * 16 + grp * 4 + j;
              float t = s[mt][nt][j] * 0.125f;
              if (masked && (k + strict > q)) t = -1e30f;
              s[mt][nt][j] = t;
            }
          float mx = -3e38f;
#pragma unroll
          for (int mt = 0; mt < 4; ++mt)
#pragma unroll
            for (int j = 0; j < 4; ++j) mx = fmaxf(mx, s[mt][nt][j]);
          mx = fmaxf(mx, __shfl_xor(mx, 16));
          mx = fmaxf(mx, __shfl_xor(mx, 32));
          const float mnew = fmaxf(mreg[nt], mx);
          sc[nt] = __expf(mreg[nt] - mnew);
          mreg[nt] = mnew;
          float ts = 0.f;
#pragma unroll
          for (int mt = 0; mt < 4; ++mt)
#pragma unroll
            for (int j = 0; j < 4; ++j) {
              float pp = __expf(s[mt][nt][j] - mnew);
              s[mt][nt][j] = pp; ts += pp;
            }
          ts += __shfl_xor(ts, 16);
          ts += __shfl_xor(ts, 32);
          lreg[nt] = lreg[nt] * sc[nt] + ts;
        }
        // ---- P -> bf16 -> per-wave LDS (swizzled) ----
        char* PsB = (char*)(&Ps[wid][0]);
#pragma unroll
        for (int nt = 0; nt < 2; ++nt)
#pragma unroll
          for (int mt = 0; mt < 4; ++mt) {
            uint2 w;
            w.x = (unsigned)f2b(s[mt][nt][0]) | ((unsigned)f2b(s[mt][nt][1]) << 16);
            w.y = (unsigned)f2b(s[mt][nt][2]) | ((unsigned)f2b(s[mt][nt][3]) << 16);
            int row = nt * 16 + c0;
            int off = (row * 128 + mt * 32 + grp * 8) ^ ((c0 & 7) << 4);
            *reinterpret_cast<uint2*>(PsB + off) = w;
          }
        // ---- online rescale of ctx ----
#pragma unroll
        for (int mtq = 0; mtq < 2; ++mtq) {
          f32x4 sv;
#pragma unroll
          for (int j = 0; j < 4; ++j) sv[j] = __shfl(sc[mtq], grp * 4 + j);
#pragma unroll
          for (int dt = 0; dt < 4; ++dt) acc[mtq][dt] *= sv;
        }
        // ---- PV ----
        bf16x8 pf[2][2], vf2[4][2];
#pragma unroll
        for (int mtq = 0; mtq < 2; ++mtq)
#pragma unroll
          for (int ks = 0; ks < 2; ++ks)
            pf[mtq][ks] = *reinterpret_cast<const bf16x8*>(
                PsB + (mtq * 16 + c0) * 128 + 16 * ((4 * ks + grp) ^ (c0 & 7)));
#pragma unroll
        for (int dt = 0; dt < 4; ++dt)
#pragma unroll
          for (int ks = 0; ks < 2; ++ks)
            vf2[dt][ks] = *reinterpret_cast<const bf16x8*>(
                (const char*)Vt + (dt * 16 + c0) * 144 + ks * 64 + grp * 16);
        __builtin_amdgcn_s_setprio(1);
#pragma unroll
        for (int mtq = 0; mtq < 2; ++mtq)
#pragma unroll
          for (int dt = 0; dt < 4; ++dt)
#pragma unroll
            for (int ks = 0; ks < 2; ++ks)
              acc[mtq][dt] = __builtin_amdgcn_mfma_f32_16x16x32_bf16(
                  pf[mtq][ks], vf2[dt][ks], acc[mtq][dt], 0, 0, 0);
        __builtin_amdgcn_s_setprio(0);
      }
      __syncthreads();
    }

    // ---- epilogue: /l, *routing, store (skip q==0) ----
#pragma unroll
    for (int mtq = 0; mtq < 2; ++mtq) {
      const float inv = factor / lreg[mtq];
      f32x4 iv;
#pragma unroll
      for (int j = 0; j < 4; ++j) iv[j] = __shfl(inv, grp * 4 + j);
#pragma unroll
      for (int j = 0; j < 4; ++j) {
        const int q = qbase + mtq * 16 + grp * 4 + j;
        if (q == 0) continue;
#pragma unroll
        for (int dt = 0; dt < 4; ++dt)
          ctx[((size_t)(b * SEQ + q)) * DM + h * DK + dt * 16 + c0] =
              f2b(acc[mtq][dt][j] * iv[j]);
      }
    }
  }
}

// ---------------- add + layernorm (residual f32, delta bf16) ----------------
__global__ __launch_bounds__(256) void add_ln_kernel(
    const float* __restrict__ X, const bf16_t* __restrict__ A2,
    const float* __restrict__ gam, const float* __restrict__ bet,
    float* __restrict__ outf, bf16_t* __restrict__ outb) {
  const int row = blockIdx.x, tid = threadIdx.x, wid = tid >> 6, lane = tid & 63;
  const size_t base = (size_t)row * DM;
  float2 xv = *reinterpret_cast<const float2*>(X + base + 2 * tid);
  float a0, a1;
  unp2(*reinterpret_cast<const unsigned*>(A2 + base + 2 * tid), a0, a1);
  float z0 = xv.x + a0, z1 = xv.y + a1;
  __shared__ float red[4];
  float s = z0 + z1;
#pragma unroll
  for (int off = 32; off; off >>= 1) s += __shfl_xor(s, off);
  if (lane == 0) red[wid] = s;
  __syncthreads();
  const float mean = (red[0] + red[1] + red[2] + red[3]) * (1.f / 512.f);
  __syncthreads();
  const float d0 = z0 - mean, d1 = z1 - mean;
  float ss = d0 * d0 + d1 * d1;
#pragma unroll
  for (int off = 32; off; off >>= 1) ss += __shfl_xor(ss, off);
  if (lane == 0) red[wid] = ss;
  __syncthreads();
  const float var = (red[0] + red[1] + red[2] + red[3]) * (1.f / 512.f);
  const float inv = rsqrtf(var + 1e-5f);
  const float2 gv = *reinterpret_cast<const float2*>(gam + 2 * tid);
  const float2 bv = *reinterpret_cast<const float2*>(bet + 2 * tid);
  const float o0 = d0 * inv * gv.x + bv.x;
  const float o1 = d1 * inv * gv.y + bv.y;
  float2 of; of.x = o0; of.y = o1;
  *reinterpret_cast<float2*>(outf + base + 2 * tid) = of;
  *reinterpret_cast<unsigned*>(outb + base + 2 * tid) =
      (unsigned)f2b(o0) | ((unsigned)f2b(o1) << 16);
}

// ---------------- balance ----------------
__global__ void balance_kernel(const float* __restrict__ fP, float* __restrict__ out) {
  if (threadIdx.x == 0 && blockIdx.x == 0) {
    float fs = 0.f, pssum = 0.f, P[6];
    for (int j = 0; j < 6; ++j) {
      fs += fP[j];
      P[j] = fP[6 + j] * (1.f / (float)MROWS);
      pssum += P[j];
    }
    float bal = 0.f;
    for (int j = 0; j < 6; ++j)
      bal += (fP[j] / (fs + 1e-5f)) * (P[j] / (pssum + 1e-5f));
    out[0] = bal;
  }
}

// ---------------- host ----------------
extern "C" void kernel_launch(void* const* d_in, const int* in_sizes, int n_in,
                              void* d_out, int out_size, void* d_ws, size_t ws_size,
                              hipStream_t stream) {
  (void)in_sizes; (void)n_in; (void)out_size; (void)ws_size;
  const float* q_embed  = (const float*)d_in[0];
  const float* qa_embed = (const float*)d_in[1];
  const float* Wq  = (const float*)d_in[2];
  const float* bq  = (const float*)d_in[3];
  const float* Wv  = (const float*)d_in[4];
  const float* bv  = (const float*)d_in[5];
  const float* Wg  = (const float*)d_in[6];
  const float* Wo  = (const float*)d_in[7];
  const float* bo  = (const float*)d_in[8];
  const float* ln1g = (const float*)d_in[9];
  const float* ln1b = (const float*)d_in[10];
  const float* W1  = (const float*)d_in[11];
  const float* b1  = (const float*)d_in[12];
  const float* W2  = (const float*)d_in[13];
  const float* b2  = (const float*)d_in[14];
  const float* ln2g = (const float*)d_in[15];
  const float* ln2b = (const float*)d_in[16];

  char* p = (char*)d_ws;
  auto alloc = [&](size_t bytes) -> char* {
    char* r = p; p += (bytes + 255) & ~(size_t)255; return r;
  };
  const size_t WDE = (size_t)NL * DM * DM;   // stacked weight elems
  const size_t AE  = (size_t)MROWS * DM;     // activation elems
  bf16_t* wq_b = (bf16_t*)alloc(WDE * 2);
  bf16_t* wv_b = (bf16_t*)alloc(WDE * 2);
  bf16_t* wo_b = (bf16_t*)alloc(WDE * 2);
  bf16_t* w1_b = (bf16_t*)alloc(WDE * 2);
  bf16_t* w2_b = (bf16_t*)alloc(WDE * 2);
  float* y_f   = (float*)alloc(AE * 4);
  float* x_f   = (float*)alloc(AE * 4);
  float* x1_f  = (float*)alloc(AE * 4);
  bf16_t* y_b   = (bf16_t*)alloc(AE * 2);
  bf16_t* x_b   = (bf16_t*)alloc(AE * 2);
  bf16_t* qv_b  = (bf16_t*)alloc((size_t)MROWS * QVLD * 2);  // q|v merged
  bf16_t* ctx_b = (bf16_t*)alloc(AE * 2);
  bf16_t* x1_b  = (bf16_t*)alloc(AE * 2);
  bf16_t* tmp_b = (bf16_t*)alloc(AE * 2);
  bf16_t* ffn1_b = (bf16_t*)alloc(AE * 2);
  float* rdyn = (float*)alloc(BSZ * 6 * 4);
  float* fP   = (float*)alloc(NL * 12 * 4);

  hipMemsetAsync(fP, 0, NL * 12 * 4, stream);

  // weights -> bf16
  f2b_kernel<<<1536, 256, 0, stream>>>(Wq, wq_b, (int)(WDE / 4));
  f2b_kernel<<<1536, 256, 0, stream>>>(Wv, wv_b, (int)(WDE / 4));
  f2b_kernel<<<1536, 256, 0, stream>>>(Wo, wo_b, (int)(WDE / 4));
  f2b_kernel<<<1536, 256, 0, stream>>>(W1, w1_b, (int)(WDE / 4));
  f2b_kernel<<<1536, 256, 0, stream>>>(W2, w2_b, (int)(WDE / 4));
  // initial activations -> bf16
  f2b_kernel<<<2048, 256, 0, stream>>>(qa_embed, y_b, (int)(AE / 4));
  f2b_kernel<<<2048, 256, 0, stream>>>(q_embed, x_b, (int)(AE / 4));

  const size_t DD = (size_t)DM * DM;
  dim3 g512(4, 128), g1024(8, 128);

  auto layer = [&](int i, const float* xqf, const bf16_t* xqb, const bf16_t* xvb,
                   float* outf, bf16_t* outb, int strict) {
    hipMemsetAsync(rdyn, 0, BSZ * 6 * 4, stream);
    if (xqb == xvb) {
      // merged q|v projection: N=1024
      gemm_bt<false, false, true><<<g1024, 256, 0, stream>>>(
          xqb, wq_b + i * DD, wv_b + i * DD, bq + i * DM, bv + i * DM,
          nullptr, qv_b, QVLD);
    } else {
      gemm_bt<false, false, true><<<g512, 256, 0, stream>>>(
          xqb, wq_b + i * DD, wq_b + i * DD, bq + i * DM, bq + i * DM,
          nullptr, qv_b, QVLD);
      gemm_bt<false, false, true><<<g512, 256, 0, stream>>>(
          xvb, wv_b + i * DD, wv_b + i * DD, bv + i * DM, bv + i * DM,
          nullptr, qv_b + 512, QVLD);
    }
    gates_kernel<<<MROWS / 64, 256, 0, stream>>>(qv_b, Wg + (size_t)i * HD_ * DM, rdyn, fP + i * 12);
    rowzero_kernel<<<dim3(NH, BSZ), 256, 0, stream>>>(qv_b, rdyn, ctx_b);
    fattn_kernel<<<dim3(2, NH, BSZ), 256, 0, stream>>>(qv_b, rdyn, ctx_b, strict);
    gemm_bt<false, false, true><<<g512, 256, 0, stream>>>(
        ctx_b, wo_b + i * DD, wo_b + i * DD, bo + i * DM, bo + i * DM,
        nullptr, tmp_b, DM);
    add_ln_kernel<<<MROWS, 256, 0, stream>>>(xqf, tmp_b, ln1g + i * DM, ln1b + i * DM, x1_f, x1_b);
    gemm_bt<true, false, true><<<g512, 256, 0, stream>>>(
        x1_b, w1_b + i * DD, w1_b + i * DD, b1 + i * DM, b1 + i * DM,
        nullptr, ffn1_b, DM);
    gemm_bt<false, false, true><<<g512, 256, 0, stream>>>(
        ffn1_b, w2_b + i * DD, w2_b + i * DD, b2 + i * DM, b2 + i * DM,
        nullptr, tmp_b, DM);
    add_ln_kernel<<<MROWS, 256, 0, stream>>>(x1_f, tmp_b, ln2g + i * DM, ln2b + i * DM, outf, outb);
  };

  float* outx = (float*)d_out;
  layer(0, qa_embed, y_b, y_b, y_f, y_b, 0);
  layer(1, y_f, y_b, y_b, y_f, y_b, 0);
  layer(2, q_embed, x_b, x_b, x_f, x_b, 0);
  layer(3, x_f, x_b, y_b, x_f, x_b, 1);
  layer(4, x_f, x_b, x_b, x_f, x_b, 0);
  layer(5, x_f, x_b, y_b, outx, x_b, 1);
  balance_kernel<<<1, 64, 0, stream>>>(fP + 5 * 12, outx + (size_t)MROWS * DM);
}

// Round 5
// 1260.794 us; speedup vs baseline: 8.0549x; 1.0200x over previous
//
#include <hip/hip_runtime.h>
#include <cstdint>

// ---------------- constants ----------------
#define BSZ 32
#define SEQ 512
#define DM  512
#define NH  8
#define DK  64
#define HS_ 2
#define HD_ 6
#define NL  6
#define MROWS (BSZ*SEQ)          // 16384
#define QVLD 1024                // row stride of merged q|v buffer

typedef unsigned short bf16_t;
typedef __attribute__((ext_vector_type(4))) float f32x4;
typedef __attribute__((ext_vector_type(8))) short bf16x8;
typedef __attribute__((ext_vector_type(8))) unsigned short u16x8;

#define DEV static __device__ __forceinline__

DEV float bf2f(bf16_t b) {
  unsigned int u = ((unsigned int)b) << 16;
  float f; __builtin_memcpy(&f, &u, 4); return f;
}
DEV bf16_t f2b(float f) {  // RNE bf16 (finite inputs)
  unsigned int u; __builtin_memcpy(&u, &f, 4);
  unsigned int r = (u + 0x7fffu + ((u >> 16) & 1u)) >> 16;
  return (bf16_t)r;
}
DEV void unp2(unsigned int w, float& a, float& b) {
  unsigned int ua = w << 16, ub = w & 0xffff0000u;
  __builtin_memcpy(&a, &ua, 4); __builtin_memcpy(&b, &ub, 4);
}

DEV void gload_lds16(const bf16_t* g, bf16_t* l) {
  __builtin_amdgcn_global_load_lds(
      (const __attribute__((address_space(1))) void*)g,
      (__attribute__((address_space(3))) void*)l, 16, 0, 0);
}

// ---------------- f32 -> bf16 converts ----------------
__global__ __launch_bounds__(256) void f2b_kernel(const float* __restrict__ in,
                                                  bf16_t* __restrict__ out, int n4) {
  int i = blockIdx.x * 256 + threadIdx.x;
  int stride = gridDim.x * 256;
  for (; i < n4; i += stride) {
    float4 v = reinterpret_cast<const float4*>(in)[i];
    ushort4 o;
    o.x = f2b(v.x); o.y = f2b(v.y); o.z = f2b(v.z); o.w = f2b(v.w);
    reinterpret_cast<ushort4*>(out)[i] = o;
  }
}

// 5 stacked weight tensors -> one contiguous bf16 arena. grid (1536, 5), 1 iter.
__global__ __launch_bounds__(256) void f2bw_kernel(
    const float* __restrict__ s0, const float* __restrict__ s1,
    const float* __restrict__ s2, const float* __restrict__ s3,
    const float* __restrict__ s4, bf16_t* __restrict__ dst) {
  const float* srcs[5] = {s0, s1, s2, s3, s4};
  const float* s = srcs[blockIdx.y];
  bf16_t* d = dst + (size_t)blockIdx.y * ((size_t)NL * DM * DM);
  const int i = blockIdx.x * 256 + threadIdx.x;
  float4 v = reinterpret_cast<const float4*>(s)[i];
  ushort4 o;
  o.x = f2b(v.x); o.y = f2b(v.y); o.z = f2b(v.z); o.w = f2b(v.w);
  reinterpret_cast<ushort4*>(d)[i] = o;
}

// ---------------- MFMA GEMM (128x128 tile, BK=64): qv projection ----------------
// Y[:, 0:512) = A0 @ W0^T + b0 ; Y[:, 512:1024) = A1 @ W1^T + b1. Output bf16, ldy=1024.
__global__ __launch_bounds__(256) void gemm_qv(
    const bf16_t* __restrict__ A0, const bf16_t* __restrict__ A1,
    const bf16_t* __restrict__ W0, const bf16_t* __restrict__ W1,
    const float* __restrict__ b0, const float* __restrict__ b1,
    bf16_t* __restrict__ Yb) {
  const int K = 512;
  const int bn = blockIdx.x, bm = blockIdx.y;
  const int tid = threadIdx.x, wid = tid >> 6, lane = tid & 63;
  const int wr = wid >> 1, wc = wid & 1;   // 2x2 wave grid, 64x64 each
  __shared__ __align__(16) bf16_t As[128 * 64];
  __shared__ __align__(16) bf16_t Bs[128 * 64];

  const bool hi = bn >= 4;
  const bf16_t* Asel = hi ? A1 : A0;
  const bf16_t* Wsel = hi ? (W1 - (size_t)512 * K) : W0;
  const float* bsel = hi ? (b1 - 512) : b0;

  f32x4 acc[4][4];
#pragma unroll
  for (int m = 0; m < 4; ++m)
#pragma unroll
    for (int n = 0; n < 4; ++n) acc[m][n] = f32x4{0.f, 0.f, 0.f, 0.f};

  const int lrow = lane & 15, lko = (lane >> 4) * 8;
  const int sr = wid * 8 + (lane >> 3), scol = (lane & 7) * 8;  // staging row/col
  const size_t arow0 = (size_t)bm * 128, brow0 = (size_t)bn * 128;

  for (int k0 = 0; k0 < K; k0 += 64) {
#pragma unroll
    for (int i = 0; i < 4; ++i) {
      gload_lds16(Asel + (arow0 + i * 32 + sr) * K + k0 + scol, &As[(i * 4 + wid) * 512]);
      gload_lds16(Wsel + (brow0 + i * 32 + sr) * K + k0 + scol, &Bs[(i * 4 + wid) * 512]);
    }
    __syncthreads();
    bf16x8 af[4][2], bw[4][2];
#pragma unroll
    for (int m = 0; m < 4; ++m)
#pragma unroll
      for (int ks = 0; ks < 2; ++ks)
        af[m][ks] = *reinterpret_cast<const bf16x8*>(
            &As[(wr * 64 + m * 16 + lrow) * 64 + ks * 32 + lko]);
#pragma unroll
    for (int n = 0; n < 4; ++n)
#pragma unroll
      for (int ks = 0; ks < 2; ++ks)
        bw[n][ks] = *reinterpret_cast<const bf16x8*>(
            &Bs[(wc * 64 + n * 16 + lrow) * 64 + ks * 32 + lko]);
    __builtin_amdgcn_s_setprio(1);
#pragma unroll
    for (int ks = 0; ks < 2; ++ks)
#pragma unroll
      for (int m = 0; m < 4; ++m)
#pragma unroll
        for (int n = 0; n < 4; ++n)
          acc[m][n] = __builtin_amdgcn_mfma_f32_16x16x32_bf16(af[m][ks], bw[n][ks], acc[m][n], 0, 0, 0);
    __builtin_amdgcn_s_setprio(0);
    __syncthreads();
  }

  const int r0 = bm * 128 + wr * 64 + (lane >> 4) * 4;
  const int c0 = bn * 128 + wc * 64 + lrow;
#pragma unroll
  for (int n = 0; n < 4; ++n) {
    const int col = c0 + n * 16;
    const float bc = bsel[col];
#pragma unroll
    for (int m = 0; m < 4; ++m)
#pragma unroll
      for (int j = 0; j < 4; ++j)
        Yb[(size_t)(r0 + m * 16 + j) * QVLD + col] = f2b(acc[m][n][j] + bc);
  }
}

// ---------------- MFMA GEMM (64x128 tile, BK=64): N=512, bf16 out ----------------
// grid (4, 256). 4 waves 2x2, each 32x64.
template <bool RELU>
__global__ __launch_bounds__(256) void gemm_n512(
    const bf16_t* __restrict__ A, const bf16_t* __restrict__ W,
    const float* __restrict__ bias, bf16_t* __restrict__ Yb) {
  const int K = 512;
  const int bn = blockIdx.x, bm = blockIdx.y;
  const int tid = threadIdx.x, wid = tid >> 6, lane = tid & 63;
  const int wr = wid >> 1, wc = wid & 1;   // 2x2 wave grid, 32x64 each
  __shared__ __align__(16) bf16_t As[64 * 64];
  __shared__ __align__(16) bf16_t Bs[128 * 64];

  f32x4 acc[2][4];
#pragma unroll
  for (int m = 0; m < 2; ++m)
#pragma unroll
    for (int n = 0; n < 4; ++n) acc[m][n] = f32x4{0.f, 0.f, 0.f, 0.f};

  const int lrow = lane & 15, lko = (lane >> 4) * 8;
  const int sr = wid * 8 + (lane >> 3), scol = (lane & 7) * 8;
  const size_t arow0 = (size_t)bm * 64, brow0 = (size_t)bn * 128;

  for (int k0 = 0; k0 < K; k0 += 64) {
#pragma unroll
    for (int i = 0; i < 2; ++i)
      gload_lds16(A + (arow0 + i * 32 + sr) * K + k0 + scol, &As[(i * 4 + wid) * 512]);
#pragma unroll
    for (int i = 0; i < 4; ++i)
      gload_lds16(W + (brow0 + i * 32 + sr) * K + k0 + scol, &Bs[(i * 4 + wid) * 512]);
    __syncthreads();
    bf16x8 af[2][2], bw[4][2];
#pragma unroll
    for (int m = 0; m < 2; ++m)
#pragma unroll
      for (int ks = 0; ks < 2; ++ks)
        af[m][ks] = *reinterpret_cast<const bf16x8*>(
            &As[(wr * 32 + m * 16 + lrow) * 64 + ks * 32 + lko]);
#pragma unroll
    for (int n = 0; n < 4; ++n)
#pragma unroll
      for (int ks = 0; ks < 2; ++ks)
        bw[n][ks] = *reinterpret_cast<const bf16x8*>(
            &Bs[(wc * 64 + n * 16 + lrow) * 64 + ks * 32 + lko]);
    __builtin_amdgcn_s_setprio(1);
#pragma unroll
    for (int ks = 0; ks < 2; ++ks)
#pragma unroll
      for (int m = 0; m < 2; ++m)
#pragma unroll
        for (int n = 0; n < 4; ++n)
          acc[m][n] = __builtin_amdgcn_mfma_f32_16x16x32_bf16(af[m][ks], bw[n][ks], acc[m][n], 0, 0, 0);
    __builtin_amdgcn_s_setprio(0);
    __syncthreads();
  }

  const int r0 = bm * 64 + wr * 32 + (lane >> 4) * 4;
  const int c0 = bn * 128 + wc * 64 + lrow;
#pragma unroll
  for (int n = 0; n < 4; ++n) {
    const int col = c0 + n * 16;
    const float bc = bias[col];
#pragma unroll
    for (int m = 0; m < 2; ++m)
#pragma unroll
      for (int j = 0; j < 4; ++j) {
        float v = acc[m][n][j] + bc;
        if (RELU) v = fmaxf(v, 0.f);
        Yb[(size_t)(r0 + m * 16 + j) * DM + col] = f2b(v);
      }
  }
}

// ---------------- gating: softmax(q @ Wg^T), top-4-of-6, fused routing ----------------
__global__ __launch_bounds__(256) void gates_kernel(
    const bf16_t* __restrict__ qv, const float* __restrict__ Wg,
    float* __restrict__ rdyn, float* __restrict__ fP) {
  __shared__ float wg_s[HD_ * DM];
  __shared__ float blk[4][18];
  const int tid = threadIdx.x, wid = tid >> 6, lane = tid & 63;
  for (int i = tid; i < HD_ * DM / 4; i += 256)
    reinterpret_cast<float4*>(wg_s)[i] = reinterpret_cast<const float4*>(Wg)[i];
  __syncthreads();
  const int bb = blockIdx.x >> 3;
  const int t0 = (blockIdx.x & 7) * 64 + wid * 16;
  float fs[6] = {0, 0, 0, 0, 0, 0}, ps[6] = {0, 0, 0, 0, 0, 0}, rs[6] = {0, 0, 0, 0, 0, 0};
  for (int it = 0; it < 16; ++it) {
    const int tok = bb * SEQ + t0 + it;
    uint4 u = reinterpret_cast<const uint4*>(qv + (size_t)tok * QVLD)[lane];
    float x[8];
    unp2(u.x, x[0], x[1]); unp2(u.y, x[2], x[3]);
    unp2(u.z, x[4], x[5]); unp2(u.w, x[6], x[7]);
    float g[6];
#pragma unroll
    for (int j = 0; j < 6; ++j) {
      float p = 0.f;
#pragma unroll
      for (int e = 0; e < 8; ++e) p = fmaf(x[e], wg_s[j * DM + lane * 8 + e], p);
#pragma unroll
      for (int off = 32; off; off >>= 1) p += __shfl_xor(p, off);
      g[j] = p;
    }
    float mx = g[0];
#pragma unroll
    for (int j = 1; j < 6; ++j) mx = fmaxf(mx, g[j]);
    float se = 0.f;
#pragma unroll
    for (int j = 0; j < 6; ++j) { g[j] = __expf(g[j] - mx); se += g[j]; }
    float inv = 1.f / se;
#pragma unroll
    for (int j = 0; j < 6; ++j) g[j] *= inv;
    int d1 = 0;
#pragma unroll
    for (int j = 1; j < 6; ++j)
      if (g[j] < g[d1] || (g[j] == g[d1] && j > d1)) d1 = j;
    int d2 = (d1 == 0) ? 1 : 0;
#pragma unroll
    for (int j = 0; j < 6; ++j) {
      if (j == d1) continue;
      if (g[j] < g[d2] || (g[j] == g[d2] && j > d2)) d2 = j;
    }
#pragma unroll
    for (int j = 0; j < 6; ++j) {
      const bool drop = (j == d1) || (j == d2);
      fs[j] += drop ? 0.f : 1.f;
      ps[j] += g[j];
      rs[j] += drop ? 0.f : g[j];
    }
  }
  if (lane == 0) {
#pragma unroll
    for (int j = 0; j < 6; ++j) {
      blk[wid][j] = fs[j]; blk[wid][6 + j] = ps[j]; blk[wid][12 + j] = rs[j];
    }
  }
  __syncthreads();
  if (tid < 18) {
    float s = blk[0][tid] + blk[1][tid] + blk[2][tid] + blk[3][tid];
    if (tid < 12) atomicAdd(&fP[tid], s);
    else atomicAdd(&rdyn[bb * 6 + (tid - 12)], s * (1.f / 512.f));
  }
}

// ---------------- row-0 quirk: ctx[b,0,h,:] = factor * mean_k V ----------------
__global__ __launch_bounds__(256) void rowzero_kernel(
    const bf16_t* __restrict__ qv, const float* __restrict__ rdyn,
    bf16_t* __restrict__ ctx) {
  const int h = blockIdx.x, b = blockIdx.y;
  const int tid = threadIdx.x;
  const int c8 = tid & 7;        // col block (8 elems)
  const int rc = tid >> 3;       // row chunk 0..31 (16 rows each)
  const bf16_t* vb = qv + 512 + ((size_t)(b * SEQ)) * QVLD + h * DK + c8 * 8;
  float s[8] = {0, 0, 0, 0, 0, 0, 0, 0};
  for (int i = 0; i < 16; ++i) {
    u16x8 vv = *reinterpret_cast<const u16x8*>(vb + (size_t)(rc * 16 + i) * QVLD);
#pragma unroll
    for (int e = 0; e < 8; ++e) s[e] += bf2f(vv[e]);
  }
  __shared__ float red[64][33];
#pragma unroll
  for (int e = 0; e < 8; ++e) red[c8 * 8 + e][rc] = s[e];
  __syncthreads();
  if (tid < 64) {
    float t = 0.f;
#pragma unroll
    for (int c = 0; c < 32; ++c) t += red[tid][c];
    const float factor = (h < HS_) ? 1.f : rdyn[b * 6 + (h - HS_)];
    ctx[((size_t)(b * SEQ)) * DM + h * DK + tid] = f2b(t * (1.f / 512.f) * factor);
  }
}

// ---------------- fused flash attention (MFMA) ----------------
// grid (2, h, b), 256 thr. Block bx does q-tiles {bx, 3-bx} (balanced: 10 k-tiles each).
__global__ __launch_bounds__(256) void fattn_kernel(
    const bf16_t* __restrict__ qv, const float* __restrict__ rdyn,
    bf16_t* __restrict__ ctx, int strict) {
  const int bx = blockIdx.x, h = blockIdx.y, b = blockIdx.z;
  const int tid = threadIdx.x, wid = tid >> 6, lane = tid & 63;
  const int c0 = lane & 15, grp = lane >> 4;
  const int l3 = lane >> 3, c3 = lane & 7;
  const int kidx = lane & 31, dhalf = lane >> 5;

  __shared__ __align__(16) bf16_t Ks[64 * 64];        // swizzled [64k][64ch]
  __shared__ __align__(16) bf16_t Vt[64 * 72];        // transposed [64d][64k+8pad]
  __shared__ __align__(16) bf16_t Ps[4][32 * 64];     // per-wave P, swizzled

  const bf16_t* qp = qv;          // q half, row stride QVLD
  const bf16_t* vp = qv + 512;    // v half
  const float factor = (h < HS_) ? 1.f : rdyn[b * 6 + (h - HS_)];

  for (int ph = 0; ph < 2; ++ph) {
    const int qt = ph ? 3 - bx : bx;
    const int qbase = qt * 128 + wid * 32;

    bf16x8 qf[2][2];
#pragma unroll
    for (int nt = 0; nt < 2; ++nt)
#pragma unroll
      for (int ks = 0; ks < 2; ++ks)
        qf[nt][ks] = *reinterpret_cast<const bf16x8*>(
            qp + ((size_t)(b * SEQ + qbase + nt * 16 + c0)) * QVLD + h * DK + ks * 32 + grp * 8);

    f32x4 acc[2][4];
#pragma unroll
    for (int m = 0; m < 2; ++m)
#pragma unroll
      for (int d = 0; d < 4; ++d) acc[m][d] = f32x4{0.f, 0.f, 0.f, 0.f};
    float mreg[2] = {-3e38f, -3e38f};
    float lreg[2] = {0.f, 0.f};

    const int lastk = (qbase + 31 - strict) >> 6;
    const int ktmax = 2 * qt + 1;

    for (int kt = 0; kt <= ktmax; ++kt) {
#pragma unroll
      for (int i = 0; i < 2; ++i) {
        int row = i * 32 + wid * 8 + l3;
        int blk = c3 ^ l3;
        gload_lds16(qp + ((size_t)(b * SEQ + kt * 64 + row)) * QVLD + h * DK + blk * 8,
                    Ks + (i * 32 + wid * 8) * 64);
      }
#pragma unroll
      for (int j = 0; j < 2; ++j) {
        const int p = wid * 2 + j;
        const int d0 = p * 8 + dhalf * 4;
        const bf16_t* src = vp + ((size_t)(b * SEQ + kt * 64 + 2 * kidx)) * QVLD + h * DK + d0;
        ushort4 lo = *reinterpret_cast<const ushort4*>(src);
        ushort4 hv = *reinterpret_cast<const ushort4*>(src + QVLD);
        *reinterpret_cast<unsigned*>(&Vt[(d0 + 0) * 72 + 2 * kidx]) = (unsigned)lo.x | ((unsigned)hv.x << 16);
        *reinterpret_cast<unsigned*>(&Vt[(d0 + 1) * 72 + 2 * kidx]) = (unsigned)lo.y | ((unsigned)hv.y << 16);
        *reinterpret_cast<unsigned*>(&Vt[(d0 + 2) * 72 + 2 * kidx]) = (unsigned)lo.z | ((unsigned)hv.z << 16);
        *reinterpret_cast<unsigned*>(&Vt[(d0 + 3) * 72 + 2 * kidx]) = (unsigned)lo.w | ((unsigned)hv.w << 16);
      }
      __syncthreads();

      if (kt <= lastk) {
        const char* KsB = (const char*)Ks;
        bf16x8 kf[4][2];
#pragma unroll
        for (int mt = 0; mt < 4; ++mt)
#pragma unroll
          for (int ks = 0; ks < 2; ++ks)
            kf[mt][ks] = *reinterpret_cast<const bf16x8*>(
                KsB + (mt * 16 + c0) * 128 + 16 * ((4 * ks + grp) ^ (c0 & 7)));
        f32x4 s[4][2];
#pragma unroll
        for (int mt = 0; mt < 4; ++mt)
#pragma unroll
          for (int nt = 0; nt < 2; ++nt) s[mt][nt] = f32x4{0.f, 0.f, 0.f, 0.f};
        __builtin_amdgcn_s_setprio(1);
#pragma unroll
        for (int mt = 0; mt < 4; ++mt)
#pragma unroll
          for (int nt = 0; nt < 2; ++nt)
#pragma unroll
            for (int ks = 0; ks < 2; ++ks)
              s[mt][nt] = __builtin_amdgcn_mfma_f32_16x16x32_bf16(
                  kf[mt][ks], qf[nt][ks], s[mt][nt], 0, 0, 0);
        __builtin_amdgcn_s_setprio(0);

        const bool masked = (kt == lastk);
        float sc[2];
#pragma unroll
        for (int nt = 0; nt < 2; ++nt) {
          const int q = qbase + nt * 16 + c0;
#pragma unroll
          for (int mt = 0; mt < 4; ++mt)
#pragma unroll
            for (int j = 0; j < 4; ++j) {
              int k = kt * 64 + mt * 16 + grp * 4 + j;
              float t = s[mt][nt][j] * 0.125f;
              if (masked && (k + strict > q)) t = -1e30f;
              s[mt][nt][j] = t;
            }
          float mx = -3e38f;
#pragma unroll
          for (int mt = 0; mt < 4; ++mt)
#pragma unroll
            for (int j = 0; j < 4; ++j) mx = fmaxf(mx, s[mt][nt][j]);
          mx = fmaxf(mx, __shfl_xor(mx, 16));
          mx = fmaxf(mx, __shfl_xor(mx, 32));
          const float mnew = fmaxf(mreg[nt], mx);
          sc[nt] = __expf(mreg[nt] - mnew);
          mreg[nt] = mnew;
          float ts = 0.f;
#pragma unroll
          for (int mt = 0; mt < 4; ++mt)
#pragma unroll
            for (int j = 0; j < 4; ++j) {
              float pp = __expf(s[mt][nt][j] - mnew);
              s[mt][nt][j] = pp; ts += pp;
            }
          ts += __shfl_xor(ts, 16);
          ts += __shfl_xor(ts, 32);
          lreg[nt] = lreg[nt] * sc[nt] + ts;
        }
        char* PsB = (char*)(&Ps[wid][0]);
#pragma unroll
        for (int nt = 0; nt < 2; ++nt)
#pragma unroll
          for (int mt = 0; mt < 4; ++mt) {
            uint2 w;
            w.x = (unsigned)f2b(s[mt][nt][0]) | ((unsigned)f2b(s[mt][nt][1]) << 16);
            w.y = (unsigned)f2b(s[mt][nt][2]) | ((unsigned)f2b(s[mt][nt][3]) << 16);
            int row = nt * 16 + c0;
            int off = (row * 128 + mt * 32 + grp * 8) ^ ((c0 & 7) << 4);
            *reinterpret_cast<uint2*>(PsB + off) = w;
          }
#pragma unroll
        for (int mtq = 0; mtq < 2; ++mtq) {
          f32x4 sv;
#pragma unroll
          for (int j = 0; j < 4; ++j) sv[j] = __shfl(sc[mtq], grp * 4 + j);
#pragma unroll
          for (int dt = 0; dt < 4; ++dt) acc[mtq][dt] *= sv;
        }
        bf16x8 pf[2][2], vf2[4][2];
#pragma unroll
        for (int mtq = 0; mtq < 2; ++mtq)
#pragma unroll
          for (int ks = 0; ks < 2; ++ks)
            pf[mtq][ks] = *reinterpret_cast<const bf16x8*>(
                PsB + (mtq * 16 + c0) * 128 + 16 * ((4 * ks + grp) ^ (c0 & 7)));
#pragma unroll
        for (int dt = 0; dt < 4; ++dt)
#pragma unroll
          for (int ks = 0; ks < 2; ++ks)
            vf2[dt][ks] = *reinterpret_cast<const bf16x8*>(
                (const char*)Vt + (dt * 16 + c0) * 144 + ks * 64 + grp * 16);
        __builtin_amdgcn_s_setprio(1);
#pragma unroll
        for (int mtq = 0; mtq < 2; ++mtq)
#pragma unroll
          for (int dt = 0; dt < 4; ++dt)
#pragma unroll
            for (int ks = 0; ks < 2; ++ks)
              acc[mtq][dt] = __builtin_amdgcn_mfma_f32_16x16x32_bf16(
                  pf[mtq][ks], vf2[dt][ks], acc[mtq][dt], 0, 0, 0);
        __builtin_amdgcn_s_setprio(0);
      }
      __syncthreads();
    }

#pragma unroll
    for (int mtq = 0; mtq < 2; ++mtq) {
      const float inv = factor / lreg[mtq];
      f32x4 iv;
#pragma unroll
      for (int j = 0; j < 4; ++j) iv[j] = __shfl(inv, grp * 4 + j);
#pragma unroll
      for (int j = 0; j < 4; ++j) {
        const int q = qbase + mtq * 16 + grp * 4 + j;
        if (q == 0) continue;
#pragma unroll
        for (int dt = 0; dt < 4; ++dt)
          ctx[((size_t)(b * SEQ + q)) * DM + h * DK + dt * 16 + c0] =
              f2b(acc[mtq][dt][j] * iv[j]);
      }
    }
  }
}

// ---------------- add + layernorm (residual f32, delta bf16) ----------------
__global__ __launch_bounds__(256) void add_ln_kernel(
    const float* __restrict__ X, const bf16_t* __restrict__ A2,
    const float* __restrict__ gam, const float* __restrict__ bet,
    float* __restrict__ outf, bf16_t* __restrict__ outb) {
  const int row = blockIdx.x, tid = threadIdx.x, wid = tid >> 6, lane = tid & 63;
  const size_t base = (size_t)row * DM;
  float2 xv = *reinterpret_cast<const float2*>(X + base + 2 * tid);
  float a0, a1;
  unp2(*reinterpret_cast<const unsigned*>(A2 + base + 2 * tid), a0, a1);
  float z0 = xv.x + a0, z1 = xv.y + a1;
  __shared__ float red[4];
  float s = z0 + z1;
#pragma unroll
  for (int off = 32; off; off >>= 1) s += __shfl_xor(s, off);
  if (lane == 0) red[wid] = s;
  __syncthreads();
  const float mean = (red[0] + red[1] + red[2] + red[3]) * (1.f / 512.f);
  __syncthreads();
  const float d0 = z0 - mean, d1 = z1 - mean;
  float ss = d0 * d0 + d1 * d1;
#pragma unroll
  for (int off = 32; off; off >>= 1) ss += __shfl_xor(ss, off);
  if (lane == 0) red[wid] = ss;
  __syncthreads();
  const float var = (red[0] + red[1] + red[2] + red[3]) * (1.f / 512.f);
  const float inv = rsqrtf(var + 1e-5f);
  const float2 gv = *reinterpret_cast<const float2*>(gam + 2 * tid);
  const float2 bv = *reinterpret_cast<const float2*>(bet + 2 * tid);
  const float o0 = d0 * inv * gv.x + bv.x;
  const float o1 = d1 * inv * gv.y + bv.y;
  float2 of; of.x = o0; of.y = o1;
  *reinterpret_cast<float2*>(outf + base + 2 * tid) = of;
  *reinterpret_cast<unsigned*>(outb + base + 2 * tid) =
      (unsigned)f2b(o0) | ((unsigned)f2b(o1) << 16);
}

// ---------------- balance ----------------
__global__ void balance_kernel(const float* __restrict__ fP, float* __restrict__ out) {
  if (threadIdx.x == 0 && blockIdx.x == 0) {
    float fs = 0.f, pssum = 0.f, P[6];
    for (int j = 0; j < 6; ++j) {
      fs += fP[j];
      P[j] = fP[6 + j] * (1.f / (float)MROWS);
      pssum += P[j];
    }
    float bal = 0.f;
    for (int j = 0; j < 6; ++j)
      bal += (fP[j] / (fs + 1e-5f)) * (P[j] / (pssum + 1e-5f));
    out[0] = bal;
  }
}

// ---------------- host ----------------
extern "C" void kernel_launch(void* const* d_in, const int* in_sizes, int n_in,
                              void* d_out, int out_size, void* d_ws, size_t ws_size,
                              hipStream_t stream) {
  (void)in_sizes; (void)n_in; (void)out_size; (void)ws_size;
  const float* q_embed  = (const float*)d_in[0];
  const float* qa_embed = (const float*)d_in[1];
  const float* Wq  = (const float*)d_in[2];
  const float* bq  = (const float*)d_in[3];
  const float* Wv  = (const float*)d_in[4];
  const float* bv  = (const float*)d_in[5];
  const float* Wg  = (const float*)d_in[6];
  const float* Wo  = (const float*)d_in[7];
  const float* bo  = (const float*)d_in[8];
  const float* ln1g = (const float*)d_in[9];
  const float* ln1b = (const float*)d_in[10];
  const float* W1  = (const float*)d_in[11];
  const float* b1  = (const float*)d_in[12];
  const float* W2  = (const float*)d_in[13];
  const float* b2  = (const float*)d_in[14];
  const float* ln2g = (const float*)d_in[15];
  const float* ln2b = (const float*)d_in[16];

  char* p = (char*)d_ws;
  auto alloc = [&](size_t bytes) -> char* {
    char* r = p; p += (bytes + 255) & ~(size_t)255; return r;
  };
  const size_t WDE = (size_t)NL * DM * DM;   // stacked weight elems (per tensor)
  const size_t AE  = (size_t)MROWS * DM;     // activation elems
  bf16_t* wall_b = (bf16_t*)alloc(5 * WDE * 2);   // wq|wv|wo|w1|w2 contiguous
  bf16_t* wq_b = wall_b;
  bf16_t* wv_b = wall_b + WDE;
  bf16_t* wo_b = wall_b + 2 * WDE;
  bf16_t* w1_b = wall_b + 3 * WDE;
  bf16_t* w2_b = wall_b + 4 * WDE;
  float* y_f   = (float*)alloc(AE * 4);
  float* x_f   = (float*)alloc(AE * 4);
  float* x1_f  = (float*)alloc(AE * 4);
  bf16_t* y_b   = (bf16_t*)alloc(AE * 2);
  bf16_t* x_b   = (bf16_t*)alloc(AE * 2);
  bf16_t* qv_b  = (bf16_t*)alloc((size_t)MROWS * QVLD * 2);  // q|v merged
  bf16_t* ctx_b = (bf16_t*)alloc(AE * 2);
  bf16_t* x1_b  = (bf16_t*)alloc(AE * 2);
  bf16_t* tmp_b = (bf16_t*)alloc(AE * 2);
  bf16_t* ffn1_b = (bf16_t*)alloc(AE * 2);
  float* rdyn = (float*)alloc(BSZ * 6 * 4);
  float* fP   = (float*)alloc(NL * 12 * 4);

  hipMemsetAsync(fP, 0, NL * 12 * 4, stream);

  // weights -> bf16 (one launch, 5 tensors)
  f2bw_kernel<<<dim3((unsigned)(WDE / 4 / 256), 5), 256, 0, stream>>>(
      Wq, Wv, Wo, W1, W2, wall_b);
  // initial activations -> bf16
  f2b_kernel<<<2048, 256, 0, stream>>>(qa_embed, y_b, (int)(AE / 4));
  f2b_kernel<<<2048, 256, 0, stream>>>(q_embed, x_b, (int)(AE / 4));

  const size_t DD = (size_t)DM * DM;
  dim3 gqv(8, 128), gn5(4, 256);

  auto layer = [&](int i, const float* xqf, const bf16_t* xqb, const bf16_t* xvb,
                   float* outf, bf16_t* outb, int strict) {
    hipMemsetAsync(rdyn, 0, BSZ * 6 * 4, stream);
    gemm_qv<<<gqv, 256, 0, stream>>>(
        xqb, xvb, wq_b + i * DD, wv_b + i * DD, bq + i * DM, bv + i * DM, qv_b);
    gates_kernel<<<MROWS / 64, 256, 0, stream>>>(qv_b, Wg + (size_t)i * HD_ * DM, rdyn, fP + i * 12);
    rowzero_kernel<<<dim3(NH, BSZ), 256, 0, stream>>>(qv_b, rdyn, ctx_b);
    fattn_kernel<<<dim3(2, NH, BSZ), 256, 0, stream>>>(qv_b, rdyn, ctx_b, strict);
    gemm_n512<false><<<gn5, 256, 0, stream>>>(ctx_b, wo_b + i * DD, bo + i * DM, tmp_b);
    add_ln_kernel<<<MROWS, 256, 0, stream>>>(xqf, tmp_b, ln1g + i * DM, ln1b + i * DM, x1_f, x1_b);
    gemm_n512<true><<<gn5, 256, 0, stream>>>(x1_b, w1_b + i * DD, b1 + i * DM, ffn1_b);
    gemm_n512<false><<<gn5, 256, 0, stream>>>(ffn1_b, w2_b + i * DD, b2 + i * DM, tmp_b);
    add_ln_kernel<<<MROWS, 256, 0, stream>>>(x1_f, tmp_b, ln2g + i * DM, ln2b + i * DM, outf, outb);
  };

  float* outx = (float*)d_out;
  layer(0, qa_embed, y_b, y_b, y_f, y_b, 0);
  layer(1, y_f, y_b, y_b, y_f, y_b, 0);
  layer(2, q_embed, x_b, x_b, x_f, x_b, 0);
  layer(3, x_f, x_b, y_b, x_f, x_b, 1);
  layer(4, x_f, x_b, x_b, x_f, x_b, 0);
  layer(5, x_f, x_b, y_b, outx, x_b, 1);
  balance_kernel<<<1, 64, 0, stream>>>(fP + 5 * 12, outx + (size_t)MROWS * DM);
}

// Round 6
// 1050.124 us; speedup vs baseline: 9.6709x; 1.2006x over previous
//
#include <hip/hip_runtime.h>
#include <cstdint>

// ---------------- constants ----------------
#define BSZ 32
#define SEQ 512
#define DM  512
#define NH  8
#define DK  64
#define HS_ 2
#define HD_ 6
#define NL  6
#define MROWS (BSZ*SEQ)          // 16384
#define QVLD 1024                // row stride of merged q|v buffer
#define SCL 0.18033688011112043f // 0.125 * log2(e)  (exp2 domain)

typedef unsigned short bf16_t;
typedef __attribute__((ext_vector_type(4))) float f32x4;
typedef __attribute__((ext_vector_type(8))) short bf16x8;
typedef __attribute__((ext_vector_type(8))) unsigned short u16x8;

#define DEV static __device__ __forceinline__

DEV float bf2f(bf16_t b) {
  unsigned int u = ((unsigned int)b) << 16;
  float f; __builtin_memcpy(&f, &u, 4); return f;
}
DEV bf16_t f2b(float f) {  // RNE bf16 (finite inputs)
  unsigned int u; __builtin_memcpy(&u, &f, 4);
  unsigned int r = (u + 0x7fffu + ((u >> 16) & 1u)) >> 16;
  return (bf16_t)r;
}
DEV void unp2(unsigned int w, float& a, float& b) {
  unsigned int ua = w << 16, ub = w & 0xffff0000u;
  __builtin_memcpy(&a, &ua, 4); __builtin_memcpy(&b, &ub, 4);
}
DEV unsigned cvtpk(float lo, float hi) {
  unsigned r;
  asm("v_cvt_pk_bf16_f32 %0, %1, %2" : "=v"(r) : "v"(lo), "v"(hi));
  return r;
}

DEV void gload_lds16(const bf16_t* g, bf16_t* l) {
  __builtin_amdgcn_global_load_lds(
      (const __attribute__((address_space(1))) void*)g,
      (__attribute__((address_space(3))) void*)l, 16, 0, 0);
}

// ---------------- f32 -> bf16 converts ----------------
__global__ __launch_bounds__(256) void f2b_kernel(const float* __restrict__ in,
                                                  bf16_t* __restrict__ out, int n4) {
  int i = blockIdx.x * 256 + threadIdx.x;
  int stride = gridDim.x * 256;
  for (; i < n4; i += stride) {
    float4 v = reinterpret_cast<const float4*>(in)[i];
    ushort4 o;
    o.x = f2b(v.x); o.y = f2b(v.y); o.z = f2b(v.z); o.w = f2b(v.w);
    reinterpret_cast<ushort4*>(out)[i] = o;
  }
}

// 5 stacked weight tensors -> one contiguous bf16 arena. grid (1536, 5).
__global__ __launch_bounds__(256) void f2bw_kernel(
    const float* __restrict__ s0, const float* __restrict__ s1,
    const float* __restrict__ s2, const float* __restrict__ s3,
    const float* __restrict__ s4, bf16_t* __restrict__ dst) {
  const float* srcs[5] = {s0, s1, s2, s3, s4};
  const float* s = srcs[blockIdx.y];
  bf16_t* d = dst + (size_t)blockIdx.y * ((size_t)NL * DM * DM);
  const int i = blockIdx.x * 256 + threadIdx.x;
  float4 v = reinterpret_cast<const float4*>(s)[i];
  ushort4 o;
  o.x = f2b(v.x); o.y = f2b(v.y); o.z = f2b(v.z); o.w = f2b(v.w);
  reinterpret_cast<ushort4*>(d)[i] = o;
}

// ---------------- MFMA GEMM (128x128 tile, BK=64): qv projection ----------------
// Y[:, 0:512) = A0 @ W0^T + b0 ; Y[:, 512:1024) = A1 @ W1^T + b1. bf16 out, ldy=1024.
__global__ __launch_bounds__(256) void gemm_qv(
    const bf16_t* __restrict__ A0, const bf16_t* __restrict__ A1,
    const bf16_t* __restrict__ W0, const bf16_t* __restrict__ W1,
    const float* __restrict__ b0, const float* __restrict__ b1,
    bf16_t* __restrict__ Yb) {
  const int K = 512;
  // XCD swizzle: group bm-contiguous tiles on one XCD (1024 wgs, 8 XCDs)
  const int lin = blockIdx.y * 8 + blockIdx.x;
  const int swz = (lin & 7) * 128 + (lin >> 3);
  const int bn = swz & 7, bm = swz >> 3;
  const int tid = threadIdx.x, wid = tid >> 6, lane = tid & 63;
  const int wr = wid >> 1, wc = wid & 1;   // 2x2 wave grid, 64x64 each
  __shared__ __align__(16) bf16_t As[128 * 64];
  __shared__ __align__(16) bf16_t Bs[128 * 64];

  const bool hi = bn >= 4;
  const bf16_t* Asel = hi ? A1 : A0;
  const bf16_t* Wsel = hi ? (W1 - (size_t)512 * K) : W0;
  const float* bsel = hi ? (b1 - 512) : b0;

  f32x4 acc[4][4];
#pragma unroll
  for (int m = 0; m < 4; ++m)
#pragma unroll
    for (int n = 0; n < 4; ++n) acc[m][n] = f32x4{0.f, 0.f, 0.f, 0.f};

  const int lrow = lane & 15, lko = (lane >> 4) * 8;
  const int sr = wid * 8 + (lane >> 3), scol = (lane & 7) * 8;  // staging row/col
  const size_t arow0 = (size_t)bm * 128, brow0 = (size_t)bn * 128;

  for (int k0 = 0; k0 < K; k0 += 64) {
#pragma unroll
    for (int i = 0; i < 4; ++i) {
      gload_lds16(Asel + (arow0 + i * 32 + sr) * K + k0 + scol, &As[(i * 4 + wid) * 512]);
      gload_lds16(Wsel + (brow0 + i * 32 + sr) * K + k0 + scol, &Bs[(i * 4 + wid) * 512]);
    }
    __syncthreads();
    bf16x8 af[4][2], bw[4][2];
#pragma unroll
    for (int m = 0; m < 4; ++m)
#pragma unroll
      for (int ks = 0; ks < 2; ++ks)
        af[m][ks] = *reinterpret_cast<const bf16x8*>(
            &As[(wr * 64 + m * 16 + lrow) * 64 + ks * 32 + lko]);
#pragma unroll
    for (int n = 0; n < 4; ++n)
#pragma unroll
      for (int ks = 0; ks < 2; ++ks)
        bw[n][ks] = *reinterpret_cast<const bf16x8*>(
            &Bs[(wc * 64 + n * 16 + lrow) * 64 + ks * 32 + lko]);
    __builtin_amdgcn_s_setprio(1);
#pragma unroll
    for (int ks = 0; ks < 2; ++ks)
#pragma unroll
      for (int m = 0; m < 4; ++m)
#pragma unroll
        for (int n = 0; n < 4; ++n)
          acc[m][n] = __builtin_amdgcn_mfma_f32_16x16x32_bf16(af[m][ks], bw[n][ks], acc[m][n], 0, 0, 0);
    __builtin_amdgcn_s_setprio(0);
    __syncthreads();
  }

  const int r0 = bm * 128 + wr * 64 + (lane >> 4) * 4;
  const int c0 = bn * 128 + wc * 64 + lrow;
#pragma unroll
  for (int n = 0; n < 4; ++n) {
    const int col = c0 + n * 16;
    const float bc = bsel[col];
#pragma unroll
    for (int m = 0; m < 4; ++m)
#pragma unroll
      for (int j = 0; j < 4; ++j)
        Yb[(size_t)(r0 + m * 16 + j) * QVLD + col] = f2b(acc[m][n][j] + bc);
  }
}

// ---------------- MFMA GEMM (64x128 tile, BK=64): N=512, bf16 out ----------------
template <bool RELU>
__global__ __launch_bounds__(256) void gemm_n512(
    const bf16_t* __restrict__ A, const bf16_t* __restrict__ W,
    const float* __restrict__ bias, bf16_t* __restrict__ Yb) {
  const int K = 512;
  const int lin = blockIdx.y * 4 + blockIdx.x;
  const int swz = (lin & 7) * 128 + (lin >> 3);
  const int bn = swz & 3, bm = swz >> 2;
  const int tid = threadIdx.x, wid = tid >> 6, lane = tid & 63;
  const int wr = wid >> 1, wc = wid & 1;   // 2x2 wave grid, 32x64 each
  __shared__ __align__(16) bf16_t As[64 * 64];
  __shared__ __align__(16) bf16_t Bs[128 * 64];

  f32x4 acc[2][4];
#pragma unroll
  for (int m = 0; m < 2; ++m)
#pragma unroll
    for (int n = 0; n < 4; ++n) acc[m][n] = f32x4{0.f, 0.f, 0.f, 0.f};

  const int lrow = lane & 15, lko = (lane >> 4) * 8;
  const int sr = wid * 8 + (lane >> 3), scol = (lane & 7) * 8;
  const size_t arow0 = (size_t)bm * 64, brow0 = (size_t)bn * 128;

  for (int k0 = 0; k0 < K; k0 += 64) {
#pragma unroll
    for (int i = 0; i < 2; ++i)
      gload_lds16(A + (arow0 + i * 32 + sr) * K + k0 + scol, &As[(i * 4 + wid) * 512]);
#pragma unroll
    for (int i = 0; i < 4; ++i)
      gload_lds16(W + (brow0 + i * 32 + sr) * K + k0 + scol, &Bs[(i * 4 + wid) * 512]);
    __syncthreads();
    bf16x8 af[2][2], bw[4][2];
#pragma unroll
    for (int m = 0; m < 2; ++m)
#pragma unroll
      for (int ks = 0; ks < 2; ++ks)
        af[m][ks] = *reinterpret_cast<const bf16x8*>(
            &As[(wr * 32 + m * 16 + lrow) * 64 + ks * 32 + lko]);
#pragma unroll
    for (int n = 0; n < 4; ++n)
#pragma unroll
      for (int ks = 0; ks < 2; ++ks)
        bw[n][ks] = *reinterpret_cast<const bf16x8*>(
            &Bs[(wc * 64 + n * 16 + lrow) * 64 + ks * 32 + lko]);
    __builtin_amdgcn_s_setprio(1);
#pragma unroll
    for (int ks = 0; ks < 2; ++ks)
#pragma unroll
      for (int m = 0; m < 2; ++m)
#pragma unroll
        for (int n = 0; n < 4; ++n)
          acc[m][n] = __builtin_amdgcn_mfma_f32_16x16x32_bf16(af[m][ks], bw[n][ks], acc[m][n], 0, 0, 0);
    __builtin_amdgcn_s_setprio(0);
    __syncthreads();
  }

  const int r0 = bm * 64 + wr * 32 + (lane >> 4) * 4;
  const int c0 = bn * 128 + wc * 64 + lrow;
#pragma unroll
  for (int n = 0; n < 4; ++n) {
    const int col = c0 + n * 16;
    const float bc = bias[col];
#pragma unroll
    for (int m = 0; m < 2; ++m)
#pragma unroll
      for (int j = 0; j < 4; ++j) {
        float v = acc[m][n][j] + bc;
        if (RELU) v = fmaxf(v, 0.f);
        Yb[(size_t)(r0 + m * 16 + j) * DM + col] = f2b(v);
      }
  }
}

// ---------------- gating: softmax(q @ Wg^T), top-4-of-6, fused routing ----------------
__global__ __launch_bounds__(256) void gates_kernel(
    const bf16_t* __restrict__ qv, const float* __restrict__ Wg,
    float* __restrict__ rdyn, float* __restrict__ fP) {
  __shared__ float wg_s[HD_ * DM];
  __shared__ float blk[4][18];
  const int tid = threadIdx.x, wid = tid >> 6, lane = tid & 63;
  for (int i = tid; i < HD_ * DM / 4; i += 256)
    reinterpret_cast<float4*>(wg_s)[i] = reinterpret_cast<const float4*>(Wg)[i];
  __syncthreads();
  const int bb = blockIdx.x >> 3;
  const int t0 = (blockIdx.x & 7) * 64 + wid * 16;
  float fs[6] = {0, 0, 0, 0, 0, 0}, ps[6] = {0, 0, 0, 0, 0, 0}, rs[6] = {0, 0, 0, 0, 0, 0};
  for (int it = 0; it < 16; ++it) {
    const int tok = bb * SEQ + t0 + it;
    uint4 u = reinterpret_cast<const uint4*>(qv + (size_t)tok * QVLD)[lane];
    float x[8];
    unp2(u.x, x[0], x[1]); unp2(u.y, x[2], x[3]);
    unp2(u.z, x[4], x[5]); unp2(u.w, x[6], x[7]);
    float g[6];
#pragma unroll
    for (int j = 0; j < 6; ++j) {
      float p = 0.f;
#pragma unroll
      for (int e = 0; e < 8; ++e) p = fmaf(x[e], wg_s[j * DM + lane * 8 + e], p);
#pragma unroll
      for (int off = 32; off; off >>= 1) p += __shfl_xor(p, off);
      g[j] = p;
    }
    float mx = g[0];
#pragma unroll
    for (int j = 1; j < 6; ++j) mx = fmaxf(mx, g[j]);
    float se = 0.f;
#pragma unroll
    for (int j = 0; j < 6; ++j) { g[j] = __expf(g[j] - mx); se += g[j]; }
    float inv = 1.f / se;
#pragma unroll
    for (int j = 0; j < 6; ++j) g[j] *= inv;
    int d1 = 0;
#pragma unroll
    for (int j = 1; j < 6; ++j)
      if (g[j] < g[d1] || (g[j] == g[d1] && j > d1)) d1 = j;
    int d2 = (d1 == 0) ? 1 : 0;
#pragma unroll
    for (int j = 0; j < 6; ++j) {
      if (j == d1) continue;
      if (g[j] < g[d2] || (g[j] == g[d2] && j > d2)) d2 = j;
    }
#pragma unroll
    for (int j = 0; j < 6; ++j) {
      const bool drop = (j == d1) || (j == d2);
      fs[j] += drop ? 0.f : 1.f;
      ps[j] += g[j];
      rs[j] += drop ? 0.f : g[j];
    }
  }
  if (lane == 0) {
#pragma unroll
    for (int j = 0; j < 6; ++j) {
      blk[wid][j] = fs[j]; blk[wid][6 + j] = ps[j]; blk[wid][12 + j] = rs[j];
    }
  }
  __syncthreads();
  if (tid < 18) {
    float s = blk[0][tid] + blk[1][tid] + blk[2][tid] + blk[3][tid];
    if (tid < 12) atomicAdd(&fP[tid], s);
    else atomicAdd(&rdyn[bb * 6 + (tid - 12)], s * (1.f / 512.f));
  }
}

// ---------------- row-0 quirk: ctx[b,0,h,:] = factor * mean_k V ----------------
__global__ __launch_bounds__(256) void rowzero_kernel(
    const bf16_t* __restrict__ qv, const float* __restrict__ rdyn,
    bf16_t* __restrict__ ctx) {
  const int h = blockIdx.x, b = blockIdx.y;
  const int tid = threadIdx.x;
  const int c8 = tid & 7;        // col block (8 elems)
  const int rc = tid >> 3;       // row chunk 0..31 (16 rows each)
  const bf16_t* vb = qv + 512 + ((size_t)(b * SEQ)) * QVLD + h * DK + c8 * 8;
  float s[8] = {0, 0, 0, 0, 0, 0, 0, 0};
  for (int i = 0; i < 16; ++i) {
    u16x8 vv = *reinterpret_cast<const u16x8*>(vb + (size_t)(rc * 16 + i) * QVLD);
#pragma unroll
    for (int e = 0; e < 8; ++e) s[e] += bf2f(vv[e]);
  }
  __shared__ float red[64][33];
#pragma unroll
  for (int e = 0; e < 8; ++e) red[c8 * 8 + e][rc] = s[e];
  __syncthreads();
  if (tid < 64) {
    float t = 0.f;
#pragma unroll
    for (int c = 0; c < 32; ++c) t += red[tid][c];
    const float factor = (h < HS_) ? 1.f : rdyn[b * 6 + (h - HS_)];
    ctx[((size_t)(b * SEQ)) * DM + h * DK + tid] = f2b(t * (1.f / 512.f) * factor);
  }
}

// ---------------- fused flash attention (MFMA) ----------------
// grid (2, 8, 32), 256 thr. Block bx owns q-tiles {bx, 3-bx}; ONE kt loop with
// both accumulator sets live -> K/V staged once per kt (14 stages vs 20).
__global__ __launch_bounds__(256, 2) void fattn_kernel(
    const bf16_t* __restrict__ qv, const float* __restrict__ rdyn,
    bf16_t* __restrict__ ctx, int strict) {
  // XCD swizzle: co-locate the (b,h) block pair on one XCD (512 wgs)
  const int lin = (blockIdx.z * 8 + blockIdx.y) * 2 + blockIdx.x;
  const int swz = (lin & 7) * 64 + (lin >> 3);
  const int bx = swz & 1, h = (swz >> 1) & 7, b = swz >> 4;
  const int tid = threadIdx.x, wid = tid >> 6, lane = tid & 63;
  const int c0 = lane & 15, grp = lane >> 4;
  const int l3 = lane >> 3, c3 = lane & 7;
  const int kidx = lane & 31, dhalf = lane >> 5;

  __shared__ __align__(16) bf16_t Ks[64 * 64];        // swizzled [64k][64ch]
  __shared__ __align__(16) bf16_t Vt[64 * 72];        // transposed [64d][64k+8pad]
  __shared__ __align__(16) bf16_t Ps[4][32 * 64];     // per-wave P, swizzled

  const bf16_t* qp = qv;          // q half, row stride QVLD
  const bf16_t* vp = qv + 512;    // v half
  const float factor = (h < HS_) ? 1.f : rdyn[b * 6 + (h - HS_)];

  const int qtA = bx, qtB = 3 - bx;                   // qtA < qtB
  const int qbaseA = qtA * 128 + wid * 32;
  const int qbaseB = qtB * 128 + wid * 32;

  bf16x8 qfA[2][2], qfB[2][2];
#pragma unroll
  for (int nt = 0; nt < 2; ++nt)
#pragma unroll
    for (int ks = 0; ks < 2; ++ks) {
      qfA[nt][ks] = *reinterpret_cast<const bf16x8*>(
          qp + ((size_t)(b * SEQ + qbaseA + nt * 16 + c0)) * QVLD + h * DK + ks * 32 + grp * 8);
      qfB[nt][ks] = *reinterpret_cast<const bf16x8*>(
          qp + ((size_t)(b * SEQ + qbaseB + nt * 16 + c0)) * QVLD + h * DK + ks * 32 + grp * 8);
    }

  f32x4 accA[2][4], accB[2][4];
#pragma unroll
  for (int m = 0; m < 2; ++m)
#pragma unroll
    for (int d = 0; d < 4; ++d) {
      accA[m][d] = f32x4{0.f, 0.f, 0.f, 0.f};
      accB[m][d] = f32x4{0.f, 0.f, 0.f, 0.f};
    }
  float mA[2] = {-3e38f, -3e38f}, lA[2] = {0.f, 0.f};
  float mB[2] = {-3e38f, -3e38f}, lB[2] = {0.f, 0.f};

  const int lastA = (qbaseA + 31 - strict) >> 6;
  const int lastB = (qbaseB + 31 - strict) >> 6;
  const int ktmax = 2 * qtB + 1;

  // compute one q-tile against the currently staged K/V tile
  auto do_tile = [&](bf16x8 (&qf)[2][2], f32x4 (&acc)[2][4], float (&mreg)[2],
                     float (&lreg)[2], int qbase, bool masked, int kt) {
    const char* KsB = (const char*)Ks;
    bf16x8 kf[4][2];
#pragma unroll
    for (int mt = 0; mt < 4; ++mt)
#pragma unroll
      for (int ks = 0; ks < 2; ++ks)
        kf[mt][ks] = *reinterpret_cast<const bf16x8*>(
            KsB + (mt * 16 + c0) * 128 + 16 * ((4 * ks + grp) ^ (c0 & 7)));
    f32x4 s[4][2];
#pragma unroll
    for (int mt = 0; mt < 4; ++mt)
#pragma unroll
      for (int nt = 0; nt < 2; ++nt) s[mt][nt] = f32x4{0.f, 0.f, 0.f, 0.f};
    __builtin_amdgcn_s_setprio(1);
#pragma unroll
    for (int mt = 0; mt < 4; ++mt)
#pragma unroll
      for (int nt = 0; nt < 2; ++nt)
#pragma unroll
        for (int ks = 0; ks < 2; ++ks)
          s[mt][nt] = __builtin_amdgcn_mfma_f32_16x16x32_bf16(
              kf[mt][ks], qf[nt][ks], s[mt][nt], 0, 0, 0);
    __builtin_amdgcn_s_setprio(0);

    float sc[2];
#pragma unroll
    for (int nt = 0; nt < 2; ++nt) {
      const int q = qbase + nt * 16 + c0;
#pragma unroll
      for (int mt = 0; mt < 4; ++mt)
#pragma unroll
        for (int j = 0; j < 4; ++j) {
          int k = kt * 64 + mt * 16 + grp * 4 + j;
          float t = s[mt][nt][j] * SCL;        // exp2 domain
          if (masked && (k + strict > q)) t = -1e30f;
          s[mt][nt][j] = t;
        }
      float mx = -3e38f;
#pragma unroll
      for (int mt = 0; mt < 4; ++mt)
#pragma unroll
        for (int j = 0; j < 4; ++j) mx = fmaxf(mx, s[mt][nt][j]);
      mx = fmaxf(mx, __shfl_xor(mx, 16));
      mx = fmaxf(mx, __shfl_xor(mx, 32));
      const float mnew = fmaxf(mreg[nt], mx);
      sc[nt] = exp2f(mreg[nt] - mnew);
      mreg[nt] = mnew;
      float ts = 0.f;
#pragma unroll
      for (int mt = 0; mt < 4; ++mt)
#pragma unroll
        for (int j = 0; j < 4; ++j) {
          float pp = exp2f(s[mt][nt][j] - mnew);
          s[mt][nt][j] = pp; ts += pp;
        }
      ts += __shfl_xor(ts, 16);
      ts += __shfl_xor(ts, 32);
      lreg[nt] = lreg[nt] * sc[nt] + ts;
    }
    // P -> bf16 -> per-wave LDS (swizzled), hardware cvt_pk
    char* PsB = (char*)(&Ps[wid][0]);
#pragma unroll
    for (int nt = 0; nt < 2; ++nt)
#pragma unroll
      for (int mt = 0; mt < 4; ++mt) {
        uint2 w;
        w.x = cvtpk(s[mt][nt][0], s[mt][nt][1]);
        w.y = cvtpk(s[mt][nt][2], s[mt][nt][3]);
        int row = nt * 16 + c0;
        int off = (row * 128 + mt * 32 + grp * 8) ^ ((c0 & 7) << 4);
        *reinterpret_cast<uint2*>(PsB + off) = w;
      }
    // online rescale of ctx
#pragma unroll
    for (int mtq = 0; mtq < 2; ++mtq) {
      f32x4 sv;
#pragma unroll
      for (int j = 0; j < 4; ++j) sv[j] = __shfl(sc[mtq], grp * 4 + j);
#pragma unroll
      for (int dt = 0; dt < 4; ++dt) acc[mtq][dt] *= sv;
    }
    // PV
    bf16x8 pf[2][2], vf2[4][2];
#pragma unroll
    for (int mtq = 0; mtq < 2; ++mtq)
#pragma unroll
      for (int ks = 0; ks < 2; ++ks)
        pf[mtq][ks] = *reinterpret_cast<const bf16x8*>(
            PsB + (mtq * 16 + c0) * 128 + 16 * ((4 * ks + grp) ^ (c0 & 7)));
#pragma unroll
    for (int dt = 0; dt < 4; ++dt)
#pragma unroll
      for (int ks = 0; ks < 2; ++ks)
        vf2[dt][ks] = *reinterpret_cast<const bf16x8*>(
            (const char*)Vt + (dt * 16 + c0) * 144 + ks * 64 + grp * 16);
    __builtin_amdgcn_s_setprio(1);
#pragma unroll
    for (int mtq = 0; mtq < 2; ++mtq)
#pragma unroll
      for (int dt = 0; dt < 4; ++dt)
#pragma unroll
        for (int ks = 0; ks < 2; ++ks)
          acc[mtq][dt] = __builtin_amdgcn_mfma_f32_16x16x32_bf16(
              pf[mtq][ks], vf2[dt][ks], acc[mtq][dt], 0, 0, 0);
    __builtin_amdgcn_s_setprio(0);
  };

  for (int kt = 0; kt <= ktmax; ++kt) {
    // ---- stage K tile via global_load_lds, source pre-swizzled ----
#pragma unroll
    for (int i = 0; i < 2; ++i) {
      int row = i * 32 + wid * 8 + l3;
      int blk = c3 ^ l3;
      gload_lds16(qp + ((size_t)(b * SEQ + kt * 64 + row)) * QVLD + h * DK + blk * 8,
                  Ks + (i * 32 + wid * 8) * 64);
    }
    // ---- stage V transposed: lane owns 2 kk-cols x 4 d-rows, 4B writes ----
#pragma unroll
    for (int j = 0; j < 2; ++j) {
      const int p = wid * 2 + j;
      const int d0 = p * 8 + dhalf * 4;
      const bf16_t* src = vp + ((size_t)(b * SEQ + kt * 64 + 2 * kidx)) * QVLD + h * DK + d0;
      ushort4 lo = *reinterpret_cast<const ushort4*>(src);
      ushort4 hv = *reinterpret_cast<const ushort4*>(src + QVLD);
      *reinterpret_cast<unsigned*>(&Vt[(d0 + 0) * 72 + 2 * kidx]) = (unsigned)lo.x | ((unsigned)hv.x << 16);
      *reinterpret_cast<unsigned*>(&Vt[(d0 + 1) * 72 + 2 * kidx]) = (unsigned)lo.y | ((unsigned)hv.y << 16);
      *reinterpret_cast<unsigned*>(&Vt[(d0 + 2) * 72 + 2 * kidx]) = (unsigned)lo.z | ((unsigned)hv.z << 16);
      *reinterpret_cast<unsigned*>(&Vt[(d0 + 3) * 72 + 2 * kidx]) = (unsigned)lo.w | ((unsigned)hv.w << 16);
    }
    __syncthreads();
    if (kt <= lastB) do_tile(qfB, accB, mB, lB, qbaseB, kt == lastB, kt);
    if (kt <= lastA) do_tile(qfA, accA, mA, lA, qbaseA, kt == lastA, kt);
    __syncthreads();
  }

  // ---- epilogues: /l, *routing, store (skip q==0) ----
#pragma unroll
  for (int e = 0; e < 2; ++e) {
    const int qbase = e ? qbaseB : qbaseA;
    f32x4 (&acc)[2][4] = e ? accB : accA;
    float (&lreg)[2] = e ? lB : lA;
#pragma unroll
    for (int mtq = 0; mtq < 2; ++mtq) {
      const float inv = factor / lreg[mtq];
      f32x4 iv;
#pragma unroll
      for (int j = 0; j < 4; ++j) iv[j] = __shfl(inv, grp * 4 + j);
#pragma unroll
      for (int j = 0; j < 4; ++j) {
        const int q = qbase + mtq * 16 + grp * 4 + j;
        if (q == 0) continue;
#pragma unroll
        for (int dt = 0; dt < 4; ++dt)
          ctx[((size_t)(b * SEQ + q)) * DM + h * DK + dt * 16 + c0] =
              f2b(acc[mtq][dt][j] * iv[j]);
      }
    }
  }
}

// ---------------- add + layernorm: wave-per-row, bf16 residual ----------------
// OUT=0: bf16 out; OUT=1: f32 out (final layer)
template <int OUT>
__global__ __launch_bounds__(256) void add_ln_kernel(
    const bf16_t* __restrict__ X, const bf16_t* __restrict__ A2,
    const float* __restrict__ gam, const float* __restrict__ bet,
    bf16_t* __restrict__ outb, float* __restrict__ outf) {
  const int wid = threadIdx.x >> 6, lane = threadIdx.x & 63;
  const size_t row = (size_t)blockIdx.x * 4 + wid;
  const size_t base = row * DM + lane * 8;
  uint4 xu = *reinterpret_cast<const uint4*>(X + base);
  uint4 au = *reinterpret_cast<const uint4*>(A2 + base);
  float z[8];
  {
    float p0, p1, q0, q1;
    unp2(xu.x, p0, p1); unp2(au.x, q0, q1); z[0] = p0 + q0; z[1] = p1 + q1;
    unp2(xu.y, p0, p1); unp2(au.y, q0, q1); z[2] = p0 + q0; z[3] = p1 + q1;
    unp2(xu.z, p0, p1); unp2(au.z, q0, q1); z[4] = p0 + q0; z[5] = p1 + q1;
    unp2(xu.w, p0, p1); unp2(au.w, q0, q1); z[6] = p0 + q0; z[7] = p1 + q1;
  }
  float s = 0.f;
#pragma unroll
  for (int e = 0; e < 8; ++e) s += z[e];
#pragma unroll
  for (int off = 32; off; off >>= 1) s += __shfl_xor(s, off);
  const float mean = s * (1.f / 512.f);
  float ss = 0.f;
#pragma unroll
  for (int e = 0; e < 8; ++e) { float d = z[e] - mean; ss += d * d; }
#pragma unroll
  for (int off = 32; off; off >>= 1) ss += __shfl_xor(ss, off);
  const float inv = rsqrtf(ss * (1.f / 512.f) + 1e-5f);
  float4 g0 = *reinterpret_cast<const float4*>(gam + lane * 8);
  float4 g1 = *reinterpret_cast<const float4*>(gam + lane * 8 + 4);
  float4 b0 = *reinterpret_cast<const float4*>(bet + lane * 8);
  float4 b1 = *reinterpret_cast<const float4*>(bet + lane * 8 + 4);
  float o[8];
  o[0] = (z[0] - mean) * inv * g0.x + b0.x;
  o[1] = (z[1] - mean) * inv * g0.y + b0.y;
  o[2] = (z[2] - mean) * inv * g0.z + b0.z;
  o[3] = (z[3] - mean) * inv * g0.w + b0.w;
  o[4] = (z[4] - mean) * inv * g1.x + b1.x;
  o[5] = (z[5] - mean) * inv * g1.y + b1.y;
  o[6] = (z[6] - mean) * inv * g1.z + b1.z;
  o[7] = (z[7] - mean) * inv * g1.w + b1.w;
  if (OUT == 0) {
    uint4 w;
    w.x = (unsigned)f2b(o[0]) | ((unsigned)f2b(o[1]) << 16);
    w.y = (unsigned)f2b(o[2]) | ((unsigned)f2b(o[3]) << 16);
    w.z = (unsigned)f2b(o[4]) | ((unsigned)f2b(o[5]) << 16);
    w.w = (unsigned)f2b(o[6]) | ((unsigned)f2b(o[7]) << 16);
    *reinterpret_cast<uint4*>(outb + base) = w;
  } else {
    float4 f0, f1;
    f0.x = o[0]; f0.y = o[1]; f0.z = o[2]; f0.w = o[3];
    f1.x = o[4]; f1.y = o[5]; f1.z = o[6]; f1.w = o[7];
    *reinterpret_cast<float4*>(outf + base) = f0;
    *reinterpret_cast<float4*>(outf + base + 4) = f1;
  }
}

// ---------------- balance ----------------
__global__ void balance_kernel(const float* __restrict__ fP, float* __restrict__ out) {
  if (threadIdx.x == 0 && blockIdx.x == 0) {
    float fs = 0.f, pssum = 0.f, P[6];
    for (int j = 0; j < 6; ++j) {
      fs += fP[j];
      P[j] = fP[6 + j] * (1.f / (float)MROWS);
      pssum += P[j];
    }
    float bal = 0.f;
    for (int j = 0; j < 6; ++j)
      bal += (fP[j] / (fs + 1e-5f)) * (P[j] / (pssum + 1e-5f));
    out[0] = bal;
  }
}

// ---------------- host ----------------
extern "C" void kernel_launch(void* const* d_in, const int* in_sizes, int n_in,
                              void* d_out, int out_size, void* d_ws, size_t ws_size,
                              hipStream_t stream) {
  (void)in_sizes; (void)n_in; (void)out_size; (void)ws_size;
  const float* q_embed  = (const float*)d_in[0];
  const float* qa_embed = (const float*)d_in[1];
  const float* Wq  = (const float*)d_in[2];
  const float* bq  = (const float*)d_in[3];
  const float* Wv  = (const float*)d_in[4];
  const float* bv  = (const float*)d_in[5];
  const float* Wg  = (const float*)d_in[6];
  const float* Wo  = (const float*)d_in[7];
  const float* bo  = (const float*)d_in[8];
  const float* ln1g = (const float*)d_in[9];
  const float* ln1b = (const float*)d_in[10];
  const float* W1  = (const float*)d_in[11];
  const float* b1  = (const float*)d_in[12];
  const float* W2  = (const float*)d_in[13];
  const float* b2  = (const float*)d_in[14];
  const float* ln2g = (const float*)d_in[15];
  const float* ln2b = (const float*)d_in[16];

  char* p = (char*)d_ws;
  auto alloc = [&](size_t bytes) -> char* {
    char* r = p; p += (bytes + 255) & ~(size_t)255; return r;
  };
  const size_t WDE = (size_t)NL * DM * DM;   // stacked weight elems (per tensor)
  const size_t AE  = (size_t)MROWS * DM;     // activation elems
  bf16_t* wall_b = (bf16_t*)alloc(5 * WDE * 2);   // wq|wv|wo|w1|w2 contiguous
  bf16_t* wq_b = wall_b;
  bf16_t* wv_b = wall_b + WDE;
  bf16_t* wo_b = wall_b + 2 * WDE;
  bf16_t* w1_b = wall_b + 3 * WDE;
  bf16_t* w2_b = wall_b + 4 * WDE;
  bf16_t* y_b   = (bf16_t*)alloc(AE * 2);
  bf16_t* x_b   = (bf16_t*)alloc(AE * 2);
  bf16_t* qv_b  = (bf16_t*)alloc((size_t)MROWS * QVLD * 2);  // q|v merged
  bf16_t* ctx_b = (bf16_t*)alloc(AE * 2);
  bf16_t* x1_b  = (bf16_t*)alloc(AE * 2);
  bf16_t* tmp_b = (bf16_t*)alloc(AE * 2);
  bf16_t* ffn1_b = (bf16_t*)alloc(AE * 2);
  float* rdyn = (float*)alloc(BSZ * 6 * 4);
  float* fP   = (float*)alloc(NL * 12 * 4);

  hipMemsetAsync(fP, 0, NL * 12 * 4, stream);

  // weights -> bf16 (one launch, 5 tensors)
  f2bw_kernel<<<dim3((unsigned)(WDE / 4 / 256), 5), 256, 0, stream>>>(
      Wq, Wv, Wo, W1, W2, wall_b);
  // initial activations -> bf16
  f2b_kernel<<<2048, 256, 0, stream>>>(qa_embed, y_b, (int)(AE / 4));
  f2b_kernel<<<2048, 256, 0, stream>>>(q_embed, x_b, (int)(AE / 4));

  const size_t DD = (size_t)DM * DM;
  dim3 gqv(8, 128), gn5(4, 256);
  float* outx = (float*)d_out;

  auto layer = [&](int i, bf16_t* resb, const bf16_t* xvb, int strict, bool last) {
    hipMemsetAsync(rdyn, 0, BSZ * 6 * 4, stream);
    gemm_qv<<<gqv, 256, 0, stream>>>(
        resb, xvb, wq_b + i * DD, wv_b + i * DD, bq + i * DM, bv + i * DM, qv_b);
    gates_kernel<<<MROWS / 64, 256, 0, stream>>>(qv_b, Wg + (size_t)i * HD_ * DM, rdyn, fP + i * 12);
    rowzero_kernel<<<dim3(NH, BSZ), 256, 0, stream>>>(qv_b, rdyn, ctx_b);
    fattn_kernel<<<dim3(2, NH, BSZ), 256, 0, stream>>>(qv_b, rdyn, ctx_b, strict);
    gemm_n512<false><<<gn5, 256, 0, stream>>>(ctx_b, wo_b + i * DD, bo + i * DM, tmp_b);
    add_ln_kernel<0><<<MROWS / 4, 256, 0, stream>>>(
        resb, tmp_b, ln1g + i * DM, ln1b + i * DM, x1_b, nullptr);
    gemm_n512<true><<<gn5, 256, 0, stream>>>(x1_b, w1_b + i * DD, b1 + i * DM, ffn1_b);
    gemm_n512<false><<<gn5, 256, 0, stream>>>(ffn1_b, w2_b + i * DD, b2 + i * DM, tmp_b);
    if (last)
      add_ln_kernel<1><<<MROWS / 4, 256, 0, stream>>>(
          x1_b, tmp_b, ln2g + i * DM, ln2b + i * DM, nullptr, outx);
    else
      add_ln_kernel<0><<<MROWS / 4, 256, 0, stream>>>(
          x1_b, tmp_b, ln2g + i * DM, ln2b + i * DM, resb, nullptr);
  };

  layer(0, y_b, y_b, 0, false);
  layer(1, y_b, y_b, 0, false);
  layer(2, x_b, x_b, 0, false);
  layer(3, x_b, y_b, 1, false);
  layer(4, x_b, x_b, 0, false);
  layer(5, x_b, y_b, 1, true);
  balance_kernel<<<1, 64, 0, stream>>>(fP + 5 * 12, outx + (size_t)MROWS * DM);
}

// Round 7
// 1024.078 us; speedup vs baseline: 9.9168x; 1.0254x over previous
//
#include <hip/hip_runtime.h>
#include <cstdint>

// ---------------- constants ----------------
#define BSZ 32
#define SEQ 512
#define DM  512
#define NH  8
#define DK  64
#define HS_ 2
#define HD_ 6
#define NL  6
#define MROWS (BSZ*SEQ)          // 16384
#define QVLD 1024                // row stride of merged q|v buffer
#define SCL 0.18033688011112043f // 0.125 * log2(e)  (exp2 domain)

typedef unsigned short bf16_t;
typedef __attribute__((ext_vector_type(4))) float f32x4;
typedef __attribute__((ext_vector_type(8))) short bf16x8;
typedef __attribute__((ext_vector_type(8))) unsigned short u16x8;

#define DEV static __device__ __forceinline__

DEV float bf2f(bf16_t b) {
  unsigned int u = ((unsigned int)b) << 16;
  float f; __builtin_memcpy(&f, &u, 4); return f;
}
DEV bf16_t f2b(float f) {  // RNE bf16 (finite inputs)
  unsigned int u; __builtin_memcpy(&u, &f, 4);
  unsigned int r = (u + 0x7fffu + ((u >> 16) & 1u)) >> 16;
  return (bf16_t)r;
}
DEV void unp2(unsigned int w, float& a, float& b) {
  unsigned int ua = w << 16, ub = w & 0xffff0000u;
  __builtin_memcpy(&a, &ua, 4); __builtin_memcpy(&b, &ub, 4);
}
DEV unsigned cvtpk(float lo, float hi) {
  unsigned r;
  asm("v_cvt_pk_bf16_f32 %0, %1, %2" : "=v"(r) : "v"(lo), "v"(hi));
  return r;
}

DEV void gload_lds16(const bf16_t* g, bf16_t* l) {
  __builtin_amdgcn_global_load_lds(
      (const __attribute__((address_space(1))) void*)g,
      (__attribute__((address_space(3))) void*)l, 16, 0, 0);
}

// ---------------- f32 -> bf16 converts ----------------
// two activation tensors in one launch: grid (AE/4/256, 2)
__global__ __launch_bounds__(256) void f2b2_kernel(
    const float* __restrict__ s0, const float* __restrict__ s1,
    bf16_t* __restrict__ d0, bf16_t* __restrict__ d1) {
  const float* s = blockIdx.y ? s1 : s0;
  bf16_t* d = blockIdx.y ? d1 : d0;
  const int i = blockIdx.x * 256 + threadIdx.x;
  float4 v = reinterpret_cast<const float4*>(s)[i];
  ushort4 o;
  o.x = f2b(v.x); o.y = f2b(v.y); o.z = f2b(v.z); o.w = f2b(v.w);
  reinterpret_cast<ushort4*>(d)[i] = o;
}

// 5 stacked weight tensors -> one contiguous bf16 arena. grid (1536, 5).
__global__ __launch_bounds__(256) void f2bw_kernel(
    const float* __restrict__ s0, const float* __restrict__ s1,
    const float* __restrict__ s2, const float* __restrict__ s3,
    const float* __restrict__ s4, bf16_t* __restrict__ dst) {
  const float* srcs[5] = {s0, s1, s2, s3, s4};
  const float* s = srcs[blockIdx.y];
  bf16_t* d = dst + (size_t)blockIdx.y * ((size_t)NL * DM * DM);
  const int i = blockIdx.x * 256 + threadIdx.x;
  float4 v = reinterpret_cast<const float4*>(s)[i];
  ushort4 o;
  o.x = f2b(v.x); o.y = f2b(v.y); o.z = f2b(v.z); o.w = f2b(v.w);
  reinterpret_cast<ushort4*>(d)[i] = o;
}

// ---------------- MFMA GEMM (128x128 tile, BK=64): qv projection ----------------
__global__ __launch_bounds__(256) void gemm_qv(
    const bf16_t* __restrict__ A0, const bf16_t* __restrict__ A1,
    const bf16_t* __restrict__ W0, const bf16_t* __restrict__ W1,
    const float* __restrict__ b0, const float* __restrict__ b1,
    bf16_t* __restrict__ Yb) {
  const int K = 512;
  const int lin = blockIdx.y * 8 + blockIdx.x;
  const int swz = (lin & 7) * 128 + (lin >> 3);
  const int bn = swz & 7, bm = swz >> 3;
  const int tid = threadIdx.x, wid = tid >> 6, lane = tid & 63;
  const int wr = wid >> 1, wc = wid & 1;   // 2x2 wave grid, 64x64 each
  __shared__ __align__(16) bf16_t As[128 * 64];
  __shared__ __align__(16) bf16_t Bs[128 * 64];

  const bool hi = bn >= 4;
  const bf16_t* Asel = hi ? A1 : A0;
  const bf16_t* Wsel = hi ? (W1 - (size_t)512 * K) : W0;
  const float* bsel = hi ? (b1 - 512) : b0;

  f32x4 acc[4][4];
#pragma unroll
  for (int m = 0; m < 4; ++m)
#pragma unroll
    for (int n = 0; n < 4; ++n) acc[m][n] = f32x4{0.f, 0.f, 0.f, 0.f};

  const int lrow = lane & 15, lko = (lane >> 4) * 8;
  const int sr = wid * 8 + (lane >> 3), scol = (lane & 7) * 8;
  const size_t arow0 = (size_t)bm * 128, brow0 = (size_t)bn * 128;

  for (int k0 = 0; k0 < K; k0 += 64) {
#pragma unroll
    for (int i = 0; i < 4; ++i) {
      gload_lds16(Asel + (arow0 + i * 32 + sr) * K + k0 + scol, &As[(i * 4 + wid) * 512]);
      gload_lds16(Wsel + (brow0 + i * 32 + sr) * K + k0 + scol, &Bs[(i * 4 + wid) * 512]);
    }
    __syncthreads();
    bf16x8 af[4][2], bw[4][2];
#pragma unroll
    for (int m = 0; m < 4; ++m)
#pragma unroll
      for (int ks = 0; ks < 2; ++ks)
        af[m][ks] = *reinterpret_cast<const bf16x8*>(
            &As[(wr * 64 + m * 16 + lrow) * 64 + ks * 32 + lko]);
#pragma unroll
    for (int n = 0; n < 4; ++n)
#pragma unroll
      for (int ks = 0; ks < 2; ++ks)
        bw[n][ks] = *reinterpret_cast<const bf16x8*>(
            &Bs[(wc * 64 + n * 16 + lrow) * 64 + ks * 32 + lko]);
    __builtin_amdgcn_s_setprio(1);
#pragma unroll
    for (int ks = 0; ks < 2; ++ks)
#pragma unroll
      for (int m = 0; m < 4; ++m)
#pragma unroll
        for (int n = 0; n < 4; ++n)
          acc[m][n] = __builtin_amdgcn_mfma_f32_16x16x32_bf16(af[m][ks], bw[n][ks], acc[m][n], 0, 0, 0);
    __builtin_amdgcn_s_setprio(0);
    __syncthreads();
  }

  const int r0 = bm * 128 + wr * 64 + (lane >> 4) * 4;
  const int c0 = bn * 128 + wc * 64 + lrow;
#pragma unroll
  for (int n = 0; n < 4; ++n) {
    const int col = c0 + n * 16;
    const float bc = bsel[col];
#pragma unroll
    for (int m = 0; m < 4; ++m)
#pragma unroll
      for (int j = 0; j < 4; ++j)
        Yb[(size_t)(r0 + m * 16 + j) * QVLD + col] = f2b(acc[m][n][j] + bc);
  }
}

// ---------------- MFMA GEMM (64x128 tile, BK=64): N=512, bf16 out ----------------
template <bool RELU>
__global__ __launch_bounds__(256) void gemm_n512(
    const bf16_t* __restrict__ A, const bf16_t* __restrict__ W,
    const float* __restrict__ bias, bf16_t* __restrict__ Yb) {
  const int K = 512;
  const int lin = blockIdx.y * 4 + blockIdx.x;
  const int swz = (lin & 7) * 128 + (lin >> 3);
  const int bn = swz & 3, bm = swz >> 2;
  const int tid = threadIdx.x, wid = tid >> 6, lane = tid & 63;
  const int wr = wid >> 1, wc = wid & 1;   // 2x2 wave grid, 32x64 each
  __shared__ __align__(16) bf16_t As[64 * 64];
  __shared__ __align__(16) bf16_t Bs[128 * 64];

  f32x4 acc[2][4];
#pragma unroll
  for (int m = 0; m < 2; ++m)
#pragma unroll
    for (int n = 0; n < 4; ++n) acc[m][n] = f32x4{0.f, 0.f, 0.f, 0.f};

  const int lrow = lane & 15, lko = (lane >> 4) * 8;
  const int sr = wid * 8 + (lane >> 3), scol = (lane & 7) * 8;
  const size_t arow0 = (size_t)bm * 64, brow0 = (size_t)bn * 128;

  for (int k0 = 0; k0 < K; k0 += 64) {
#pragma unroll
    for (int i = 0; i < 2; ++i)
      gload_lds16(A + (arow0 + i * 32 + sr) * K + k0 + scol, &As[(i * 4 + wid) * 512]);
#pragma unroll
    for (int i = 0; i < 4; ++i)
      gload_lds16(W + (brow0 + i * 32 + sr) * K + k0 + scol, &Bs[(i * 4 + wid) * 512]);
    __syncthreads();
    bf16x8 af[2][2], bw[4][2];
#pragma unroll
    for (int m = 0; m < 2; ++m)
#pragma unroll
      for (int ks = 0; ks < 2; ++ks)
        af[m][ks] = *reinterpret_cast<const bf16x8*>(
            &As[(wr * 32 + m * 16 + lrow) * 64 + ks * 32 + lko]);
#pragma unroll
    for (int n = 0; n < 4; ++n)
#pragma unroll
      for (int ks = 0; ks < 2; ++ks)
        bw[n][ks] = *reinterpret_cast<const bf16x8*>(
            &Bs[(wc * 64 + n * 16 + lrow) * 64 + ks * 32 + lko]);
    __builtin_amdgcn_s_setprio(1);
#pragma unroll
    for (int ks = 0; ks < 2; ++ks)
#pragma unroll
      for (int m = 0; m < 2; ++m)
#pragma unroll
        for (int n = 0; n < 4; ++n)
          acc[m][n] = __builtin_amdgcn_mfma_f32_16x16x32_bf16(af[m][ks], bw[n][ks], acc[m][n], 0, 0, 0);
    __builtin_amdgcn_s_setprio(0);
    __syncthreads();
  }

  const int r0 = bm * 64 + wr * 32 + (lane >> 4) * 4;
  const int c0 = bn * 128 + wc * 64 + lrow;
#pragma unroll
  for (int n = 0; n < 4; ++n) {
    const int col = c0 + n * 16;
    const float bc = bias[col];
#pragma unroll
    for (int m = 0; m < 2; ++m)
#pragma unroll
      for (int j = 0; j < 4; ++j) {
        float v = acc[m][n][j] + bc;
        if (RELU) v = fmaxf(v, 0.f);
        Yb[(size_t)(r0 + m * 16 + j) * DM + col] = f2b(v);
      }
  }
}

// ---------------- gating: softmax(q @ Wg^T), top-4-of-6, fused routing ----------------
__global__ __launch_bounds__(256) void gates_kernel(
    const bf16_t* __restrict__ qv, const float* __restrict__ Wg,
    float* __restrict__ rdyn, float* __restrict__ fP) {
  __shared__ float wg_s[HD_ * DM];
  __shared__ float blk[4][18];
  const int tid = threadIdx.x, wid = tid >> 6, lane = tid & 63;
  for (int i = tid; i < HD_ * DM / 4; i += 256)
    reinterpret_cast<float4*>(wg_s)[i] = reinterpret_cast<const float4*>(Wg)[i];
  __syncthreads();
  const int bb = blockIdx.x >> 3;
  const int t0 = (blockIdx.x & 7) * 64 + wid * 16;
  float fs[6] = {0, 0, 0, 0, 0, 0}, ps[6] = {0, 0, 0, 0, 0, 0}, rs[6] = {0, 0, 0, 0, 0, 0};
  for (int it = 0; it < 16; ++it) {
    const int tok = bb * SEQ + t0 + it;
    uint4 u = reinterpret_cast<const uint4*>(qv + (size_t)tok * QVLD)[lane];
    float x[8];
    unp2(u.x, x[0], x[1]); unp2(u.y, x[2], x[3]);
    unp2(u.z, x[4], x[5]); unp2(u.w, x[6], x[7]);
    float g[6];
#pragma unroll
    for (int j = 0; j < 6; ++j) {
      float p = 0.f;
#pragma unroll
      for (int e = 0; e < 8; ++e) p = fmaf(x[e], wg_s[j * DM + lane * 8 + e], p);
#pragma unroll
      for (int off = 32; off; off >>= 1) p += __shfl_xor(p, off);
      g[j] = p;
    }
    float mx = g[0];
#pragma unroll
    for (int j = 1; j < 6; ++j) mx = fmaxf(mx, g[j]);
    float se = 0.f;
#pragma unroll
    for (int j = 0; j < 6; ++j) { g[j] = __expf(g[j] - mx); se += g[j]; }
    float inv = 1.f / se;
#pragma unroll
    for (int j = 0; j < 6; ++j) g[j] *= inv;
    int d1 = 0;
#pragma unroll
    for (int j = 1; j < 6; ++j)
      if (g[j] < g[d1] || (g[j] == g[d1] && j > d1)) d1 = j;
    int d2 = (d1 == 0) ? 1 : 0;
#pragma unroll
    for (int j = 0; j < 6; ++j) {
      if (j == d1) continue;
      if (g[j] < g[d2] || (g[j] == g[d2] && j > d2)) d2 = j;
    }
#pragma unroll
    for (int j = 0; j < 6; ++j) {
      const bool drop = (j == d1) || (j == d2);
      fs[j] += drop ? 0.f : 1.f;
      ps[j] += g[j];
      rs[j] += drop ? 0.f : g[j];
    }
  }
  if (lane == 0) {
#pragma unroll
    for (int j = 0; j < 6; ++j) {
      blk[wid][j] = fs[j]; blk[wid][6 + j] = ps[j]; blk[wid][12 + j] = rs[j];
    }
  }
  __syncthreads();
  if (tid < 18) {
    float s = blk[0][tid] + blk[1][tid] + blk[2][tid] + blk[3][tid];
    if (tid < 12) atomicAdd(&fP[tid], s);
    else atomicAdd(&rdyn[bb * 6 + (tid - 12)], s * (1.f / 512.f));
  }
}

// ---------------- fused flash attention (MFMA, dbuf pipeline, row0 fused) -----
// grid (2, 8, 32), 256 thr. Block bx owns q-tiles {bx, 3-bx}. Double-buffered
// K/V staging: issue stage(kt+1) -> compute(kt) -> write V(kt+1) -> barrier.
// Block bx==0 stages all 8 V tiles -> accumulates colsum for the row-0 quirk.
__global__ __launch_bounds__(256, 2) void fattn_kernel(
    const bf16_t* __restrict__ qv, const float* __restrict__ rdyn,
    bf16_t* __restrict__ ctx, int strict) {
  const int lin = (blockIdx.z * 8 + blockIdx.y) * 2 + blockIdx.x;
  const int swz = (lin & 7) * 64 + (lin >> 3);
  const int bx = swz & 1, h = (swz >> 1) & 7, b = swz >> 4;
  const int tid = threadIdx.x, wid = tid >> 6, lane = tid & 63;
  const int c0 = lane & 15, grp = lane >> 4;
  const int l3 = lane >> 3, c3 = lane & 7;
  const int kidx = lane & 31, dhalf = lane >> 5;

  __shared__ __align__(16) bf16_t Ks[2][64 * 64];     // swizzled [64k][64ch]
  __shared__ __align__(16) bf16_t Vt[2][64 * 72];     // transposed [64d][64k+8pad]
  __shared__ __align__(16) bf16_t Ps[4][32 * 64];     // per-wave P, swizzled
  __shared__ float csum[64];

  const bf16_t* qp = qv;          // q half, row stride QVLD
  const bf16_t* vp = qv + 512;    // v half
  const float factor = (h < HS_) ? 1.f : rdyn[b * 6 + (h - HS_)];

  const int qtA = bx, qtB = 3 - bx;                   // qtA < qtB
  const int qbaseA = qtA * 128 + wid * 32;
  const int qbaseB = qtB * 128 + wid * 32;

  bf16x8 qfA[2][2], qfB[2][2];
#pragma unroll
  for (int nt = 0; nt < 2; ++nt)
#pragma unroll
    for (int ks = 0; ks < 2; ++ks) {
      qfA[nt][ks] = *reinterpret_cast<const bf16x8*>(
          qp + ((size_t)(b * SEQ + qbaseA + nt * 16 + c0)) * QVLD + h * DK + ks * 32 + grp * 8);
      qfB[nt][ks] = *reinterpret_cast<const bf16x8*>(
          qp + ((size_t)(b * SEQ + qbaseB + nt * 16 + c0)) * QVLD + h * DK + ks * 32 + grp * 8);
    }

  f32x4 accA[2][4], accB[2][4];
#pragma unroll
  for (int m = 0; m < 2; ++m)
#pragma unroll
    for (int d = 0; d < 4; ++d) {
      accA[m][d] = f32x4{0.f, 0.f, 0.f, 0.f};
      accB[m][d] = f32x4{0.f, 0.f, 0.f, 0.f};
    }
  float mA[2] = {-3e38f, -3e38f}, lA[2] = {0.f, 0.f};
  float mB[2] = {-3e38f, -3e38f}, lB[2] = {0.f, 0.f};
  float cs[8] = {0, 0, 0, 0, 0, 0, 0, 0};   // V column-sum partials (bx==0)

  const int lastA = (qbaseA + 31 - strict) >> 6;
  const int lastB = (qbaseB + 31 - strict) >> 6;
  const int ktmax = 2 * qtB + 1;

  auto stageK = [&](int kt, bf16_t* dst) {
#pragma unroll
    for (int i = 0; i < 2; ++i) {
      int row = i * 32 + wid * 8 + l3;
      int blk = c3 ^ l3;
      gload_lds16(qp + ((size_t)(b * SEQ + kt * 64 + row)) * QVLD + h * DK + blk * 8,
                  dst + (i * 32 + wid * 8) * 64);
    }
  };
  auto loadV = [&](int kt, ushort4 (&lo)[2], ushort4 (&hv)[2]) {
#pragma unroll
    for (int j = 0; j < 2; ++j) {
      const int d0 = (wid * 2 + j) * 8 + dhalf * 4;
      const bf16_t* src = vp + ((size_t)(b * SEQ + kt * 64 + 2 * kidx)) * QVLD + h * DK + d0;
      lo[j] = *reinterpret_cast<const ushort4*>(src);
      hv[j] = *reinterpret_cast<const ushort4*>(src + QVLD);
    }
  };
  auto writeV = [&](bf16_t* Vtb, ushort4 (&lo)[2], ushort4 (&hv)[2]) {
#pragma unroll
    for (int j = 0; j < 2; ++j) {
      const int d0 = (wid * 2 + j) * 8 + dhalf * 4;
      *reinterpret_cast<unsigned*>(&Vtb[(d0 + 0) * 72 + 2 * kidx]) = (unsigned)lo[j].x | ((unsigned)hv[j].x << 16);
      *reinterpret_cast<unsigned*>(&Vtb[(d0 + 1) * 72 + 2 * kidx]) = (unsigned)lo[j].y | ((unsigned)hv[j].y << 16);
      *reinterpret_cast<unsigned*>(&Vtb[(d0 + 2) * 72 + 2 * kidx]) = (unsigned)lo[j].z | ((unsigned)hv[j].z << 16);
      *reinterpret_cast<unsigned*>(&Vtb[(d0 + 3) * 72 + 2 * kidx]) = (unsigned)lo[j].w | ((unsigned)hv[j].w << 16);
      if (bx == 0) {
        cs[j * 4 + 0] += bf2f(lo[j].x) + bf2f(hv[j].x);
        cs[j * 4 + 1] += bf2f(lo[j].y) + bf2f(hv[j].y);
        cs[j * 4 + 2] += bf2f(lo[j].z) + bf2f(hv[j].z);
        cs[j * 4 + 3] += bf2f(lo[j].w) + bf2f(hv[j].w);
      }
    }
  };

  auto do_tile = [&](bf16x8 (&qf)[2][2], f32x4 (&acc)[2][4], float (&mreg)[2],
                     float (&lreg)[2], int qbase, bool masked, int kt,
                     const bf16_t* Ksb, const bf16_t* Vtb) {
    const char* KsB = (const char*)Ksb;
    bf16x8 kf[4][2];
#pragma unroll
    for (int mt = 0; mt < 4; ++mt)
#pragma unroll
      for (int ks = 0; ks < 2; ++ks)
        kf[mt][ks] = *reinterpret_cast<const bf16x8*>(
            KsB + (mt * 16 + c0) * 128 + 16 * ((4 * ks + grp) ^ (c0 & 7)));
    f32x4 s[4][2];
#pragma unroll
    for (int mt = 0; mt < 4; ++mt)
#pragma unroll
      for (int nt = 0; nt < 2; ++nt) s[mt][nt] = f32x4{0.f, 0.f, 0.f, 0.f};
    __builtin_amdgcn_s_setprio(1);
#pragma unroll
    for (int mt = 0; mt < 4; ++mt)
#pragma unroll
      for (int nt = 0; nt < 2; ++nt)
#pragma unroll
        for (int ks = 0; ks < 2; ++ks)
          s[mt][nt] = __builtin_amdgcn_mfma_f32_16x16x32_bf16(
              kf[mt][ks], qf[nt][ks], s[mt][nt], 0, 0, 0);
    __builtin_amdgcn_s_setprio(0);

    float sc[2];
#pragma unroll
    for (int nt = 0; nt < 2; ++nt) {
      const int q = qbase + nt * 16 + c0;
#pragma unroll
      for (int mt = 0; mt < 4; ++mt)
#pragma unroll
        for (int j = 0; j < 4; ++j) {
          int k = kt * 64 + mt * 16 + grp * 4 + j;
          float t = s[mt][nt][j] * SCL;        // exp2 domain
          if (masked && (k + strict > q)) t = -1e30f;
          s[mt][nt][j] = t;
        }
      float mx = -3e38f;
#pragma unroll
      for (int mt = 0; mt < 4; ++mt)
#pragma unroll
        for (int j = 0; j < 4; ++j) mx = fmaxf(mx, s[mt][nt][j]);
      mx = fmaxf(mx, __shfl_xor(mx, 16));
      mx = fmaxf(mx, __shfl_xor(mx, 32));
      const float mnew = fmaxf(mreg[nt], mx);
      sc[nt] = exp2f(mreg[nt] - mnew);
      mreg[nt] = mnew;
      float ts = 0.f;
#pragma unroll
      for (int mt = 0; mt < 4; ++mt)
#pragma unroll
        for (int j = 0; j < 4; ++j) {
          float pp = exp2f(s[mt][nt][j] - mnew);
          s[mt][nt][j] = pp; ts += pp;
        }
      ts += __shfl_xor(ts, 16);
      ts += __shfl_xor(ts, 32);
      lreg[nt] = lreg[nt] * sc[nt] + ts;
    }
    char* PsB = (char*)(&Ps[wid][0]);
#pragma unroll
    for (int nt = 0; nt < 2; ++nt)
#pragma unroll
      for (int mt = 0; mt < 4; ++mt) {
        uint2 w;
        w.x = cvtpk(s[mt][nt][0], s[mt][nt][1]);
        w.y = cvtpk(s[mt][nt][2], s[mt][nt][3]);
        int row = nt * 16 + c0;
        int off = (row * 128 + mt * 32 + grp * 8) ^ ((c0 & 7) << 4);
        *reinterpret_cast<uint2*>(PsB + off) = w;
      }
#pragma unroll
    for (int mtq = 0; mtq < 2; ++mtq) {
      f32x4 sv;
#pragma unroll
      for (int j = 0; j < 4; ++j) sv[j] = __shfl(sc[mtq], grp * 4 + j);
#pragma unroll
      for (int dt = 0; dt < 4; ++dt) acc[mtq][dt] *= sv;
    }
    bf16x8 pf[2][2], vf2[4][2];
#pragma unroll
    for (int mtq = 0; mtq < 2; ++mtq)
#pragma unroll
      for (int ks = 0; ks < 2; ++ks)
        pf[mtq][ks] = *reinterpret_cast<const bf16x8*>(
            PsB + (mtq * 16 + c0) * 128 + 16 * ((4 * ks + grp) ^ (c0 & 7)));
#pragma unroll
    for (int dt = 0; dt < 4; ++dt)
#pragma unroll
      for (int ks = 0; ks < 2; ++ks)
        vf2[dt][ks] = *reinterpret_cast<const bf16x8*>(
            (const char*)Vtb + (dt * 16 + c0) * 144 + ks * 64 + grp * 16);
    __builtin_amdgcn_s_setprio(1);
#pragma unroll
    for (int mtq = 0; mtq < 2; ++mtq)
#pragma unroll
      for (int dt = 0; dt < 4; ++dt)
#pragma unroll
        for (int ks = 0; ks < 2; ++ks)
          acc[mtq][dt] = __builtin_amdgcn_mfma_f32_16x16x32_bf16(
              pf[mtq][ks], vf2[dt][ks], acc[mtq][dt], 0, 0, 0);
    __builtin_amdgcn_s_setprio(0);
  };

  // ---- prologue: tile 0 into buffer 0 ----
  {
    ushort4 lo[2], hv[2];
    stageK(0, Ks[0]);
    loadV(0, lo, hv);
    writeV(Vt[0], lo, hv);
    __syncthreads();   // drains K DMA (vmcnt) + V ds_writes (lgkm)
  }

  int cbuf = 0;
  for (int kt = 0; kt <= ktmax; ++kt, cbuf ^= 1) {
    ushort4 lo[2], hv[2];
    const bool pref = kt < ktmax;
    if (pref) {
      stageK(kt + 1, Ks[cbuf ^ 1]);   // DMA into other buffer
      loadV(kt + 1, lo, hv);          // regs; latency hidden under compute
    }
    if (kt <= lastB) do_tile(qfB, accB, mB, lB, qbaseB, kt == lastB, kt, Ks[cbuf], Vt[cbuf]);
    if (kt <= lastA) do_tile(qfA, accA, mA, lA, qbaseA, kt == lastA, kt, Ks[cbuf], Vt[cbuf]);
    if (pref) writeV(Vt[cbuf ^ 1], lo, hv);
    __syncthreads();
  }

  // ---- row-0 quirk: ctx[b,0,h,:] = factor * mean_k V (block bx==0 only) ----
  if (bx == 0) {
#pragma unroll
    for (int e = 0; e < 8; ++e)
#pragma unroll
      for (int off = 1; off <= 16; off <<= 1) cs[e] += __shfl_xor(cs[e], off);
    if ((lane & 31) == 0) {
#pragma unroll
      for (int e = 0; e < 8; ++e)
        csum[(wid * 2 + (e >> 2)) * 8 + dhalf * 4 + (e & 3)] = cs[e];
    }
  }
  __syncthreads();
  if (bx == 0 && tid < 64)
    ctx[((size_t)(b * SEQ)) * DM + h * DK + tid] = f2b(csum[tid] * (1.f / 512.f) * factor);

  // ---- epilogues: /l, *routing, store (skip q==0) ----
#pragma unroll
  for (int e = 0; e < 2; ++e) {
    const int qbase = e ? qbaseB : qbaseA;
    f32x4 (&acc)[2][4] = e ? accB : accA;
    float (&lreg)[2] = e ? lB : lA;
#pragma unroll
    for (int mtq = 0; mtq < 2; ++mtq) {
      const float inv = factor / lreg[mtq];
      f32x4 iv;
#pragma unroll
      for (int j = 0; j < 4; ++j) iv[j] = __shfl(inv, grp * 4 + j);
#pragma unroll
      for (int j = 0; j < 4; ++j) {
        const int q = qbase + mtq * 16 + grp * 4 + j;
        if (q == 0) continue;
#pragma unroll
        for (int dt = 0; dt < 4; ++dt)
          ctx[((size_t)(b * SEQ + q)) * DM + h * DK + dt * 16 + c0] =
              f2b(acc[mtq][dt][j] * iv[j]);
      }
    }
  }
}

// ---------------- add + layernorm: wave-per-row, bf16 residual ----------------
template <int OUT>
__global__ __launch_bounds__(256) void add_ln_kernel(
    const bf16_t* __restrict__ X, const bf16_t* __restrict__ A2,
    const float* __restrict__ gam, const float* __restrict__ bet,
    bf16_t* __restrict__ outb, float* __restrict__ outf) {
  const int wid = threadIdx.x >> 6, lane = threadIdx.x & 63;
  const size_t row = (size_t)blockIdx.x * 4 + wid;
  const size_t base = row * DM + lane * 8;
  uint4 xu = *reinterpret_cast<const uint4*>(X + base);
  uint4 au = *reinterpret_cast<const uint4*>(A2 + base);
  float z[8];
  {
    float p0, p1, q0, q1;
    unp2(xu.x, p0, p1); unp2(au.x, q0, q1); z[0] = p0 + q0; z[1] = p1 + q1;
    unp2(xu.y, p0, p1); unp2(au.y, q0, q1); z[2] = p0 + q0; z[3] = p1 + q1;
    unp2(xu.z, p0, p1); unp2(au.z, q0, q1); z[4] = p0 + q0; z[5] = p1 + q1;
    unp2(xu.w, p0, p1); unp2(au.w, q0, q1); z[6] = p0 + q0; z[7] = p1 + q1;
  }
  float s = 0.f;
#pragma unroll
  for (int e = 0; e < 8; ++e) s += z[e];
#pragma unroll
  for (int off = 32; off; off >>= 1) s += __shfl_xor(s, off);
  const float mean = s * (1.f / 512.f);
  float ss = 0.f;
#pragma unroll
  for (int e = 0; e < 8; ++e) { float d = z[e] - mean; ss += d * d; }
#pragma unroll
  for (int off = 32; off; off >>= 1) ss += __shfl_xor(ss, off);
  const float inv = rsqrtf(ss * (1.f / 512.f) + 1e-5f);
  float4 g0 = *reinterpret_cast<const float4*>(gam + lane * 8);
  float4 g1 = *reinterpret_cast<const float4*>(gam + lane * 8 + 4);
  float4 b0 = *reinterpret_cast<const float4*>(bet + lane * 8);
  float4 b1 = *reinterpret_cast<const float4*>(bet + lane * 8 + 4);
  float o[8];
  o[0] = (z[0] - mean) * inv * g0.x + b0.x;
  o[1] = (z[1] - mean) * inv * g0.y + b0.y;
  o[2] = (z[2] - mean) * inv * g0.z + b0.z;
  o[3] = (z[3] - mean) * inv * g0.w + b0.w;
  o[4] = (z[4] - mean) * inv * g1.x + b1.x;
  o[5] = (z[5] - mean) * inv * g1.y + b1.y;
  o[6] = (z[6] - mean) * inv * g1.z + b1.z;
  o[7] = (z[7] - mean) * inv * g1.w + b1.w;
  if (OUT == 0) {
    uint4 w;
    w.x = (unsigned)f2b(o[0]) | ((unsigned)f2b(o[1]) << 16);
    w.y = (unsigned)f2b(o[2]) | ((unsigned)f2b(o[3]) << 16);
    w.z = (unsigned)f2b(o[4]) | ((unsigned)f2b(o[5]) << 16);
    w.w = (unsigned)f2b(o[6]) | ((unsigned)f2b(o[7]) << 16);
    *reinterpret_cast<uint4*>(outb + base) = w;
  } else {
    float4 f0, f1;
    f0.x = o[0]; f0.y = o[1]; f0.z = o[2]; f0.w = o[3];
    f1.x = o[4]; f1.y = o[5]; f1.z = o[6]; f1.w = o[7];
    *reinterpret_cast<float4*>(outf + base) = f0;
    *reinterpret_cast<float4*>(outf + base + 4) = f1;
  }
}

// ---------------- balance ----------------
__global__ void balance_kernel(const float* __restrict__ fP, float* __restrict__ out) {
  if (threadIdx.x == 0 && blockIdx.x == 0) {
    float fs = 0.f, pssum = 0.f, P[6];
    for (int j = 0; j < 6; ++j) {
      fs += fP[j];
      P[j] = fP[6 + j] * (1.f / (float)MROWS);
      pssum += P[j];
    }
    float bal = 0.f;
    for (int j = 0; j < 6; ++j)
      bal += (fP[j] / (fs + 1e-5f)) * (P[j] / (pssum + 1e-5f));
    out[0] = bal;
  }
}

// ---------------- host ----------------
extern "C" void kernel_launch(void* const* d_in, const int* in_sizes, int n_in,
                              void* d_out, int out_size, void* d_ws, size_t ws_size,
                              hipStream_t stream) {
  (void)in_sizes; (void)n_in; (void)out_size; (void)ws_size;
  const float* q_embed  = (const float*)d_in[0];
  const float* qa_embed = (const float*)d_in[1];
  const float* Wq  = (const float*)d_in[2];
  const float* bq  = (const float*)d_in[3];
  const float* Wv  = (const float*)d_in[4];
  const float* bv  = (const float*)d_in[5];
  const float* Wg  = (const float*)d_in[6];
  const float* Wo  = (const float*)d_in[7];
  const float* bo  = (const float*)d_in[8];
  const float* ln1g = (const float*)d_in[9];
  const float* ln1b = (const float*)d_in[10];
  const float* W1  = (const float*)d_in[11];
  const float* b1  = (const float*)d_in[12];
  const float* W2  = (const float*)d_in[13];
  const float* b2  = (const float*)d_in[14];
  const float* ln2g = (const float*)d_in[15];
  const float* ln2b = (const float*)d_in[16];

  char* p = (char*)d_ws;
  auto alloc = [&](size_t bytes) -> char* {
    char* r = p; p += (bytes + 255) & ~(size_t)255; return r;
  };
  const size_t WDE = (size_t)NL * DM * DM;   // stacked weight elems (per tensor)
  const size_t AE  = (size_t)MROWS * DM;     // activation elems
  bf16_t* wall_b = (bf16_t*)alloc(5 * WDE * 2);   // wq|wv|wo|w1|w2 contiguous
  bf16_t* wq_b = wall_b;
  bf16_t* wv_b = wall_b + WDE;
  bf16_t* wo_b = wall_b + 2 * WDE;
  bf16_t* w1_b = wall_b + 3 * WDE;
  bf16_t* w2_b = wall_b + 4 * WDE;
  bf16_t* y_b   = (bf16_t*)alloc(AE * 2);
  bf16_t* x_b   = (bf16_t*)alloc(AE * 2);
  bf16_t* qv_b  = (bf16_t*)alloc((size_t)MROWS * QVLD * 2);  // q|v merged
  bf16_t* ctx_b = (bf16_t*)alloc(AE * 2);
  bf16_t* x1_b  = (bf16_t*)alloc(AE * 2);
  bf16_t* tmp_b = (bf16_t*)alloc(AE * 2);
  bf16_t* ffn1_b = (bf16_t*)alloc(AE * 2);
  float* stats = (float*)alloc(NL * (12 + BSZ * 6) * 4);  // fP[NL][12] | rdyn[NL][32][6]
  float* fPbase = stats;
  float* rdynbase = stats + NL * 12;

  hipMemsetAsync(stats, 0, NL * (12 + BSZ * 6) * 4, stream);

  // weights -> bf16 (one launch, 5 tensors); activations (one launch, 2 tensors)
  f2bw_kernel<<<dim3((unsigned)(WDE / 4 / 256), 5), 256, 0, stream>>>(
      Wq, Wv, Wo, W1, W2, wall_b);
  f2b2_kernel<<<dim3((unsigned)(AE / 4 / 256), 2), 256, 0, stream>>>(
      qa_embed, q_embed, y_b, x_b);

  const size_t DD = (size_t)DM * DM;
  dim3 gqv(8, 128), gn5(4, 256);
  float* outx = (float*)d_out;

  auto layer = [&](int i, bf16_t* resb, const bf16_t* xvb, int strict, bool last) {
    float* fP = fPbase + i * 12;
    float* rdyn = rdynbase + i * (BSZ * 6);
    gemm_qv<<<gqv, 256, 0, stream>>>(
        resb, xvb, wq_b + i * DD, wv_b + i * DD, bq + i * DM, bv + i * DM, qv_b);
    gates_kernel<<<MROWS / 64, 256, 0, stream>>>(qv_b, Wg + (size_t)i * HD_ * DM, rdyn, fP);
    fattn_kernel<<<dim3(2, NH, BSZ), 256, 0, stream>>>(qv_b, rdyn, ctx_b, strict);
    gemm_n512<false><<<gn5, 256, 0, stream>>>(ctx_b, wo_b + i * DD, bo + i * DM, tmp_b);
    add_ln_kernel<0><<<MROWS / 4, 256, 0, stream>>>(
        resb, tmp_b, ln1g + i * DM, ln1b + i * DM, x1_b, nullptr);
    gemm_n512<true><<<gn5, 256, 0, stream>>>(x1_b, w1_b + i * DD, b1 + i * DM, ffn1_b);
    gemm_n512<false><<<gn5, 256, 0, stream>>>(ffn1_b, w2_b + i * DD, b2 + i * DM, tmp_b);
    if (last)
      add_ln_kernel<1><<<MROWS / 4, 256, 0, stream>>>(
          x1_b, tmp_b, ln2g + i * DM, ln2b + i * DM, nullptr, outx);
    else
      add_ln_kernel<0><<<MROWS / 4, 256, 0, stream>>>(
          x1_b, tmp_b, ln2g + i * DM, ln2b + i * DM, resb, nullptr);
  };

  layer(0, y_b, y_b, 0, false);
  layer(1, y_b, y_b, 0, false);
  layer(2, x_b, x_b, 0, false);
  layer(3, x_b, y_b, 1, false);
  layer(4, x_b, x_b, 0, false);
  layer(5, x_b, y_b, 1, true);
  balance_kernel<<<1, 64, 0, stream>>>(fPbase + 5 * 12, outx + (size_t)MROWS * DM);
}

// Round 8
// 1013.238 us; speedup vs baseline: 10.0229x; 1.0107x over previous
//
#include <hip/hip_runtime.h>
#include <cstdint>

// ---------------- constants ----------------
#define BSZ 32
#define SEQ 512
#define DM  512
#define NH  8
#define DK  64
#define HS_ 2
#define HD_ 6
#define NL  6
#define MROWS (BSZ*SEQ)          // 16384
#define QVLD 1024                // row stride of merged q|v buffer
#define SCL 0.18033688011112043f // 0.125 * log2(e)  (exp2 domain)

typedef unsigned short bf16_t;
typedef __attribute__((ext_vector_type(4))) float f32x4;
typedef __attribute__((ext_vector_type(8))) short bf16x8;
typedef __attribute__((ext_vector_type(8))) unsigned short u16x8;

#define DEV static __device__ __forceinline__

DEV float bf2f(bf16_t b) {
  unsigned int u = ((unsigned int)b) << 16;
  float f; __builtin_memcpy(&f, &u, 4); return f;
}
DEV bf16_t f2b(float f) {  // RNE bf16 (finite inputs)
  unsigned int u; __builtin_memcpy(&u, &f, 4);
  unsigned int r = (u + 0x7fffu + ((u >> 16) & 1u)) >> 16;
  return (bf16_t)r;
}
DEV void unp2(unsigned int w, float& a, float& b) {
  unsigned int ua = w << 16, ub = w & 0xffff0000u;
  __builtin_memcpy(&a, &ua, 4); __builtin_memcpy(&b, &ub, 4);
}
DEV unsigned cvtpk(float lo, float hi) {
  unsigned r;
  asm("v_cvt_pk_bf16_f32 %0, %1, %2" : "=v"(r) : "v"(lo), "v"(hi));
  return r;
}

DEV void gload_lds16(const bf16_t* g, bf16_t* l) {
  __builtin_amdgcn_global_load_lds(
      (const __attribute__((address_space(1))) void*)g,
      (__attribute__((address_space(3))) void*)l, 16, 0, 0);
}

// scale a bf16x8 Q fragment by SCL (exp2-domain pre-scale)
DEV bf16x8 scale_q(bf16x8 v) {
  u16x8 u;
  __builtin_memcpy(&u, &v, 16);
  unsigned w[4];
#pragma unroll
  for (int e = 0; e < 4; ++e)
    w[e] = cvtpk(bf2f(u[2 * e]) * SCL, bf2f(u[2 * e + 1]) * SCL);
  bf16x8 r;
  __builtin_memcpy(&r, w, 16);
  return r;
}

// ---------------- f32 -> bf16 converts ----------------
__global__ __launch_bounds__(256) void f2b2_kernel(
    const float* __restrict__ s0, const float* __restrict__ s1,
    bf16_t* __restrict__ d0, bf16_t* __restrict__ d1) {
  const float* s = blockIdx.y ? s1 : s0;
  bf16_t* d = blockIdx.y ? d1 : d0;
  const int i = blockIdx.x * 256 + threadIdx.x;
  float4 v = reinterpret_cast<const float4*>(s)[i];
  ushort4 o;
  o.x = f2b(v.x); o.y = f2b(v.y); o.z = f2b(v.z); o.w = f2b(v.w);
  reinterpret_cast<ushort4*>(d)[i] = o;
}

__global__ __launch_bounds__(256) void f2bw_kernel(
    const float* __restrict__ s0, const float* __restrict__ s1,
    const float* __restrict__ s2, const float* __restrict__ s3,
    const float* __restrict__ s4, bf16_t* __restrict__ dst) {
  const float* srcs[5] = {s0, s1, s2, s3, s4};
  const float* s = srcs[blockIdx.y];
  bf16_t* d = dst + (size_t)blockIdx.y * ((size_t)NL * DM * DM);
  const int i = blockIdx.x * 256 + threadIdx.x;
  float4 v = reinterpret_cast<const float4*>(s)[i];
  ushort4 o;
  o.x = f2b(v.x); o.y = f2b(v.y); o.z = f2b(v.z); o.w = f2b(v.w);
  reinterpret_cast<ushort4*>(d)[i] = o;
}

// ---------------- MFMA GEMM (128x128 tile, BK=64): qv projection ----------------
__global__ __launch_bounds__(256) void gemm_qv(
    const bf16_t* __restrict__ A0, const bf16_t* __restrict__ A1,
    const bf16_t* __restrict__ W0, const bf16_t* __restrict__ W1,
    const float* __restrict__ b0, const float* __restrict__ b1,
    bf16_t* __restrict__ Yb) {
  const int K = 512;
  const int lin = blockIdx.y * 8 + blockIdx.x;
  const int swz = (lin & 7) * 128 + (lin >> 3);
  const int bn = swz & 7, bm = swz >> 3;
  const int tid = threadIdx.x, wid = tid >> 6, lane = tid & 63;
  const int wr = wid >> 1, wc = wid & 1;   // 2x2 wave grid, 64x64 each
  __shared__ __align__(16) bf16_t As[128 * 64];
  __shared__ __align__(16) bf16_t Bs[128 * 64];

  const bool hi = bn >= 4;
  const bf16_t* Asel = hi ? A1 : A0;
  const bf16_t* Wsel = hi ? (W1 - (size_t)512 * K) : W0;
  const float* bsel = hi ? (b1 - 512) : b0;

  f32x4 acc[4][4];
#pragma unroll
  for (int m = 0; m < 4; ++m)
#pragma unroll
    for (int n = 0; n < 4; ++n) acc[m][n] = f32x4{0.f, 0.f, 0.f, 0.f};

  const int lrow = lane & 15, lko = (lane >> 4) * 8;
  const int sr = wid * 8 + (lane >> 3), scol = (lane & 7) * 8;
  const size_t arow0 = (size_t)bm * 128, brow0 = (size_t)bn * 128;

  for (int k0 = 0; k0 < K; k0 += 64) {
#pragma unroll
    for (int i = 0; i < 4; ++i) {
      gload_lds16(Asel + (arow0 + i * 32 + sr) * K + k0 + scol, &As[(i * 4 + wid) * 512]);
      gload_lds16(Wsel + (brow0 + i * 32 + sr) * K + k0 + scol, &Bs[(i * 4 + wid) * 512]);
    }
    __syncthreads();
    bf16x8 af[4][2], bw[4][2];
#pragma unroll
    for (int m = 0; m < 4; ++m)
#pragma unroll
      for (int ks = 0; ks < 2; ++ks)
        af[m][ks] = *reinterpret_cast<const bf16x8*>(
            &As[(wr * 64 + m * 16 + lrow) * 64 + ks * 32 + lko]);
#pragma unroll
    for (int n = 0; n < 4; ++n)
#pragma unroll
      for (int ks = 0; ks < 2; ++ks)
        bw[n][ks] = *reinterpret_cast<const bf16x8*>(
            &Bs[(wc * 64 + n * 16 + lrow) * 64 + ks * 32 + lko]);
    __builtin_amdgcn_s_setprio(1);
#pragma unroll
    for (int ks = 0; ks < 2; ++ks)
#pragma unroll
      for (int m = 0; m < 4; ++m)
#pragma unroll
        for (int n = 0; n < 4; ++n)
          acc[m][n] = __builtin_amdgcn_mfma_f32_16x16x32_bf16(af[m][ks], bw[n][ks], acc[m][n], 0, 0, 0);
    __builtin_amdgcn_s_setprio(0);
    __syncthreads();
  }

  const int r0 = bm * 128 + wr * 64 + (lane >> 4) * 4;
  const int c0 = bn * 128 + wc * 64 + lrow;
#pragma unroll
  for (int n = 0; n < 4; ++n) {
    const int col = c0 + n * 16;
    const float bc = bsel[col];
#pragma unroll
    for (int m = 0; m < 4; ++m)
#pragma unroll
      for (int j = 0; j < 4; ++j)
        Yb[(size_t)(r0 + m * 16 + j) * QVLD + col] = f2b(acc[m][n][j] + bc);
  }
}

// ---------------- MFMA GEMM (64x128 tile, BK=64): N=512, bf16 out ----------------
template <bool RELU>
__global__ __launch_bounds__(256) void gemm_n512(
    const bf16_t* __restrict__ A, const bf16_t* __restrict__ W,
    const float* __restrict__ bias, bf16_t* __restrict__ Yb) {
  const int K = 512;
  const int lin = blockIdx.y * 4 + blockIdx.x;
  const int swz = (lin & 7) * 128 + (lin >> 3);
  const int bn = swz & 3, bm = swz >> 2;
  const int tid = threadIdx.x, wid = tid >> 6, lane = tid & 63;
  const int wr = wid >> 1, wc = wid & 1;   // 2x2 wave grid, 32x64 each
  __shared__ __align__(16) bf16_t As[64 * 64];
  __shared__ __align__(16) bf16_t Bs[128 * 64];

  f32x4 acc[2][4];
#pragma unroll
  for (int m = 0; m < 2; ++m)
#pragma unroll
    for (int n = 0; n < 4; ++n) acc[m][n] = f32x4{0.f, 0.f, 0.f, 0.f};

  const int lrow = lane & 15, lko = (lane >> 4) * 8;
  const int sr = wid * 8 + (lane >> 3), scol = (lane & 7) * 8;
  const size_t arow0 = (size_t)bm * 64, brow0 = (size_t)bn * 128;

  for (int k0 = 0; k0 < K; k0 += 64) {
#pragma unroll
    for (int i = 0; i < 2; ++i)
      gload_lds16(A + (arow0 + i * 32 + sr) * K + k0 + scol, &As[(i * 4 + wid) * 512]);
#pragma unroll
    for (int i = 0; i < 4; ++i)
      gload_lds16(W + (brow0 + i * 32 + sr) * K + k0 + scol, &Bs[(i * 4 + wid) * 512]);
    __syncthreads();
    bf16x8 af[2][2], bw[4][2];
#pragma unroll
    for (int m = 0; m < 2; ++m)
#pragma unroll
      for (int ks = 0; ks < 2; ++ks)
        af[m][ks] = *reinterpret_cast<const bf16x8*>(
            &As[(wr * 32 + m * 16 + lrow) * 64 + ks * 32 + lko]);
#pragma unroll
    for (int n = 0; n < 4; ++n)
#pragma unroll
      for (int ks = 0; ks < 2; ++ks)
        bw[n][ks] = *reinterpret_cast<const bf16x8*>(
            &Bs[(wc * 64 + n * 16 + lrow) * 64 + ks * 32 + lko]);
    __builtin_amdgcn_s_setprio(1);
#pragma unroll
    for (int ks = 0; ks < 2; ++ks)
#pragma unroll
      for (int m = 0; m < 2; ++m)
#pragma unroll
        for (int n = 0; n < 4; ++n)
          acc[m][n] = __builtin_amdgcn_mfma_f32_16x16x32_bf16(af[m][ks], bw[n][ks], acc[m][n], 0, 0, 0);
    __builtin_amdgcn_s_setprio(0);
    __syncthreads();
  }

  const int r0 = bm * 64 + wr * 32 + (lane >> 4) * 4;
  const int c0 = bn * 128 + wc * 64 + lrow;
#pragma unroll
  for (int n = 0; n < 4; ++n) {
    const int col = c0 + n * 16;
    const float bc = bias[col];
#pragma unroll
    for (int m = 0; m < 2; ++m)
#pragma unroll
      for (int j = 0; j < 4; ++j) {
        float v = acc[m][n][j] + bc;
        if (RELU) v = fmaxf(v, 0.f);
        Yb[(size_t)(r0 + m * 16 + j) * DM + col] = f2b(v);
      }
  }
}

// ---------------- gating: softmax(q @ Wg^T), top-4-of-6, fused routing ----------------
__global__ __launch_bounds__(256) void gates_kernel(
    const bf16_t* __restrict__ qv, const float* __restrict__ Wg,
    float* __restrict__ rdyn, float* __restrict__ fP) {
  __shared__ float wg_s[HD_ * DM];
  __shared__ float blk[4][18];
  const int tid = threadIdx.x, wid = tid >> 6, lane = tid & 63;
  for (int i = tid; i < HD_ * DM / 4; i += 256)
    reinterpret_cast<float4*>(wg_s)[i] = reinterpret_cast<const float4*>(Wg)[i];
  __syncthreads();
  const int bb = blockIdx.x >> 3;
  const int t0 = (blockIdx.x & 7) * 64 + wid * 16;
  float fs[6] = {0, 0, 0, 0, 0, 0}, ps[6] = {0, 0, 0, 0, 0, 0}, rs[6] = {0, 0, 0, 0, 0, 0};
  for (int it = 0; it < 16; ++it) {
    const int tok = bb * SEQ + t0 + it;
    uint4 u = reinterpret_cast<const uint4*>(qv + (size_t)tok * QVLD)[lane];
    float x[8];
    unp2(u.x, x[0], x[1]); unp2(u.y, x[2], x[3]);
    unp2(u.z, x[4], x[5]); unp2(u.w, x[6], x[7]);
    float g[6];
#pragma unroll
    for (int j = 0; j < 6; ++j) {
      float p = 0.f;
#pragma unroll
      for (int e = 0; e < 8; ++e) p = fmaf(x[e], wg_s[j * DM + lane * 8 + e], p);
#pragma unroll
      for (int off = 32; off; off >>= 1) p += __shfl_xor(p, off);
      g[j] = p;
    }
    float mx = g[0];
#pragma unroll
    for (int j = 1; j < 6; ++j) mx = fmaxf(mx, g[j]);
    float se = 0.f;
#pragma unroll
    for (int j = 0; j < 6; ++j) { g[j] = __expf(g[j] - mx); se += g[j]; }
    float inv = 1.f / se;
#pragma unroll
    for (int j = 0; j < 6; ++j) g[j] *= inv;
    int d1 = 0;
#pragma unroll
    for (int j = 1; j < 6; ++j)
      if (g[j] < g[d1] || (g[j] == g[d1] && j > d1)) d1 = j;
    int d2 = (d1 == 0) ? 1 : 0;
#pragma unroll
    for (int j = 0; j < 6; ++j) {
      if (j == d1) continue;
      if (g[j] < g[d2] || (g[j] == g[d2] && j > d2)) d2 = j;
    }
#pragma unroll
    for (int j = 0; j < 6; ++j) {
      const bool drop = (j == d1) || (j == d2);
      fs[j] += drop ? 0.f : 1.f;
      ps[j] += g[j];
      rs[j] += drop ? 0.f : g[j];
    }
  }
  if (lane == 0) {
#pragma unroll
    for (int j = 0; j < 6; ++j) {
      blk[wid][j] = fs[j]; blk[wid][6 + j] = ps[j]; blk[wid][12 + j] = rs[j];
    }
  }
  __syncthreads();
  if (tid < 18) {
    float s = blk[0][tid] + blk[1][tid] + blk[2][tid] + blk[3][tid];
    if (tid < 12) atomicAdd(&fP[tid], s);
    else atomicAdd(&rdyn[bb * 6 + (tid - 12)], s * (1.f / 512.f));
  }
}

// ---------------- fused flash attention (MFMA, row0 fused, VALU diet) ---------
// grid (2, 8, 32), 256 thr. Block bx owns q-tiles {bx, 3-bx} (balanced).
// Q pre-scaled by SCL (exp2 domain); defer-max (THR=8) skips rescale passes.
__global__ __launch_bounds__(256, 2) void fattn_kernel(
    const bf16_t* __restrict__ qv, const float* __restrict__ rdyn,
    bf16_t* __restrict__ ctx, int strict) {
  const int lin = (blockIdx.z * 8 + blockIdx.y) * 2 + blockIdx.x;
  const int swz = (lin & 7) * 64 + (lin >> 3);
  const int bx = swz & 1, h = (swz >> 1) & 7, b = swz >> 4;
  const int tid = threadIdx.x, wid = tid >> 6, lane = tid & 63;
  const int c0 = lane & 15, grp = lane >> 4;
  const int l3 = lane >> 3, c3 = lane & 7;
  const int kidx = lane & 31, dhalf = lane >> 5;

  __shared__ __align__(16) bf16_t Ks[64 * 64];        // swizzled [64k][64ch]
  __shared__ __align__(16) bf16_t Vt[64 * 72];        // transposed [64d][64k+8pad]
  __shared__ __align__(16) bf16_t Ps[4][32 * 64];     // per-wave P, swizzled
  __shared__ float csum[64];

  const bf16_t* qp = qv;          // q half, row stride QVLD
  const bf16_t* vp = qv + 512;    // v half
  const float factor = (h < HS_) ? 1.f : rdyn[b * 6 + (h - HS_)];

  const int qtA = bx, qtB = 3 - bx;                   // qtA < qtB
  const int qbaseA = qtA * 128 + wid * 32;
  const int qbaseB = qtB * 128 + wid * 32;

  bf16x8 qfA[2][2], qfB[2][2];
#pragma unroll
  for (int nt = 0; nt < 2; ++nt)
#pragma unroll
    for (int ks = 0; ks < 2; ++ks) {
      qfA[nt][ks] = scale_q(*reinterpret_cast<const bf16x8*>(
          qp + ((size_t)(b * SEQ + qbaseA + nt * 16 + c0)) * QVLD + h * DK + ks * 32 + grp * 8));
      qfB[nt][ks] = scale_q(*reinterpret_cast<const bf16x8*>(
          qp + ((size_t)(b * SEQ + qbaseB + nt * 16 + c0)) * QVLD + h * DK + ks * 32 + grp * 8));
    }

  f32x4 accA[2][4], accB[2][4];
#pragma unroll
  for (int m = 0; m < 2; ++m)
#pragma unroll
    for (int d = 0; d < 4; ++d) {
      accA[m][d] = f32x4{0.f, 0.f, 0.f, 0.f};
      accB[m][d] = f32x4{0.f, 0.f, 0.f, 0.f};
    }
  float mA[2] = {-3e38f, -3e38f}, lA[2] = {0.f, 0.f};
  float mB[2] = {-3e38f, -3e38f}, lB[2] = {0.f, 0.f};
  float cs[8] = {0, 0, 0, 0, 0, 0, 0, 0};   // V column-sum partials (bx==0)

  const int lastA = (qbaseA + 31 - strict) >> 6;
  const int lastB = (qbaseB + 31 - strict) >> 6;
  const int ktmax = 2 * qtB + 1;

  auto do_tile = [&](bf16x8 (&qf)[2][2], f32x4 (&acc)[2][4], float (&mreg)[2],
                     float (&lreg)[2], int qbase, bool masked, int kt) {
    const char* KsB = (const char*)Ks;
    bf16x8 kf[4][2];
#pragma unroll
    for (int mt = 0; mt < 4; ++mt)
#pragma unroll
      for (int ks = 0; ks < 2; ++ks)
        kf[mt][ks] = *reinterpret_cast<const bf16x8*>(
            KsB + (mt * 16 + c0) * 128 + 16 * ((4 * ks + grp) ^ (c0 & 7)));
    f32x4 s[4][2];
#pragma unroll
    for (int mt = 0; mt < 4; ++mt)
#pragma unroll
      for (int nt = 0; nt < 2; ++nt) s[mt][nt] = f32x4{0.f, 0.f, 0.f, 0.f};
    __builtin_amdgcn_s_setprio(1);
#pragma unroll
    for (int mt = 0; mt < 4; ++mt)
#pragma unroll
      for (int nt = 0; nt < 2; ++nt)
#pragma unroll
        for (int ks = 0; ks < 2; ++ks)
          s[mt][nt] = __builtin_amdgcn_mfma_f32_16x16x32_bf16(
              kf[mt][ks], qf[nt][ks], s[mt][nt], 0, 0, 0);
    __builtin_amdgcn_s_setprio(0);

    // mask (diagonal tile only; scores already in exp2 domain)
    if (masked) {
#pragma unroll
      for (int nt = 0; nt < 2; ++nt) {
        const int q = qbase + nt * 16 + c0;
#pragma unroll
        for (int mt = 0; mt < 4; ++mt)
#pragma unroll
          for (int j = 0; j < 4; ++j) {
            int k = kt * 64 + mt * 16 + grp * 4 + j;
            if (k + strict > q) s[mt][nt][j] = -1e30f;
          }
      }
    }
    // per-row max (max3-friendly triples), wave-reduce over k-groups
    float mx[2];
#pragma unroll
    for (int nt = 0; nt < 2; ++nt) {
      float a = fmaxf(s[0][nt][0], s[0][nt][1]);
      a = fmaxf(fmaxf(a, s[0][nt][2]), s[0][nt][3]);
      float bm_ = fmaxf(s[1][nt][0], s[1][nt][1]);
      bm_ = fmaxf(fmaxf(bm_, s[1][nt][2]), s[1][nt][3]);
      float c = fmaxf(s[2][nt][0], s[2][nt][1]);
      c = fmaxf(fmaxf(c, s[2][nt][2]), s[2][nt][3]);
      float d = fmaxf(s[3][nt][0], s[3][nt][1]);
      d = fmaxf(fmaxf(d, s[3][nt][2]), s[3][nt][3]);
      float m_ = fmaxf(fmaxf(a, bm_), fmaxf(c, d));
      m_ = fmaxf(m_, __shfl_xor(m_, 16));
      m_ = fmaxf(m_, __shfl_xor(m_, 32));
      mx[nt] = m_;
    }
    const bool defer = __all((mx[0] - mreg[0] <= 8.f) && (mx[1] - mreg[1] <= 8.f));
    float sc[2];
#pragma unroll
    for (int nt = 0; nt < 2; ++nt) {
      const float mnew = defer ? mreg[nt] : fmaxf(mreg[nt], mx[nt]);
      float ts = 0.f;
#pragma unroll
      for (int mt = 0; mt < 4; ++mt)
#pragma unroll
        for (int j = 0; j < 4; ++j) {
          float pp = exp2f(s[mt][nt][j] - mnew);
          s[mt][nt][j] = pp; ts += pp;
        }
      ts += __shfl_xor(ts, 16);
      ts += __shfl_xor(ts, 32);
      if (defer) {
        lreg[nt] += ts;
      } else {
        sc[nt] = exp2f(mreg[nt] - mnew);
        lreg[nt] = lreg[nt] * sc[nt] + ts;
        mreg[nt] = mnew;
      }
    }
    // P -> bf16 -> per-wave LDS (swizzled)
    char* PsB = (char*)(&Ps[wid][0]);
#pragma unroll
    for (int nt = 0; nt < 2; ++nt)
#pragma unroll
      for (int mt = 0; mt < 4; ++mt) {
        uint2 w;
        w.x = cvtpk(s[mt][nt][0], s[mt][nt][1]);
        w.y = cvtpk(s[mt][nt][2], s[mt][nt][3]);
        int row = nt * 16 + c0;
        int off = (row * 128 + mt * 32 + grp * 8) ^ ((c0 & 7) << 4);
        *reinterpret_cast<uint2*>(PsB + off) = w;
      }
    if (!defer) {
#pragma unroll
      for (int mtq = 0; mtq < 2; ++mtq) {
        f32x4 sv;
#pragma unroll
        for (int j = 0; j < 4; ++j) sv[j] = __shfl(sc[mtq], grp * 4 + j);
#pragma unroll
        for (int dt = 0; dt < 4; ++dt) acc[mtq][dt] *= sv;
      }
    }
    // PV
    bf16x8 pf[2][2], vf2[4][2];
#pragma unroll
    for (int mtq = 0; mtq < 2; ++mtq)
#pragma unroll
      for (int ks = 0; ks < 2; ++ks)
        pf[mtq][ks] = *reinterpret_cast<const bf16x8*>(
            PsB + (mtq * 16 + c0) * 128 + 16 * ((4 * ks + grp) ^ (c0 & 7)));
#pragma unroll
    for (int dt = 0; dt < 4; ++dt)
#pragma unroll
      for (int ks = 0; ks < 2; ++ks)
        vf2[dt][ks] = *reinterpret_cast<const bf16x8*>(
            (const char*)Vt + (dt * 16 + c0) * 144 + ks * 64 + grp * 16);
    __builtin_amdgcn_s_setprio(1);
#pragma unroll
    for (int mtq = 0; mtq < 2; ++mtq)
#pragma unroll
      for (int dt = 0; dt < 4; ++dt)
#pragma unroll
        for (int ks = 0; ks < 2; ++ks)
          acc[mtq][dt] = __builtin_amdgcn_mfma_f32_16x16x32_bf16(
              pf[mtq][ks], vf2[dt][ks], acc[mtq][dt], 0, 0, 0);
    __builtin_amdgcn_s_setprio(0);
  };

  for (int kt = 0; kt <= ktmax; ++kt) {
    // ---- stage K tile via global_load_lds, source pre-swizzled ----
#pragma unroll
    for (int i = 0; i < 2; ++i) {
      int row = i * 32 + wid * 8 + l3;
      int blk = c3 ^ l3;
      gload_lds16(qp + ((size_t)(b * SEQ + kt * 64 + row)) * QVLD + h * DK + blk * 8,
                  Ks + (i * 32 + wid * 8) * 64);
    }
    // ---- stage V transposed: lane owns 2 kk-cols x 4 d-rows, 4B writes ----
#pragma unroll
    for (int j = 0; j < 2; ++j) {
      const int d0 = (wid * 2 + j) * 8 + dhalf * 4;
      const bf16_t* src = vp + ((size_t)(b * SEQ + kt * 64 + 2 * kidx)) * QVLD + h * DK + d0;
      ushort4 lo = *reinterpret_cast<const ushort4*>(src);
      ushort4 hv = *reinterpret_cast<const ushort4*>(src + QVLD);
      *reinterpret_cast<unsigned*>(&Vt[(d0 + 0) * 72 + 2 * kidx]) = (unsigned)lo.x | ((unsigned)hv.x << 16);
      *reinterpret_cast<unsigned*>(&Vt[(d0 + 1) * 72 + 2 * kidx]) = (unsigned)lo.y | ((unsigned)hv.y << 16);
      *reinterpret_cast<unsigned*>(&Vt[(d0 + 2) * 72 + 2 * kidx]) = (unsigned)lo.z | ((unsigned)hv.z << 16);
      *reinterpret_cast<unsigned*>(&Vt[(d0 + 3) * 72 + 2 * kidx]) = (unsigned)lo.w | ((unsigned)hv.w << 16);
      if (bx == 0) {
        cs[j * 4 + 0] += bf2f(lo.x) + bf2f(hv.x);
        cs[j * 4 + 1] += bf2f(lo.y) + bf2f(hv.y);
        cs[j * 4 + 2] += bf2f(lo.z) + bf2f(hv.z);
        cs[j * 4 + 3] += bf2f(lo.w) + bf2f(hv.w);
      }
    }
    __syncthreads();
    if (kt <= lastB) do_tile(qfB, accB, mB, lB, qbaseB, kt == lastB, kt);
    if (kt <= lastA) do_tile(qfA, accA, mA, lA, qbaseA, kt == lastA, kt);
    __syncthreads();
  }

  // ---- row-0 quirk: ctx[b,0,h,:] = factor * mean_k V (block bx==0 only) ----
  if (bx == 0) {
#pragma unroll
    for (int e = 0; e < 8; ++e)
#pragma unroll
      for (int off = 1; off <= 16; off <<= 1) cs[e] += __shfl_xor(cs[e], off);
    if ((lane & 31) == 0) {
#pragma unroll
      for (int e = 0; e < 8; ++e)
        csum[(wid * 2 + (e >> 2)) * 8 + dhalf * 4 + (e & 3)] = cs[e];
    }
  }
  __syncthreads();
  if (bx == 0 && tid < 64)
    ctx[((size_t)(b * SEQ)) * DM + h * DK + tid] = f2b(csum[tid] * (1.f / 512.f) * factor);

  // ---- epilogues: /l, *routing, store (skip q==0) ----
#pragma unroll
  for (int e = 0; e < 2; ++e) {
    const int qbase = e ? qbaseB : qbaseA;
    f32x4 (&acc)[2][4] = e ? accB : accA;
    float (&lreg)[2] = e ? lB : lA;
#pragma unroll
    for (int mtq = 0; mtq < 2; ++mtq) {
      const float inv = factor / lreg[mtq];
      f32x4 iv;
#pragma unroll
      for (int j = 0; j < 4; ++j) iv[j] = __shfl(inv, grp * 4 + j);
#pragma unroll
      for (int j = 0; j < 4; ++j) {
        const int q = qbase + mtq * 16 + grp * 4 + j;
        if (q == 0) continue;
#pragma unroll
        for (int dt = 0; dt < 4; ++dt)
          ctx[((size_t)(b * SEQ + q)) * DM + h * DK + dt * 16 + c0] =
              f2b(acc[mtq][dt][j] * iv[j]);
      }
    }
  }
}

// ---------------- add + layernorm: wave-per-row, bf16 residual ----------------
template <int OUT>
__global__ __launch_bounds__(256) void add_ln_kernel(
    const bf16_t* __restrict__ X, const bf16_t* __restrict__ A2,
    const float* __restrict__ gam, const float* __restrict__ bet,
    bf16_t* __restrict__ outb, float* __restrict__ outf) {
  const int wid = threadIdx.x >> 6, lane = threadIdx.x & 63;
  const size_t row = (size_t)blockIdx.x * 4 + wid;
  const size_t base = row * DM + lane * 8;
  uint4 xu = *reinterpret_cast<const uint4*>(X + base);
  uint4 au = *reinterpret_cast<const uint4*>(A2 + base);
  float z[8];
  {
    float p0, p1, q0, q1;
    unp2(xu.x, p0, p1); unp2(au.x, q0, q1); z[0] = p0 + q0; z[1] = p1 + q1;
    unp2(xu.y, p0, p1); unp2(au.y, q0, q1); z[2] = p0 + q0; z[3] = p1 + q1;
    unp2(xu.z, p0, p1); unp2(au.z, q0, q1); z[4] = p0 + q0; z[5] = p1 + q1;
    unp2(xu.w, p0, p1); unp2(au.w, q0, q1); z[6] = p0 + q0; z[7] = p1 + q1;
  }
  float s = 0.f;
#pragma unroll
  for (int e = 0; e < 8; ++e) s += z[e];
#pragma unroll
  for (int off = 32; off; off >>= 1) s += __shfl_xor(s, off);
  const float mean = s * (1.f / 512.f);
  float ss = 0.f;
#pragma unroll
  for (int e = 0; e < 8; ++e) { float d = z[e] - mean; ss += d * d; }
#pragma unroll
  for (int off = 32; off; off >>= 1) ss += __shfl_xor(ss, off);
  const float inv = rsqrtf(ss * (1.f / 512.f) + 1e-5f);
  float4 g0 = *reinterpret_cast<const float4*>(gam + lane * 8);
  float4 g1 = *reinterpret_cast<const float4*>(gam + lane * 8 + 4);
  float4 b0 = *reinterpret_cast<const float4*>(bet + lane * 8);
  float4 b1 = *reinterpret_cast<const float4*>(bet + lane * 8 + 4);
  float o[8];
  o[0] = (z[0] - mean) * inv * g0.x + b0.x;
  o[1] = (z[1] - mean) * inv * g0.y + b0.y;
  o[2] = (z[2] - mean) * inv * g0.z + b0.z;
  o[3] = (z[3] - mean) * inv * g0.w + b0.w;
  o[4] = (z[4] - mean) * inv * g1.x + b1.x;
  o[5] = (z[5] - mean) * inv * g1.y + b1.y;
  o[6] = (z[6] - mean) * inv * g1.z + b1.z;
  o[7] = (z[7] - mean) * inv * g1.w + b1.w;
  if (OUT == 0) {
    uint4 w;
    w.x = (unsigned)f2b(o[0]) | ((unsigned)f2b(o[1]) << 16);
    w.y = (unsigned)f2b(o[2]) | ((unsigned)f2b(o[3]) << 16);
    w.z = (unsigned)f2b(o[4]) | ((unsigned)f2b(o[5]) << 16);
    w.w = (unsigned)f2b(o[6]) | ((unsigned)f2b(o[7]) << 16);
    *reinterpret_cast<uint4*>(outb + base) = w;
  } else {
    float4 f0, f1;
    f0.x = o[0]; f0.y = o[1]; f0.z = o[2]; f0.w = o[3];
    f1.x = o[4]; f1.y = o[5]; f1.z = o[6]; f1.w = o[7];
    *reinterpret_cast<float4*>(outf + base) = f0;
    *reinterpret_cast<float4*>(outf + base + 4) = f1;
  }
}

// ---------------- balance ----------------
__global__ void balance_kernel(const float* __restrict__ fP, float* __restrict__ out) {
  if (threadIdx.x == 0 && blockIdx.x == 0) {
    float fs = 0.f, pssum = 0.f, P[6];
    for (int j = 0; j < 6; ++j) {
      fs += fP[j];
      P[j] = fP[6 + j] * (1.f / (float)MROWS);
      pssum += P[j];
    }
    float bal = 0.f;
    for (int j = 0; j < 6; ++j)
      bal += (fP[j] / (fs + 1e-5f)) * (P[j] / (pssum + 1e-5f));
    out[0] = bal;
  }
}

// ---------------- host ----------------
extern "C" void kernel_launch(void* const* d_in, const int* in_sizes, int n_in,
                              void* d_out, int out_size, void* d_ws, size_t ws_size,
                              hipStream_t stream) {
  (void)in_sizes; (void)n_in; (void)out_size; (void)ws_size;
  const float* q_embed  = (const float*)d_in[0];
  const float* qa_embed = (const float*)d_in[1];
  const float* Wq  = (const float*)d_in[2];
  const float* bq  = (const float*)d_in[3];
  const float* Wv  = (const float*)d_in[4];
  const float* bv  = (const float*)d_in[5];
  const float* Wg  = (const float*)d_in[6];
  const float* Wo  = (const float*)d_in[7];
  const float* bo  = (const float*)d_in[8];
  const float* ln1g = (const float*)d_in[9];
  const float* ln1b = (const float*)d_in[10];
  const float* W1  = (const float*)d_in[11];
  const float* b1  = (const float*)d_in[12];
  const float* W2  = (const float*)d_in[13];
  const float* b2  = (const float*)d_in[14];
  const float* ln2g = (const float*)d_in[15];
  const float* ln2b = (const float*)d_in[16];

  char* p = (char*)d_ws;
  auto alloc = [&](size_t bytes) -> char* {
    char* r = p; p += (bytes + 255) & ~(size_t)255; return r;
  };
  const size_t WDE = (size_t)NL * DM * DM;   // stacked weight elems (per tensor)
  const size_t AE  = (size_t)MROWS * DM;     // activation elems
  bf16_t* wall_b = (bf16_t*)alloc(5 * WDE * 2);   // wq|wv|wo|w1|w2 contiguous
  bf16_t* wq_b = wall_b;
  bf16_t* wv_b = wall_b + WDE;
  bf16_t* wo_b = wall_b + 2 * WDE;
  bf16_t* w1_b = wall_b + 3 * WDE;
  bf16_t* w2_b = wall_b + 4 * WDE;
  bf16_t* y_b   = (bf16_t*)alloc(AE * 2);
  bf16_t* x_b   = (bf16_t*)alloc(AE * 2);
  bf16_t* qv_b  = (bf16_t*)alloc((size_t)MROWS * QVLD * 2);  // q|v merged
  bf16_t* ctx_b = (bf16_t*)alloc(AE * 2);
  bf16_t* x1_b  = (bf16_t*)alloc(AE * 2);
  bf16_t* tmp_b = (bf16_t*)alloc(AE * 2);
  bf16_t* ffn1_b = (bf16_t*)alloc(AE * 2);
  float* stats = (float*)alloc(NL * (12 + BSZ * 6) * 4);  // fP[NL][12] | rdyn[NL][32][6]
  float* fPbase = stats;
  float* rdynbase = stats + NL * 12;

  hipMemsetAsync(stats, 0, NL * (12 + BSZ * 6) * 4, stream);

  f2bw_kernel<<<dim3((unsigned)(WDE / 4 / 256), 5), 256, 0, stream>>>(
      Wq, Wv, Wo, W1, W2, wall_b);
  f2b2_kernel<<<dim3((unsigned)(AE / 4 / 256), 2), 256, 0, stream>>>(
      qa_embed, q_embed, y_b, x_b);

  const size_t DD = (size_t)DM * DM;
  dim3 gqv(8, 128), gn5(4, 256);
  float* outx = (float*)d_out;

  auto layer = [&](int i, bf16_t* resb, const bf16_t* xvb, int strict, bool last) {
    float* fP = fPbase + i * 12;
    float* rdyn = rdynbase + i * (BSZ * 6);
    gemm_qv<<<gqv, 256, 0, stream>>>(
        resb, xvb, wq_b + i * DD, wv_b + i * DD, bq + i * DM, bv + i * DM, qv_b);
    gates_kernel<<<MROWS / 64, 256, 0, stream>>>(qv_b, Wg + (size_t)i * HD_ * DM, rdyn, fP);
    fattn_kernel<<<dim3(2, NH, BSZ), 256, 0, stream>>>(qv_b, rdyn, ctx_b, strict);
    gemm_n512<false><<<gn5, 256, 0, stream>>>(ctx_b, wo_b + i * DD, bo + i * DM, tmp_b);
    add_ln_kernel<0><<<MROWS / 4, 256, 0, stream>>>(
        resb, tmp_b, ln1g + i * DM, ln1b + i * DM, x1_b, nullptr);
    gemm_n512<true><<<gn5, 256, 0, stream>>>(x1_b, w1_b + i * DD, b1 + i * DM, ffn1_b);
    gemm_n512<false><<<gn5, 256, 0, stream>>>(ffn1_b, w2_b + i * DD, b2 + i * DM, tmp_b);
    if (last)
      add_ln_kernel<1><<<MROWS / 4, 256, 0, stream>>>(
          x1_b, tmp_b, ln2g + i * DM, ln2b + i * DM, nullptr, outx);
    else
      add_ln_kernel<0><<<MROWS / 4, 256, 0, stream>>>(
          x1_b, tmp_b, ln2g + i * DM, ln2b + i * DM, resb, nullptr);
  };

  layer(0, y_b, y_b, 0, false);
  layer(1, y_b, y_b, 0, false);
  layer(2, x_b, x_b, 0, false);
  layer(3, x_b, y_b, 1, false);
  layer(4, x_b, x_b, 0, false);
  layer(5, x_b, y_b, 1, true);
  balance_kernel<<<1, 64, 0, stream>>>(fPbase + 5 * 12, outx + (size_t)MROWS * DM);
}

// Round 9
// 969.282 us; speedup vs baseline: 10.4775x; 1.0453x over previous
//
#include <hip/hip_runtime.h>
#include <cstdint>

// ---------------- constants ----------------
#define BSZ 32
#define SEQ 512
#define DM  512
#define NH  8
#define DK  64
#define HS_ 2
#define HD_ 6
#define NL  6
#define MROWS (BSZ*SEQ)          // 16384
#define QVLD 1024                // row stride of merged q|v buffer
#define SCL 0.18033688011112043f // 0.125 * log2(e)  (exp2 domain)

typedef unsigned short bf16_t;
typedef __attribute__((ext_vector_type(4))) float f32x4;
typedef __attribute__((ext_vector_type(8))) short bf16x8;
typedef __attribute__((ext_vector_type(8))) unsigned short u16x8;

#define DEV static __device__ __forceinline__

DEV float bf2f(bf16_t b) {
  unsigned int u = ((unsigned int)b) << 16;
  float f; __builtin_memcpy(&f, &u, 4); return f;
}
DEV bf16_t f2b(float f) {  // RNE bf16 (finite inputs)
  unsigned int u; __builtin_memcpy(&u, &f, 4);
  unsigned int r = (u + 0x7fffu + ((u >> 16) & 1u)) >> 16;
  return (bf16_t)r;
}
DEV void unp2(unsigned int w, float& a, float& b) {
  unsigned int ua = w << 16, ub = w & 0xffff0000u;
  __builtin_memcpy(&a, &ua, 4); __builtin_memcpy(&b, &ub, 4);
}
DEV unsigned cvtpk(float lo, float hi) {
  unsigned r;
  asm("v_cvt_pk_bf16_f32 %0, %1, %2" : "=v"(r) : "v"(lo), "v"(hi));
  return r;
}

DEV void gload_lds16(const bf16_t* g, bf16_t* l) {
  __builtin_amdgcn_global_load_lds(
      (const __attribute__((address_space(1))) void*)g,
      (__attribute__((address_space(3))) void*)l, 16, 0, 0);
}

// scale a bf16x8 Q fragment by SCL (exp2-domain pre-scale)
DEV bf16x8 scale_q(bf16x8 v) {
  u16x8 u;
  __builtin_memcpy(&u, &v, 16);
  unsigned w[4];
#pragma unroll
  for (int e = 0; e < 4; ++e)
    w[e] = cvtpk(bf2f(u[2 * e]) * SCL, bf2f(u[2 * e + 1]) * SCL);
  bf16x8 r;
  __builtin_memcpy(&r, w, 16);
  return r;
}

// ---------------- f32 -> bf16 converts ----------------
__global__ __launch_bounds__(256) void f2b2_kernel(
    const float* __restrict__ s0, const float* __restrict__ s1,
    bf16_t* __restrict__ d0, bf16_t* __restrict__ d1) {
  const float* s = blockIdx.y ? s1 : s0;
  bf16_t* d = blockIdx.y ? d1 : d0;
  const int i = blockIdx.x * 256 + threadIdx.x;
  float4 v = reinterpret_cast<const float4*>(s)[i];
  ushort4 o;
  o.x = f2b(v.x); o.y = f2b(v.y); o.z = f2b(v.z); o.w = f2b(v.w);
  reinterpret_cast<ushort4*>(d)[i] = o;
}

__global__ __launch_bounds__(256) void f2bw_kernel(
    const float* __restrict__ s0, const float* __restrict__ s1,
    const float* __restrict__ s2, const float* __restrict__ s3,
    const float* __restrict__ s4, bf16_t* __restrict__ dst) {
  const float* srcs[5] = {s0, s1, s2, s3, s4};
  const float* s = srcs[blockIdx.y];
  bf16_t* d = dst + (size_t)blockIdx.y * ((size_t)NL * DM * DM);
  const int i = blockIdx.x * 256 + threadIdx.x;
  float4 v = reinterpret_cast<const float4*>(s)[i];
  ushort4 o;
  o.x = f2b(v.x); o.y = f2b(v.y); o.z = f2b(v.z); o.w = f2b(v.w);
  reinterpret_cast<ushort4*>(d)[i] = o;
}

// ---------------- MFMA GEMM (128x128 tile, BK=64): qv projection ----------------
__global__ __launch_bounds__(256) void gemm_qv(
    const bf16_t* __restrict__ A0, const bf16_t* __restrict__ A1,
    const bf16_t* __restrict__ W0, const bf16_t* __restrict__ W1,
    const float* __restrict__ b0, const float* __restrict__ b1,
    bf16_t* __restrict__ Yb) {
  const int K = 512;
  const int lin = blockIdx.y * 8 + blockIdx.x;
  const int swz = (lin & 7) * 128 + (lin >> 3);
  const int bn = swz & 7, bm = swz >> 3;
  const int tid = threadIdx.x, wid = tid >> 6, lane = tid & 63;
  const int wr = wid >> 1, wc = wid & 1;   // 2x2 wave grid, 64x64 each
  __shared__ __align__(16) bf16_t As[128 * 64];
  __shared__ __align__(16) bf16_t Bs[128 * 64];

  const bool hi = bn >= 4;
  const bf16_t* Asel = hi ? A1 : A0;
  const bf16_t* Wsel = hi ? (W1 - (size_t)512 * K) : W0;
  const float* bsel = hi ? (b1 - 512) : b0;

  f32x4 acc[4][4];
#pragma unroll
  for (int m = 0; m < 4; ++m)
#pragma unroll
    for (int n = 0; n < 4; ++n) acc[m][n] = f32x4{0.f, 0.f, 0.f, 0.f};

  const int lrow = lane & 15, lko = (lane >> 4) * 8;
  const int sr = wid * 8 + (lane >> 3), scol = (lane & 7) * 8;
  const size_t arow0 = (size_t)bm * 128, brow0 = (size_t)bn * 128;

  for (int k0 = 0; k0 < K; k0 += 64) {
#pragma unroll
    for (int i = 0; i < 4; ++i) {
      gload_lds16(Asel + (arow0 + i * 32 + sr) * K + k0 + scol, &As[(i * 4 + wid) * 512]);
      gload_lds16(Wsel + (brow0 + i * 32 + sr) * K + k0 + scol, &Bs[(i * 4 + wid) * 512]);
    }
    __syncthreads();
    bf16x8 af[4][2], bw[4][2];
#pragma unroll
    for (int m = 0; m < 4; ++m)
#pragma unroll
      for (int ks = 0; ks < 2; ++ks)
        af[m][ks] = *reinterpret_cast<const bf16x8*>(
            &As[(wr * 64 + m * 16 + lrow) * 64 + ks * 32 + lko]);
#pragma unroll
    for (int n = 0; n < 4; ++n)
#pragma unroll
      for (int ks = 0; ks < 2; ++ks)
        bw[n][ks] = *reinterpret_cast<const bf16x8*>(
            &Bs[(wc * 64 + n * 16 + lrow) * 64 + ks * 32 + lko]);
    __builtin_amdgcn_s_setprio(1);
#pragma unroll
    for (int ks = 0; ks < 2; ++ks)
#pragma unroll
      for (int m = 0; m < 4; ++m)
#pragma unroll
        for (int n = 0; n < 4; ++n)
          acc[m][n] = __builtin_amdgcn_mfma_f32_16x16x32_bf16(af[m][ks], bw[n][ks], acc[m][n], 0, 0, 0);
    __builtin_amdgcn_s_setprio(0);
    __syncthreads();
  }

  const int r0 = bm * 128 + wr * 64 + (lane >> 4) * 4;
  const int c0 = bn * 128 + wc * 64 + lrow;
#pragma unroll
  for (int n = 0; n < 4; ++n) {
    const int col = c0 + n * 16;
    const float bc = bsel[col];
#pragma unroll
    for (int m = 0; m < 4; ++m)
#pragma unroll
      for (int j = 0; j < 4; ++j)
        Yb[(size_t)(r0 + m * 16 + j) * QVLD + col] = f2b(acc[m][n][j] + bc);
  }
}

// ---------------- MFMA GEMM (64x128 tile, BK=64): N=512, bf16 out ----------------
template <bool RELU>
__global__ __launch_bounds__(256) void gemm_n512(
    const bf16_t* __restrict__ A, const bf16_t* __restrict__ W,
    const float* __restrict__ bias, bf16_t* __restrict__ Yb) {
  const int K = 512;
  const int lin = blockIdx.y * 4 + blockIdx.x;
  const int swz = (lin & 7) * 128 + (lin >> 3);
  const int bn = swz & 3, bm = swz >> 2;
  const int tid = threadIdx.x, wid = tid >> 6, lane = tid & 63;
  const int wr = wid >> 1, wc = wid & 1;   // 2x2 wave grid, 32x64 each
  __shared__ __align__(16) bf16_t As[64 * 64];
  __shared__ __align__(16) bf16_t Bs[128 * 64];

  f32x4 acc[2][4];
#pragma unroll
  for (int m = 0; m < 2; ++m)
#pragma unroll
    for (int n = 0; n < 4; ++n) acc[m][n] = f32x4{0.f, 0.f, 0.f, 0.f};

  const int lrow = lane & 15, lko = (lane >> 4) * 8;
  const int sr = wid * 8 + (lane >> 3), scol = (lane & 7) * 8;
  const size_t arow0 = (size_t)bm * 64, brow0 = (size_t)bn * 128;

  for (int k0 = 0; k0 < K; k0 += 64) {
#pragma unroll
    for (int i = 0; i < 2; ++i)
      gload_lds16(A + (arow0 + i * 32 + sr) * K + k0 + scol, &As[(i * 4 + wid) * 512]);
#pragma unroll
    for (int i = 0; i < 4; ++i)
      gload_lds16(W + (brow0 + i * 32 + sr) * K + k0 + scol, &Bs[(i * 4 + wid) * 512]);
    __syncthreads();
    bf16x8 af[2][2], bw[4][2];
#pragma unroll
    for (int m = 0; m < 2; ++m)
#pragma unroll
      for (int ks = 0; ks < 2; ++ks)
        af[m][ks] = *reinterpret_cast<const bf16x8*>(
            &As[(wr * 32 + m * 16 + lrow) * 64 + ks * 32 + lko]);
#pragma unroll
    for (int n = 0; n < 4; ++n)
#pragma unroll
      for (int ks = 0; ks < 2; ++ks)
        bw[n][ks] = *reinterpret_cast<const bf16x8*>(
            &Bs[(wc * 64 + n * 16 + lrow) * 64 + ks * 32 + lko]);
    __builtin_amdgcn_s_setprio(1);
#pragma unroll
    for (int ks = 0; ks < 2; ++ks)
#pragma unroll
      for (int m = 0; m < 2; ++m)
#pragma unroll
        for (int n = 0; n < 4; ++n)
          acc[m][n] = __builtin_amdgcn_mfma_f32_16x16x32_bf16(af[m][ks], bw[n][ks], acc[m][n], 0, 0, 0);
    __builtin_amdgcn_s_setprio(0);
    __syncthreads();
  }

  const int r0 = bm * 64 + wr * 32 + (lane >> 4) * 4;
  const int c0 = bn * 128 + wc * 64 + lrow;
#pragma unroll
  for (int n = 0; n < 4; ++n) {
    const int col = c0 + n * 16;
    const float bc = bias[col];
#pragma unroll
    for (int m = 0; m < 2; ++m)
#pragma unroll
      for (int j = 0; j < 4; ++j) {
        float v = acc[m][n][j] + bc;
        if (RELU) v = fmaxf(v, 0.f);
        Yb[(size_t)(r0 + m * 16 + j) * DM + col] = f2b(v);
      }
  }
}

// ---------------- gating: softmax(q @ Wg^T), top-4-of-6, fused routing ----------------
// 32 tokens/block (4 waves x 8). 512 blocks.
__global__ __launch_bounds__(256) void gates_kernel(
    const bf16_t* __restrict__ qv, const float* __restrict__ Wg,
    float* __restrict__ rdyn, float* __restrict__ fP) {
  __shared__ float wg_s[HD_ * DM];
  __shared__ float blk[4][18];
  const int tid = threadIdx.x, wid = tid >> 6, lane = tid & 63;
  for (int i = tid; i < HD_ * DM / 4; i += 256)
    reinterpret_cast<float4*>(wg_s)[i] = reinterpret_cast<const float4*>(Wg)[i];
  __syncthreads();
  const int bb = blockIdx.x >> 4;
  const int t0 = (blockIdx.x & 15) * 32 + wid * 8;
  float fs[6] = {0, 0, 0, 0, 0, 0}, ps[6] = {0, 0, 0, 0, 0, 0}, rs[6] = {0, 0, 0, 0, 0, 0};
  for (int it = 0; it < 8; ++it) {
    const int tok = bb * SEQ + t0 + it;
    uint4 u = reinterpret_cast<const uint4*>(qv + (size_t)tok * QVLD)[lane];
    float x[8];
    unp2(u.x, x[0], x[1]); unp2(u.y, x[2], x[3]);
    unp2(u.z, x[4], x[5]); unp2(u.w, x[6], x[7]);
    float g[6];
#pragma unroll
    for (int j = 0; j < 6; ++j) {
      float p = 0.f;
#pragma unroll
      for (int e = 0; e < 8; ++e) p = fmaf(x[e], wg_s[j * DM + lane * 8 + e], p);
#pragma unroll
      for (int off = 32; off; off >>= 1) p += __shfl_xor(p, off);
      g[j] = p;
    }
    float mx = g[0];
#pragma unroll
    for (int j = 1; j < 6; ++j) mx = fmaxf(mx, g[j]);
    float se = 0.f;
#pragma unroll
    for (int j = 0; j < 6; ++j) { g[j] = __expf(g[j] - mx); se += g[j]; }
    float inv = 1.f / se;
#pragma unroll
    for (int j = 0; j < 6; ++j) g[j] *= inv;
    int d1 = 0;
#pragma unroll
    for (int j = 1; j < 6; ++j)
      if (g[j] < g[d1] || (g[j] == g[d1] && j > d1)) d1 = j;
    int d2 = (d1 == 0) ? 1 : 0;
#pragma unroll
    for (int j = 0; j < 6; ++j) {
      if (j == d1) continue;
      if (g[j] < g[d2] || (g[j] == g[d2] && j > d2)) d2 = j;
    }
#pragma unroll
    for (int j = 0; j < 6; ++j) {
      const bool drop = (j == d1) || (j == d2);
      fs[j] += drop ? 0.f : 1.f;
      ps[j] += g[j];
      rs[j] += drop ? 0.f : g[j];
    }
  }
  if (lane == 0) {
#pragma unroll
    for (int j = 0; j < 6; ++j) {
      blk[wid][j] = fs[j]; blk[wid][6 + j] = ps[j]; blk[wid][12 + j] = rs[j];
    }
  }
  __syncthreads();
  if (tid < 18) {
    float s = blk[0][tid] + blk[1][tid] + blk[2][tid] + blk[3][tid];
    if (tid < 12) atomicAdd(&fP[tid], s);
    else atomicAdd(&rdyn[bb * 6 + (tid - 12)], s * (1.f / 512.f));
  }
}

// ---------------- fused flash attention (MFMA, row0 fused, occupancy grid) ----
// grid (bh=256, qt=4), 256 thr. One q-tile per block; blocks lin=qt*256+bh, so
// the 4 co-resident blocks per CU slot span qt=0..3 of the SAME (b,h):
// per-CU work balanced (2+4+6+8 tile-units) and K/V shared in the XCD L2.
// qt==3 block stages all 8 V tiles -> computes the row-0 quirk.
__global__ __launch_bounds__(256, 2) void fattn_kernel(
    const bf16_t* __restrict__ qv, const float* __restrict__ rdyn,
    bf16_t* __restrict__ ctx, int strict) {
  const int bh = blockIdx.x, qt = blockIdx.y;
  const int b = bh >> 3, h = bh & 7;
  const int tid = threadIdx.x, wid = tid >> 6, lane = tid & 63;
  const int c0 = lane & 15, grp = lane >> 4;
  const int l3 = lane >> 3, c3 = lane & 7;
  const int kidx = lane & 31, dhalf = lane >> 5;

  __shared__ __align__(16) bf16_t Ks[64 * 64];        // swizzled [64k][64ch]
  __shared__ __align__(16) bf16_t Vt[64 * 72];        // transposed [64d][64k+8pad]
  __shared__ __align__(16) bf16_t Ps[4][32 * 64];     // per-wave P, swizzled
  __shared__ float csum[64];

  const bf16_t* qp = qv;          // q half, row stride QVLD
  const bf16_t* vp = qv + 512;    // v half
  const float factor = (h < HS_) ? 1.f : rdyn[b * 6 + (h - HS_)];

  const int qbase = qt * 128 + wid * 32;

  bf16x8 qf[2][2];
#pragma unroll
  for (int nt = 0; nt < 2; ++nt)
#pragma unroll
    for (int ks = 0; ks < 2; ++ks)
      qf[nt][ks] = scale_q(*reinterpret_cast<const bf16x8*>(
          qp + ((size_t)(b * SEQ + qbase + nt * 16 + c0)) * QVLD + h * DK + ks * 32 + grp * 8));

  f32x4 acc[2][4];
#pragma unroll
  for (int m = 0; m < 2; ++m)
#pragma unroll
    for (int d = 0; d < 4; ++d) acc[m][d] = f32x4{0.f, 0.f, 0.f, 0.f};
  float mreg[2] = {-3e38f, -3e38f};
  float lreg[2] = {0.f, 0.f};
  float cs[8] = {0, 0, 0, 0, 0, 0, 0, 0};   // V column-sum partials (qt==3)

  const int lastk = (qbase + 31 - strict) >> 6;
  const int ktmax = 2 * qt + 1;

  for (int kt = 0; kt <= ktmax; ++kt) {
    // ---- stage K tile via global_load_lds, source pre-swizzled ----
#pragma unroll
    for (int i = 0; i < 2; ++i) {
      int row = i * 32 + wid * 8 + l3;
      int blk = c3 ^ l3;
      gload_lds16(qp + ((size_t)(b * SEQ + kt * 64 + row)) * QVLD + h * DK + blk * 8,
                  Ks + (i * 32 + wid * 8) * 64);
    }
    // ---- stage V transposed: lane owns 2 kk-cols x 4 d-rows, 4B writes ----
#pragma unroll
    for (int j = 0; j < 2; ++j) {
      const int d0 = (wid * 2 + j) * 8 + dhalf * 4;
      const bf16_t* src = vp + ((size_t)(b * SEQ + kt * 64 + 2 * kidx)) * QVLD + h * DK + d0;
      ushort4 lo = *reinterpret_cast<const ushort4*>(src);
      ushort4 hv = *reinterpret_cast<const ushort4*>(src + QVLD);
      *reinterpret_cast<unsigned*>(&Vt[(d0 + 0) * 72 + 2 * kidx]) = (unsigned)lo.x | ((unsigned)hv.x << 16);
      *reinterpret_cast<unsigned*>(&Vt[(d0 + 1) * 72 + 2 * kidx]) = (unsigned)lo.y | ((unsigned)hv.y << 16);
      *reinterpret_cast<unsigned*>(&Vt[(d0 + 2) * 72 + 2 * kidx]) = (unsigned)lo.z | ((unsigned)hv.z << 16);
      *reinterpret_cast<unsigned*>(&Vt[(d0 + 3) * 72 + 2 * kidx]) = (unsigned)lo.w | ((unsigned)hv.w << 16);
      if (qt == 3) {
        cs[j * 4 + 0] += bf2f(lo.x) + bf2f(hv.x);
        cs[j * 4 + 1] += bf2f(lo.y) + bf2f(hv.y);
        cs[j * 4 + 2] += bf2f(lo.z) + bf2f(hv.z);
        cs[j * 4 + 3] += bf2f(lo.w) + bf2f(hv.w);
      }
    }
    __syncthreads();

    if (kt <= lastk) {
      const char* KsB = (const char*)Ks;
      bf16x8 kf[4][2];
#pragma unroll
      for (int mt = 0; mt < 4; ++mt)
#pragma unroll
        for (int ks = 0; ks < 2; ++ks)
          kf[mt][ks] = *reinterpret_cast<const bf16x8*>(
              KsB + (mt * 16 + c0) * 128 + 16 * ((4 * ks + grp) ^ (c0 & 7)));
      f32x4 s[4][2];
#pragma unroll
      for (int mt = 0; mt < 4; ++mt)
#pragma unroll
        for (int nt = 0; nt < 2; ++nt) s[mt][nt] = f32x4{0.f, 0.f, 0.f, 0.f};
      __builtin_amdgcn_s_setprio(1);
#pragma unroll
      for (int mt = 0; mt < 4; ++mt)
#pragma unroll
        for (int nt = 0; nt < 2; ++nt)
#pragma unroll
          for (int ks = 0; ks < 2; ++ks)
            s[mt][nt] = __builtin_amdgcn_mfma_f32_16x16x32_bf16(
                kf[mt][ks], qf[nt][ks], s[mt][nt], 0, 0, 0);
      __builtin_amdgcn_s_setprio(0);

      const bool masked = (kt == lastk);
      if (masked) {
#pragma unroll
        for (int nt = 0; nt < 2; ++nt) {
          const int q = qbase + nt * 16 + c0;
#pragma unroll
          for (int mt = 0; mt < 4; ++mt)
#pragma unroll
            for (int j = 0; j < 4; ++j) {
              int k = kt * 64 + mt * 16 + grp * 4 + j;
              if (k + strict > q) s[mt][nt][j] = -1e30f;
            }
        }
      }
      float mx[2];
#pragma unroll
      for (int nt = 0; nt < 2; ++nt) {
        float a = fmaxf(s[0][nt][0], s[0][nt][1]);
        a = fmaxf(fmaxf(a, s[0][nt][2]), s[0][nt][3]);
        float bm_ = fmaxf(s[1][nt][0], s[1][nt][1]);
        bm_ = fmaxf(fmaxf(bm_, s[1][nt][2]), s[1][nt][3]);
        float c = fmaxf(s[2][nt][0], s[2][nt][1]);
        c = fmaxf(fmaxf(c, s[2][nt][2]), s[2][nt][3]);
        float d = fmaxf(s[3][nt][0], s[3][nt][1]);
        d = fmaxf(fmaxf(d, s[3][nt][2]), s[3][nt][3]);
        float m_ = fmaxf(fmaxf(a, bm_), fmaxf(c, d));
        m_ = fmaxf(m_, __shfl_xor(m_, 16));
        m_ = fmaxf(m_, __shfl_xor(m_, 32));
        mx[nt] = m_;
      }
      const bool defer = __all((mx[0] - mreg[0] <= 8.f) && (mx[1] - mreg[1] <= 8.f));
      float sc[2];
#pragma unroll
      for (int nt = 0; nt < 2; ++nt) {
        const float mnew = defer ? mreg[nt] : fmaxf(mreg[nt], mx[nt]);
        float ts = 0.f;
#pragma unroll
        for (int mt = 0; mt < 4; ++mt)
#pragma unroll
          for (int j = 0; j < 4; ++j) {
            float pp = exp2f(s[mt][nt][j] - mnew);
            s[mt][nt][j] = pp; ts += pp;
          }
        ts += __shfl_xor(ts, 16);
        ts += __shfl_xor(ts, 32);
        if (defer) {
          lreg[nt] += ts;
        } else {
          sc[nt] = exp2f(mreg[nt] - mnew);
          lreg[nt] = lreg[nt] * sc[nt] + ts;
          mreg[nt] = mnew;
        }
      }
      char* PsB = (char*)(&Ps[wid][0]);
#pragma unroll
      for (int nt = 0; nt < 2; ++nt)
#pragma unroll
        for (int mt = 0; mt < 4; ++mt) {
          uint2 w;
          w.x = cvtpk(s[mt][nt][0], s[mt][nt][1]);
          w.y = cvtpk(s[mt][nt][2], s[mt][nt][3]);
          int row = nt * 16 + c0;
          int off = (row * 128 + mt * 32 + grp * 8) ^ ((c0 & 7) << 4);
          *reinterpret_cast<uint2*>(PsB + off) = w;
        }
      if (!defer) {
#pragma unroll
        for (int mtq = 0; mtq < 2; ++mtq) {
          f32x4 sv;
#pragma unroll
          for (int j = 0; j < 4; ++j) sv[j] = __shfl(sc[mtq], grp * 4 + j);
#pragma unroll
          for (int dt = 0; dt < 4; ++dt) acc[mtq][dt] *= sv;
        }
      }
      bf16x8 pf[2][2], vf2[4][2];
#pragma unroll
      for (int mtq = 0; mtq < 2; ++mtq)
#pragma unroll
        for (int ks = 0; ks < 2; ++ks)
          pf[mtq][ks] = *reinterpret_cast<const bf16x8*>(
              PsB + (mtq * 16 + c0) * 128 + 16 * ((4 * ks + grp) ^ (c0 & 7)));
#pragma unroll
      for (int dt = 0; dt < 4; ++dt)
#pragma unroll
        for (int ks = 0; ks < 2; ++ks)
          vf2[dt][ks] = *reinterpret_cast<const bf16x8*>(
              (const char*)Vt + (dt * 16 + c0) * 144 + ks * 64 + grp * 16);
      __builtin_amdgcn_s_setprio(1);
#pragma unroll
      for (int mtq = 0; mtq < 2; ++mtq)
#pragma unroll
        for (int dt = 0; dt < 4; ++dt)
#pragma unroll
          for (int ks = 0; ks < 2; ++ks)
            acc[mtq][dt] = __builtin_amdgcn_mfma_f32_16x16x32_bf16(
                pf[mtq][ks], vf2[dt][ks], acc[mtq][dt], 0, 0, 0);
      __builtin_amdgcn_s_setprio(0);
    }
    __syncthreads();
  }

  // ---- row-0 quirk: ctx[b,0,h,:] = factor * mean_k V (qt==3 block only) ----
  if (qt == 3) {
#pragma unroll
    for (int e = 0; e < 8; ++e)
#pragma unroll
      for (int off = 1; off <= 16; off <<= 1) cs[e] += __shfl_xor(cs[e], off);
    if ((lane & 31) == 0) {
#pragma unroll
      for (int e = 0; e < 8; ++e)
        csum[(wid * 2 + (e >> 2)) * 8 + dhalf * 4 + (e & 3)] = cs[e];
    }
    __syncthreads();
    if (tid < 64)
      ctx[((size_t)(b * SEQ)) * DM + h * DK + tid] = f2b(csum[tid] * (1.f / 512.f) * factor);
  }

  // ---- epilogue: /l, *routing, store (skip q==0) ----
#pragma unroll
  for (int mtq = 0; mtq < 2; ++mtq) {
    const float inv = factor / lreg[mtq];
    f32x4 iv;
#pragma unroll
    for (int j = 0; j < 4; ++j) iv[j] = __shfl(inv, grp * 4 + j);
#pragma unroll
    for (int j = 0; j < 4; ++j) {
      const int q = qbase + mtq * 16 + grp * 4 + j;
      if (q == 0) continue;
#pragma unroll
      for (int dt = 0; dt < 4; ++dt)
        ctx[((size_t)(b * SEQ + q)) * DM + h * DK + dt * 16 + c0] =
            f2b(acc[mtq][dt][j] * iv[j]);
    }
  }
}

// ---------------- add + layernorm: wave-per-row, bf16 residual ----------------
template <int OUT>
__global__ __launch_bounds__(256) void add_ln_kernel(
    const bf16_t* __restrict__ X, const bf16_t* __restrict__ A2,
    const float* __restrict__ gam, const float* __restrict__ bet,
    bf16_t* __restrict__ outb, float* __restrict__ outf) {
  const int wid = threadIdx.x >> 6, lane = threadIdx.x & 63;
  const size_t row = (size_t)blockIdx.x * 4 + wid;
  const size_t base = row * DM + lane * 8;
  uint4 xu = *reinterpret_cast<const uint4*>(X + base);
  uint4 au = *reinterpret_cast<const uint4*>(A2 + base);
  float z[8];
  {
    float p0, p1, q0, q1;
    unp2(xu.x, p0, p1); unp2(au.x, q0, q1); z[0] = p0 + q0; z[1] = p1 + q1;
    unp2(xu.y, p0, p1); unp2(au.y, q0, q1); z[2] = p0 + q0; z[3] = p1 + q1;
    unp2(xu.z, p0, p1); unp2(au.z, q0, q1); z[4] = p0 + q0; z[5] = p1 + q1;
    unp2(xu.w, p0, p1); unp2(au.w, q0, q1); z[6] = p0 + q0; z[7] = p1 + q1;
  }
  float s = 0.f;
#pragma unroll
  for (int e = 0; e < 8; ++e) s += z[e];
#pragma unroll
  for (int off = 32; off; off >>= 1) s += __shfl_xor(s, off);
  const float mean = s * (1.f / 512.f);
  float ss = 0.f;
#pragma unroll
  for (int e = 0; e < 8; ++e) { float d = z[e] - mean; ss += d * d; }
#pragma unroll
  for (int off = 32; off; off >>= 1) ss += __shfl_xor(ss, off);
  const float inv = rsqrtf(ss * (1.f / 512.f) + 1e-5f);
  float4 g0 = *reinterpret_cast<const float4*>(gam + lane * 8);
  float4 g1 = *reinterpret_cast<const float4*>(gam + lane * 8 + 4);
  float4 b0 = *reinterpret_cast<const float4*>(bet + lane * 8);
  float4 b1 = *reinterpret_cast<const float4*>(bet + lane * 8 + 4);
  float o[8];
  o[0] = (z[0] - mean) * inv * g0.x + b0.x;
  o[1] = (z[1] - mean) * inv * g0.y + b0.y;
  o[2] = (z[2] - mean) * inv * g0.z + b0.z;
  o[3] = (z[3] - mean) * inv * g0.w + b0.w;
  o[4] = (z[4] - mean) * inv * g1.x + b1.x;
  o[5] = (z[5] - mean) * inv * g1.y + b1.y;
  o[6] = (z[6] - mean) * inv * g1.z + b1.z;
  o[7] = (z[7] - mean) * inv * g1.w + b1.w;
  if (OUT == 0) {
    uint4 w;
    w.x = (unsigned)f2b(o[0]) | ((unsigned)f2b(o[1]) << 16);
    w.y = (unsigned)f2b(o[2]) | ((unsigned)f2b(o[3]) << 16);
    w.z = (unsigned)f2b(o[4]) | ((unsigned)f2b(o[5]) << 16);
    w.w = (unsigned)f2b(o[6]) | ((unsigned)f2b(o[7]) << 16);
    *reinterpret_cast<uint4*>(outb + base) = w;
  } else {
    float4 f0, f1;
    f0.x = o[0]; f0.y = o[1]; f0.z = o[2]; f0.w = o[3];
    f1.x = o[4]; f1.y = o[5]; f1.z = o[6]; f1.w = o[7];
    *reinterpret_cast<float4*>(outf + base) = f0;
    *reinterpret_cast<float4*>(outf + base + 4) = f1;
  }
}

// ---------------- balance ----------------
__global__ void balance_kernel(const float* __restrict__ fP, float* __restrict__ out) {
  if (threadIdx.x == 0 && blockIdx.x == 0) {
    float fs = 0.f, pssum = 0.f, P[6];
    for (int j = 0; j < 6; ++j) {
      fs += fP[j];
      P[j] = fP[6 + j] * (1.f / (float)MROWS);
      pssum += P[j];
    }
    float bal = 0.f;
    for (int j = 0; j < 6; ++j)
      bal += (fP[j] / (fs + 1e-5f)) * (P[j] / (pssum + 1e-5f));
    out[0] = bal;
  }
}

// ---------------- host ----------------
extern "C" void kernel_launch(void* const* d_in, const int* in_sizes, int n_in,
                              void* d_out, int out_size, void* d_ws, size_t ws_size,
                              hipStream_t stream) {
  (void)in_sizes; (void)n_in; (void)out_size; (void)ws_size;
  const float* q_embed  = (const float*)d_in[0];
  const float* qa_embed = (const float*)d_in[1];
  const float* Wq  = (const float*)d_in[2];
  const float* bq  = (const float*)d_in[3];
  const float* Wv  = (const float*)d_in[4];
  const float* bv  = (const float*)d_in[5];
  const float* Wg  = (const float*)d_in[6];
  const float* Wo  = (const float*)d_in[7];
  const float* bo  = (const float*)d_in[8];
  const float* ln1g = (const float*)d_in[9];
  const float* ln1b = (const float*)d_in[10];
  const float* W1  = (const float*)d_in[11];
  const float* b1  = (const float*)d_in[12];
  const float* W2  = (const float*)d_in[13];
  const float* b2  = (const float*)d_in[14];
  const float* ln2g = (const float*)d_in[15];
  const float* ln2b = (const float*)d_in[16];

  char* p = (char*)d_ws;
  auto alloc = [&](size_t bytes) -> char* {
    char* r = p; p += (bytes + 255) & ~(size_t)255; return r;
  };
  const size_t WDE = (size_t)NL * DM * DM;   // stacked weight elems (per tensor)
  const size_t AE  = (size_t)MROWS * DM;     // activation elems
  bf16_t* wall_b = (bf16_t*)alloc(5 * WDE * 2);   // wq|wv|wo|w1|w2 contiguous
  bf16_t* wq_b = wall_b;
  bf16_t* wv_b = wall_b + WDE;
  bf16_t* wo_b = wall_b + 2 * WDE;
  bf16_t* w1_b = wall_b + 3 * WDE;
  bf16_t* w2_b = wall_b + 4 * WDE;
  bf16_t* y_b   = (bf16_t*)alloc(AE * 2);
  bf16_t* x_b   = (bf16_t*)alloc(AE * 2);
  bf16_t* qv_b  = (bf16_t*)alloc((size_t)MROWS * QVLD * 2);  // q|v merged
  bf16_t* ctx_b = (bf16_t*)alloc(AE * 2);
  bf16_t* x1_b  = (bf16_t*)alloc(AE * 2);
  bf16_t* tmp_b = (bf16_t*)alloc(AE * 2);
  bf16_t* ffn1_b = (bf16_t*)alloc(AE * 2);
  float* stats = (float*)alloc(NL * (12 + BSZ * 6) * 4);  // fP[NL][12] | rdyn[NL][32][6]
  float* fPbase = stats;
  float* rdynbase = stats + NL * 12;

  hipMemsetAsync(stats, 0, NL * (12 + BSZ * 6) * 4, stream);

  f2bw_kernel<<<dim3((unsigned)(WDE / 4 / 256), 5), 256, 0, stream>>>(
      Wq, Wv, Wo, W1, W2, wall_b);
  f2b2_kernel<<<dim3((unsigned)(AE / 4 / 256), 2), 256, 0, stream>>>(
      qa_embed, q_embed, y_b, x_b);

  const size_t DD = (size_t)DM * DM;
  dim3 gqv(8, 128), gn5(4, 256), gfa(256, 4);
  float* outx = (float*)d_out;

  auto layer = [&](int i, bf16_t* resb, const bf16_t* xvb, int strict, bool last) {
    float* fP = fPbase + i * 12;
    float* rdyn = rdynbase + i * (BSZ * 6);
    gemm_qv<<<gqv, 256, 0, stream>>>(
        resb, xvb, wq_b + i * DD, wv_b + i * DD, bq + i * DM, bv + i * DM, qv_b);
    gates_kernel<<<MROWS / 32, 256, 0, stream>>>(qv_b, Wg + (size_t)i * HD_ * DM, rdyn, fP);
    fattn_kernel<<<gfa, 256, 0, stream>>>(qv_b, rdyn, ctx_b, strict);
    gemm_n512<false><<<gn5, 256, 0, stream>>>(ctx_b, wo_b + i * DD, bo + i * DM, tmp_b);
    add_ln_kernel<0><<<MROWS / 4, 256, 0, stream>>>(
        resb, tmp_b, ln1g + i * DM, ln1b + i * DM, x1_b, nullptr);
    gemm_n512<true><<<gn5, 256, 0, stream>>>(x1_b, w1_b + i * DD, b1 + i * DM, ffn1_b);
    gemm_n512<false><<<gn5, 256, 0, stream>>>(ffn1_b, w2_b + i * DD, b2 + i * DM, tmp_b);
    if (last)
      add_ln_kernel<1><<<MROWS / 4, 256, 0, stream>>>(
          x1_b, tmp_b, ln2g + i * DM, ln2b + i * DM, nullptr, outx);
    else
      add_ln_kernel<0><<<MROWS / 4, 256, 0, stream>>>(
          x1_b, tmp_b, ln2g + i * DM, ln2b + i * DM, resb, nullptr);
  };

  layer(0, y_b, y_b, 0, false);
  layer(1, y_b, y_b, 0, false);
  layer(2, x_b, x_b, 0, false);
  layer(3, x_b, y_b, 1, false);
  layer(4, x_b, x_b, 0, false);
  layer(5, x_b, y_b, 1, true);
  balance_kernel<<<1, 64, 0, stream>>>(fPbase + 5 * 12, outx + (size_t)MROWS * DM);
}

// Round 10
// 899.876 us; speedup vs baseline: 11.2856x; 1.0771x over previous
//
#include <hip/hip_runtime.h>
#include <cstdint>

// ---------------- constants ----------------
#define BSZ 32
#define SEQ 512
#define DM  512
#define NH  8
#define DK  64
#define HS_ 2
#define HD_ 6
#define NL  6
#define MROWS (BSZ*SEQ)          // 16384
#define QVLD 1024                // row stride of merged q|v buffer
#define SCL 0.18033688011112043f // 0.125 * log2(e)  (exp2 domain)

typedef unsigned short bf16_t;
typedef __attribute__((ext_vector_type(4))) float f32x4;
typedef __attribute__((ext_vector_type(8))) short bf16x8;
typedef __attribute__((ext_vector_type(8))) unsigned short u16x8;

#define DEV static __device__ __forceinline__

DEV float bf2f(bf16_t b) {
  unsigned int u = ((unsigned int)b) << 16;
  float f; __builtin_memcpy(&f, &u, 4); return f;
}
DEV bf16_t f2b(float f) {  // RNE bf16 (finite inputs)
  unsigned int u; __builtin_memcpy(&u, &f, 4);
  unsigned int r = (u + 0x7fffu + ((u >> 16) & 1u)) >> 16;
  return (bf16_t)r;
}
DEV void unp2(unsigned int w, float& a, float& b) {
  unsigned int ua = w << 16, ub = w & 0xffff0000u;
  __builtin_memcpy(&a, &ua, 4); __builtin_memcpy(&b, &ub, 4);
}
DEV unsigned cvtpk(float lo, float hi) {
  unsigned r;
  asm("v_cvt_pk_bf16_f32 %0, %1, %2" : "=v"(r) : "v"(lo), "v"(hi));
  return r;
}

DEV void gload_lds16(const bf16_t* g, bf16_t* l) {
  __builtin_amdgcn_global_load_lds(
      (const __attribute__((address_space(1))) void*)g,
      (__attribute__((address_space(3))) void*)l, 16, 0, 0);
}

// scale a bf16x8 Q fragment by SCL (exp2-domain pre-scale)
DEV bf16x8 scale_q(bf16x8 v) {
  u16x8 u;
  __builtin_memcpy(&u, &v, 16);
  unsigned w[4];
#pragma unroll
  for (int e = 0; e < 4; ++e)
    w[e] = cvtpk(bf2f(u[2 * e]) * SCL, bf2f(u[2 * e + 1]) * SCL);
  bf16x8 r;
  __builtin_memcpy(&r, w, 16);
  return r;
}

// ---------------- f32 -> bf16 converts ----------------
__global__ __launch_bounds__(256) void f2b2_kernel(
    const float* __restrict__ s0, const float* __restrict__ s1,
    bf16_t* __restrict__ d0, bf16_t* __restrict__ d1) {
  const float* s = blockIdx.y ? s1 : s0;
  bf16_t* d = blockIdx.y ? d1 : d0;
  const int i = blockIdx.x * 256 + threadIdx.x;
  float4 v = reinterpret_cast<const float4*>(s)[i];
  ushort4 o;
  o.x = f2b(v.x); o.y = f2b(v.y); o.z = f2b(v.z); o.w = f2b(v.w);
  reinterpret_cast<ushort4*>(d)[i] = o;
}

__global__ __launch_bounds__(256) void f2bw_kernel(
    const float* __restrict__ s0, const float* __restrict__ s1,
    const float* __restrict__ s2, const float* __restrict__ s3,
    const float* __restrict__ s4, bf16_t* __restrict__ dst) {
  const float* srcs[5] = {s0, s1, s2, s3, s4};
  const float* s = srcs[blockIdx.y];
  bf16_t* d = dst + (size_t)blockIdx.y * ((size_t)NL * DM * DM);
  const int i = blockIdx.x * 256 + threadIdx.x;
  float4 v = reinterpret_cast<const float4*>(s)[i];
  ushort4 o;
  o.x = f2b(v.x); o.y = f2b(v.y); o.z = f2b(v.z); o.w = f2b(v.w);
  reinterpret_cast<ushort4*>(d)[i] = o;
}

// ---------------- deep-pipelined MFMA GEMM (128x256 tile, BK=64) ----------------
// 512 thr, 8 waves (2M x 4N), per-wave 64x64 out. 3 LDS buffers, counted vmcnt(6):
// group g computes K-tile g from buf g%3 while staging tile g+2 into buf (g+2)%3
// (that buffer's tile g-1 was fully consumed before group g started -> no WAR).
// LDS swizzle: byte ^= (row&7)<<4 via pre-swizzled global source (linear DMA dest)
// + swizzled ds_read. W split at col 512 (W0/W1, b0/b1); A split likewise (A0/A1).
template <int NB, int NWG, bool RELU>
__global__ __launch_bounds__(512) void gemm8(
    const bf16_t* __restrict__ A0, const bf16_t* __restrict__ A1,
    const bf16_t* __restrict__ W0, const bf16_t* __restrict__ W1,
    const float* __restrict__ b0, const float* __restrict__ b1,
    bf16_t* __restrict__ Yb, int ldy) {
  const int K = 512;
  const int lin = blockIdx.y * NB + blockIdx.x;
  const int cpx = NWG / 8;
  const int swz = (lin & 7) * cpx + (lin >> 3);
  const int bn = swz % NB, bm = swz / NB;
  const int tid = threadIdx.x, wid = tid >> 6, lane = tid & 63;
  const int wr = wid >> 2, wc = wid & 3;        // 2M x 4N waves
  const int lrow = lane & 15, grp = lane >> 4;
  const int l3 = lane >> 3, c3 = lane & 7;

  __shared__ __align__(16) bf16_t Lds[3][24576]; // per buf: A[128][64] | B[256][64]

  const bool hi = (bn * 256) >= 512;
  const bf16_t* Asel = hi ? A1 : A0;
  const bf16_t* Wsel = hi ? (W1 - (size_t)512 * K) : W0;
  const float* bsel = hi ? (b1 - 512) : b0;

  f32x4 acc[4][4];
#pragma unroll
  for (int m = 0; m < 4; ++m)
#pragma unroll
    for (int n = 0; n < 4; ++n) acc[m][n] = f32x4{0.f, 0.f, 0.f, 0.f};

  const char* LB = (const char*)Lds;

  // stage 3 chunks (1KB each) of K-tile kt into buffer buf; half = 0/1
  auto stage3 = [&](int kt, int buf, int half) {
#pragma unroll
    for (int cc = 0; cc < 3; ++cc) {
      const int c = wid + (half * 3 + cc) * 8;    // 0..47
      const int colb = ((c3 ^ l3) * 8);           // pre-swizzled 16B col
      if (c < 16) {                               // A chunk: rows c*8..c*8+7
        gload_lds16(Asel + (size_t)(bm * 128 + c * 8 + l3) * K + kt * 64 + colb,
                    &Lds[buf][c * 512]);
      } else {                                    // B chunk
        const int cb = c - 16;
        gload_lds16(Wsel + (size_t)(bn * 256 + cb * 8 + l3) * K + kt * 64 + colb,
                    &Lds[buf][8192 + cb * 512]);
      }
    }
  };
  auto rdA = [&](int buf, int rA, int ks) -> bf16x8 {
    const int off = buf * 49152 + rA * 128 + ((ks * 64 + grp * 16) ^ ((rA & 7) << 4));
    return *reinterpret_cast<const bf16x8*>(LB + off);
  };
  auto rdB = [&](int buf, int rB, int ks) -> bf16x8 {
    const int off = buf * 49152 + 16384 + rB * 128 + ((ks * 64 + grp * 16) ^ ((rB & 7) << 4));
    return *reinterpret_cast<const bf16x8*>(LB + off);
  };

  // ---- prologue: tiles 0,1 -> buf 0,1 ----
  stage3(0, 0, 0); stage3(0, 0, 1);
  stage3(1, 1, 0); stage3(1, 1, 1);
  asm volatile("s_waitcnt vmcnt(6)" ::: "memory");   // tile0 resident
  __builtin_amdgcn_s_barrier();

  for (int g = 0; g < 8; ++g) {
    const int bufR = g % 3, bufW = (g + 2) % 3;
    const bool st = g < 6;
    // ---- phase 1: B(8) + A-quad0(4) reads, stage half0, 16 MFMA ----
    bf16x8 bwv[4][2], afv[2][2];
#pragma unroll
    for (int n = 0; n < 4; ++n)
#pragma unroll
      for (int ks = 0; ks < 2; ++ks)
        bwv[n][ks] = rdB(bufR, wc * 64 + n * 16 + lrow, ks);
#pragma unroll
    for (int m = 0; m < 2; ++m)
#pragma unroll
      for (int ks = 0; ks < 2; ++ks)
        afv[m][ks] = rdA(bufR, wr * 64 + m * 16 + lrow, ks);
    if (st) stage3(g + 2, bufW, 0);
    __builtin_amdgcn_s_barrier();
    asm volatile("s_waitcnt lgkmcnt(0)" ::: "memory");
    __builtin_amdgcn_s_setprio(1);
#pragma unroll
    for (int ks = 0; ks < 2; ++ks)
#pragma unroll
      for (int m = 0; m < 2; ++m)
#pragma unroll
        for (int n = 0; n < 4; ++n)
          acc[m][n] = __builtin_amdgcn_mfma_f32_16x16x32_bf16(afv[m][ks], bwv[n][ks], acc[m][n], 0, 0, 0);
    __builtin_amdgcn_s_setprio(0);
    __builtin_amdgcn_s_barrier();
    // ---- phase 2: A-quad1(4) reads, stage half1, 16 MFMA, counted vmcnt ----
#pragma unroll
    for (int m = 0; m < 2; ++m)
#pragma unroll
      for (int ks = 0; ks < 2; ++ks)
        afv[m][ks] = rdA(bufR, wr * 64 + 32 + m * 16 + lrow, ks);
    if (st) stage3(g + 2, bufW, 1);
    __builtin_amdgcn_s_barrier();
    asm volatile("s_waitcnt lgkmcnt(0)" ::: "memory");
    __builtin_amdgcn_s_setprio(1);
#pragma unroll
    for (int ks = 0; ks < 2; ++ks)
#pragma unroll
      for (int m = 0; m < 2; ++m)
#pragma unroll
        for (int n = 0; n < 4; ++n)
          acc[2 + m][n] = __builtin_amdgcn_mfma_f32_16x16x32_bf16(afv[m][ks], bwv[n][ks], acc[2 + m][n], 0, 0, 0);
    __builtin_amdgcn_s_setprio(0);
    if (g < 6) {
      asm volatile("s_waitcnt vmcnt(6)" ::: "memory");   // tile g+1 resident
    } else if (g == 6) {
      asm volatile("s_waitcnt vmcnt(0)" ::: "memory");   // final drain (tile 7)
    }
    __builtin_amdgcn_s_barrier();
  }

  // ---- epilogue: bias (+relu), bf16 store ----
  const int r0 = bm * 128 + wr * 64 + grp * 4;
  const int c0 = bn * 256 + wc * 64 + lrow;
#pragma unroll
  for (int n = 0; n < 4; ++n) {
    const int col = c0 + n * 16;
    const float bc = bsel[col];
#pragma unroll
    for (int qm = 0; qm < 4; ++qm)
#pragma unroll
      for (int j = 0; j < 4; ++j) {
        float v = acc[qm][n][j] + bc;
        if (RELU) v = fmaxf(v, 0.f);
        Yb[(size_t)(r0 + qm * 16 + j) * ldy + col] = f2b(v);
      }
  }
}

// ---------------- gating: softmax(q @ Wg^T), top-4-of-6, fused routing ----------------
__global__ __launch_bounds__(256) void gates_kernel(
    const bf16_t* __restrict__ qv, const float* __restrict__ Wg,
    float* __restrict__ rdyn, float* __restrict__ fP) {
  __shared__ float wg_s[HD_ * DM];
  __shared__ float blk[4][18];
  const int tid = threadIdx.x, wid = tid >> 6, lane = tid & 63;
  for (int i = tid; i < HD_ * DM / 4; i += 256)
    reinterpret_cast<float4*>(wg_s)[i] = reinterpret_cast<const float4*>(Wg)[i];
  __syncthreads();
  const int bb = blockIdx.x >> 4;
  const int t0 = (blockIdx.x & 15) * 32 + wid * 8;
  float fs[6] = {0, 0, 0, 0, 0, 0}, ps[6] = {0, 0, 0, 0, 0, 0}, rs[6] = {0, 0, 0, 0, 0, 0};
  for (int it = 0; it < 8; ++it) {
    const int tok = bb * SEQ + t0 + it;
    uint4 u = reinterpret_cast<const uint4*>(qv + (size_t)tok * QVLD)[lane];
    float x[8];
    unp2(u.x, x[0], x[1]); unp2(u.y, x[2], x[3]);
    unp2(u.z, x[4], x[5]); unp2(u.w, x[6], x[7]);
    float g[6];
#pragma unroll
    for (int j = 0; j < 6; ++j) {
      float p = 0.f;
#pragma unroll
      for (int e = 0; e < 8; ++e) p = fmaf(x[e], wg_s[j * DM + lane * 8 + e], p);
#pragma unroll
      for (int off = 32; off; off >>= 1) p += __shfl_xor(p, off);
      g[j] = p;
    }
    float mx = g[0];
#pragma unroll
    for (int j = 1; j < 6; ++j) mx = fmaxf(mx, g[j]);
    float se = 0.f;
#pragma unroll
    for (int j = 0; j < 6; ++j) { g[j] = __expf(g[j] - mx); se += g[j]; }
    float inv = 1.f / se;
#pragma unroll
    for (int j = 0; j < 6; ++j) g[j] *= inv;
    int d1 = 0;
#pragma unroll
    for (int j = 1; j < 6; ++j)
      if (g[j] < g[d1] || (g[j] == g[d1] && j > d1)) d1 = j;
    int d2 = (d1 == 0) ? 1 : 0;
#pragma unroll
    for (int j = 0; j < 6; ++j) {
      if (j == d1) continue;
      if (g[j] < g[d2] || (g[j] == g[d2] && j > d2)) d2 = j;
    }
#pragma unroll
    for (int j = 0; j < 6; ++j) {
      const bool drop = (j == d1) || (j == d2);
      fs[j] += drop ? 0.f : 1.f;
      ps[j] += g[j];
      rs[j] += drop ? 0.f : g[j];
    }
  }
  if (lane == 0) {
#pragma unroll
    for (int j = 0; j < 6; ++j) {
      blk[wid][j] = fs[j]; blk[wid][6 + j] = ps[j]; blk[wid][12 + j] = rs[j];
    }
  }
  __syncthreads();
  if (tid < 18) {
    float s = blk[0][tid] + blk[1][tid] + blk[2][tid] + blk[3][tid];
    if (tid < 12) atomicAdd(&fP[tid], s);
    else atomicAdd(&rdyn[bb * 6 + (tid - 12)], s * (1.f / 512.f));
  }
}

// ---------------- fused flash attention (MFMA, row0 fused, occupancy grid) ----
__global__ __launch_bounds__(256, 2) void fattn_kernel(
    const bf16_t* __restrict__ qv, const float* __restrict__ rdyn,
    bf16_t* __restrict__ ctx, int strict) {
  const int bh = blockIdx.x, qt = blockIdx.y;
  const int b = bh >> 3, h = bh & 7;
  const int tid = threadIdx.x, wid = tid >> 6, lane = tid & 63;
  const int c0 = lane & 15, grp = lane >> 4;
  const int l3 = lane >> 3, c3 = lane & 7;
  const int kidx = lane & 31, dhalf = lane >> 5;

  __shared__ __align__(16) bf16_t Ks[64 * 64];        // swizzled [64k][64ch]
  __shared__ __align__(16) bf16_t Vt[64 * 72];        // transposed [64d][64k+8pad]
  __shared__ __align__(16) bf16_t Ps[4][32 * 64];     // per-wave P, swizzled
  __shared__ float csum[64];

  const bf16_t* qp = qv;          // q half, row stride QVLD
  const bf16_t* vp = qv + 512;    // v half
  const float factor = (h < HS_) ? 1.f : rdyn[b * 6 + (h - HS_)];

  const int qbase = qt * 128 + wid * 32;

  bf16x8 qf[2][2];
#pragma unroll
  for (int nt = 0; nt < 2; ++nt)
#pragma unroll
    for (int ks = 0; ks < 2; ++ks)
      qf[nt][ks] = scale_q(*reinterpret_cast<const bf16x8*>(
          qp + ((size_t)(b * SEQ + qbase + nt * 16 + c0)) * QVLD + h * DK + ks * 32 + grp * 8));

  f32x4 acc[2][4];
#pragma unroll
  for (int m = 0; m < 2; ++m)
#pragma unroll
    for (int d = 0; d < 4; ++d) acc[m][d] = f32x4{0.f, 0.f, 0.f, 0.f};
  float mreg[2] = {-3e38f, -3e38f};
  float lreg[2] = {0.f, 0.f};
  float cs[8] = {0, 0, 0, 0, 0, 0, 0, 0};   // V column-sum partials (qt==3)

  const int lastk = (qbase + 31 - strict) >> 6;
  const int ktmax = 2 * qt + 1;

  for (int kt = 0; kt <= ktmax; ++kt) {
#pragma unroll
    for (int i = 0; i < 2; ++i) {
      int row = i * 32 + wid * 8 + l3;
      int blk = c3 ^ l3;
      gload_lds16(qp + ((size_t)(b * SEQ + kt * 64 + row)) * QVLD + h * DK + blk * 8,
                  Ks + (i * 32 + wid * 8) * 64);
    }
#pragma unroll
    for (int j = 0; j < 2; ++j) {
      const int d0 = (wid * 2 + j) * 8 + dhalf * 4;
      const bf16_t* src = vp + ((size_t)(b * SEQ + kt * 64 + 2 * kidx)) * QVLD + h * DK + d0;
      ushort4 lo = *reinterpret_cast<const ushort4*>(src);
      ushort4 hv = *reinterpret_cast<const ushort4*>(src + QVLD);
      *reinterpret_cast<unsigned*>(&Vt[(d0 + 0) * 72 + 2 * kidx]) = (unsigned)lo.x | ((unsigned)hv.x << 16);
      *reinterpret_cast<unsigned*>(&Vt[(d0 + 1) * 72 + 2 * kidx]) = (unsigned)lo.y | ((unsigned)hv.y << 16);
      *reinterpret_cast<unsigned*>(&Vt[(d0 + 2) * 72 + 2 * kidx]) = (unsigned)lo.z | ((unsigned)hv.z << 16);
      *reinterpret_cast<unsigned*>(&Vt[(d0 + 3) * 72 + 2 * kidx]) = (unsigned)lo.w | ((unsigned)hv.w << 16);
      if (qt == 3) {
        cs[j * 4 + 0] += bf2f(lo.x) + bf2f(hv.x);
        cs[j * 4 + 1] += bf2f(lo.y) + bf2f(hv.y);
        cs[j * 4 + 2] += bf2f(lo.z) + bf2f(hv.z);
        cs[j * 4 + 3] += bf2f(lo.w) + bf2f(hv.w);
      }
    }
    __syncthreads();

    if (kt <= lastk) {
      const char* KsB = (const char*)Ks;
      bf16x8 kf[4][2];
#pragma unroll
      for (int mt = 0; mt < 4; ++mt)
#pragma unroll
        for (int ks = 0; ks < 2; ++ks)
          kf[mt][ks] = *reinterpret_cast<const bf16x8*>(
              KsB + (mt * 16 + c0) * 128 + 16 * ((4 * ks + grp) ^ (c0 & 7)));
      f32x4 s[4][2];
#pragma unroll
      for (int mt = 0; mt < 4; ++mt)
#pragma unroll
        for (int nt = 0; nt < 2; ++nt) s[mt][nt] = f32x4{0.f, 0.f, 0.f, 0.f};
      __builtin_amdgcn_s_setprio(1);
#pragma unroll
      for (int mt = 0; mt < 4; ++mt)
#pragma unroll
        for (int nt = 0; nt < 2; ++nt)
#pragma unroll
          for (int ks = 0; ks < 2; ++ks)
            s[mt][nt] = __builtin_amdgcn_mfma_f32_16x16x32_bf16(
                kf[mt][ks], qf[nt][ks], s[mt][nt], 0, 0, 0);
      __builtin_amdgcn_s_setprio(0);

      const bool masked = (kt == lastk);
      if (masked) {
#pragma unroll
        for (int nt = 0; nt < 2; ++nt) {
          const int q = qbase + nt * 16 + c0;
#pragma unroll
          for (int mt = 0; mt < 4; ++mt)
#pragma unroll
            for (int j = 0; j < 4; ++j) {
              int k = kt * 64 + mt * 16 + grp * 4 + j;
              if (k + strict > q) s[mt][nt][j] = -1e30f;
            }
        }
      }
      float mx[2];
#pragma unroll
      for (int nt = 0; nt < 2; ++nt) {
        float a = fmaxf(s[0][nt][0], s[0][nt][1]);
        a = fmaxf(fmaxf(a, s[0][nt][2]), s[0][nt][3]);
        float bm_ = fmaxf(s[1][nt][0], s[1][nt][1]);
        bm_ = fmaxf(fmaxf(bm_, s[1][nt][2]), s[1][nt][3]);
        float c = fmaxf(s[2][nt][0], s[2][nt][1]);
        c = fmaxf(fmaxf(c, s[2][nt][2]), s[2][nt][3]);
        float d = fmaxf(s[3][nt][0], s[3][nt][1]);
        d = fmaxf(fmaxf(d, s[3][nt][2]), s[3][nt][3]);
        float m_ = fmaxf(fmaxf(a, bm_), fmaxf(c, d));
        m_ = fmaxf(m_, __shfl_xor(m_, 16));
        m_ = fmaxf(m_, __shfl_xor(m_, 32));
        mx[nt] = m_;
      }
      const bool defer = __all((mx[0] - mreg[0] <= 8.f) && (mx[1] - mreg[1] <= 8.f));
      float sc[2];
#pragma unroll
      for (int nt = 0; nt < 2; ++nt) {
        const float mnew = defer ? mreg[nt] : fmaxf(mreg[nt], mx[nt]);
        float ts = 0.f;
#pragma unroll
        for (int mt = 0; mt < 4; ++mt)
#pragma unroll
          for (int j = 0; j < 4; ++j) {
            float pp = exp2f(s[mt][nt][j] - mnew);
            s[mt][nt][j] = pp; ts += pp;
          }
        ts += __shfl_xor(ts, 16);
        ts += __shfl_xor(ts, 32);
        if (defer) {
          lreg[nt] += ts;
        } else {
          sc[nt] = exp2f(mreg[nt] - mnew);
          lreg[nt] = lreg[nt] * sc[nt] + ts;
          mreg[nt] = mnew;
        }
      }
      char* PsB = (char*)(&Ps[wid][0]);
#pragma unroll
      for (int nt = 0; nt < 2; ++nt)
#pragma unroll
        for (int mt = 0; mt < 4; ++mt) {
          uint2 w;
          w.x = cvtpk(s[mt][nt][0], s[mt][nt][1]);
          w.y = cvtpk(s[mt][nt][2], s[mt][nt][3]);
          int row = nt * 16 + c0;
          int off = (row * 128 + mt * 32 + grp * 8) ^ ((c0 & 7) << 4);
          *reinterpret_cast<uint2*>(PsB + off) = w;
        }
      if (!defer) {
#pragma unroll
        for (int mtq = 0; mtq < 2; ++mtq) {
          f32x4 sv;
#pragma unroll
          for (int j = 0; j < 4; ++j) sv[j] = __shfl(sc[mtq], grp * 4 + j);
#pragma unroll
          for (int dt = 0; dt < 4; ++dt) acc[mtq][dt] *= sv;
        }
      }
      bf16x8 pf[2][2], vf2[4][2];
#pragma unroll
      for (int mtq = 0; mtq < 2; ++mtq)
#pragma unroll
        for (int ks = 0; ks < 2; ++ks)
          pf[mtq][ks] = *reinterpret_cast<const bf16x8*>(
              PsB + (mtq * 16 + c0) * 128 + 16 * ((4 * ks + grp) ^ (c0 & 7)));
#pragma unroll
      for (int dt = 0; dt < 4; ++dt)
#pragma unroll
        for (int ks = 0; ks < 2; ++ks)
          vf2[dt][ks] = *reinterpret_cast<const bf16x8*>(
              (const char*)Vt + (dt * 16 + c0) * 144 + ks * 64 + grp * 16);
      __builtin_amdgcn_s_setprio(1);
#pragma unroll
      for (int mtq = 0; mtq < 2; ++mtq)
#pragma unroll
        for (int dt = 0; dt < 4; ++dt)
#pragma unroll
          for (int ks = 0; ks < 2; ++ks)
            acc[mtq][dt] = __builtin_amdgcn_mfma_f32_16x16x32_bf16(
                pf[mtq][ks], vf2[dt][ks], acc[mtq][dt], 0, 0, 0);
      __builtin_amdgcn_s_setprio(0);
    }
    __syncthreads();
  }

  if (qt == 3) {
#pragma unroll
    for (int e = 0; e < 8; ++e)
#pragma unroll
      for (int off = 1; off <= 16; off <<= 1) cs[e] += __shfl_xor(cs[e], off);
    if ((lane & 31) == 0) {
#pragma unroll
      for (int e = 0; e < 8; ++e)
        csum[(wid * 2 + (e >> 2)) * 8 + dhalf * 4 + (e & 3)] = cs[e];
    }
    __syncthreads();
    if (tid < 64)
      ctx[((size_t)(b * SEQ)) * DM + h * DK + tid] = f2b(csum[tid] * (1.f / 512.f) * factor);
  }

#pragma unroll
  for (int mtq = 0; mtq < 2; ++mtq) {
    const float inv = factor / lreg[mtq];
    f32x4 iv;
#pragma unroll
    for (int j = 0; j < 4; ++j) iv[j] = __shfl(inv, grp * 4 + j);
#pragma unroll
    for (int j = 0; j < 4; ++j) {
      const int q = qbase + mtq * 16 + grp * 4 + j;
      if (q == 0) continue;
#pragma unroll
      for (int dt = 0; dt < 4; ++dt)
        ctx[((size_t)(b * SEQ + q)) * DM + h * DK + dt * 16 + c0] =
            f2b(acc[mtq][dt][j] * iv[j]);
    }
  }
}

// ---------------- add + layernorm: wave-per-row, bf16 residual ----------------
template <int OUT>
__global__ __launch_bounds__(256) void add_ln_kernel(
    const bf16_t* __restrict__ X, const bf16_t* __restrict__ A2,
    const float* __restrict__ gam, const float* __restrict__ bet,
    bf16_t* __restrict__ outb, float* __restrict__ outf) {
  const int wid = threadIdx.x >> 6, lane = threadIdx.x & 63;
  const size_t row = (size_t)blockIdx.x * 4 + wid;
  const size_t base = row * DM + lane * 8;
  uint4 xu = *reinterpret_cast<const uint4*>(X + base);
  uint4 au = *reinterpret_cast<const uint4*>(A2 + base);
  float z[8];
  {
    float p0, p1, q0, q1;
    unp2(xu.x, p0, p1); unp2(au.x, q0, q1); z[0] = p0 + q0; z[1] = p1 + q1;
    unp2(xu.y, p0, p1); unp2(au.y, q0, q1); z[2] = p0 + q0; z[3] = p1 + q1;
    unp2(xu.z, p0, p1); unp2(au.z, q0, q1); z[4] = p0 + q0; z[5] = p1 + q1;
    unp2(xu.w, p0, p1); unp2(au.w, q0, q1); z[6] = p0 + q0; z[7] = p1 + q1;
  }
  float s = 0.f;
#pragma unroll
  for (int e = 0; e < 8; ++e) s += z[e];
#pragma unroll
  for (int off = 32; off; off >>= 1) s += __shfl_xor(s, off);
  const float mean = s * (1.f / 512.f);
  float ss = 0.f;
#pragma unroll
  for (int e = 0; e < 8; ++e) { float d = z[e] - mean; ss += d * d; }
#pragma unroll
  for (int off = 32; off; off >>= 1) ss += __shfl_xor(ss, off);
  const float inv = rsqrtf(ss * (1.f / 512.f) + 1e-5f);
  float4 g0 = *reinterpret_cast<const float4*>(gam + lane * 8);
  float4 g1 = *reinterpret_cast<const float4*>(gam + lane * 8 + 4);
  float4 b0 = *reinterpret_cast<const float4*>(bet + lane * 8);
  float4 b1 = *reinterpret_cast<const float4*>(bet + lane * 8 + 4);
  float o[8];
  o[0] = (z[0] - mean) * inv * g0.x + b0.x;
  o[1] = (z[1] - mean) * inv * g0.y + b0.y;
  o[2] = (z[2] - mean) * inv * g0.z + b0.z;
  o[3] = (z[3] - mean) * inv * g0.w + b0.w;
  o[4] = (z[4] - mean) * inv * g1.x + b1.x;
  o[5] = (z[5] - mean) * inv * g1.y + b1.y;
  o[6] = (z[6] - mean) * inv * g1.z + b1.z;
  o[7] = (z[7] - mean) * inv * g1.w + b1.w;
  if (OUT == 0) {
    uint4 w;
    w.x = (unsigned)f2b(o[0]) | ((unsigned)f2b(o[1]) << 16);
    w.y = (unsigned)f2b(o[2]) | ((unsigned)f2b(o[3]) << 16);
    w.z = (unsigned)f2b(o[4]) | ((unsigned)f2b(o[5]) << 16);
    w.w = (unsigned)f2b(o[6]) | ((unsigned)f2b(o[7]) << 16);
    *reinterpret_cast<uint4*>(outb + base) = w;
  } else {
    float4 f0, f1;
    f0.x = o[0]; f0.y = o[1]; f0.z = o[2]; f0.w = o[3];
    f1.x = o[4]; f1.y = o[5]; f1.z = o[6]; f1.w = o[7];
    *reinterpret_cast<float4*>(outf + base) = f0;
    *reinterpret_cast<float4*>(outf + base + 4) = f1;
  }
}

// ---------------- balance ----------------
__global__ void balance_kernel(const float* __restrict__ fP, float* __restrict__ out) {
  if (threadIdx.x == 0 && blockIdx.x == 0) {
    float fs = 0.f, pssum = 0.f, P[6];
    for (int j = 0; j < 6; ++j) {
      fs += fP[j];
      P[j] = fP[6 + j] * (1.f / (float)MROWS);
      pssum += P[j];
    }
    float bal = 0.f;
    for (int j = 0; j < 6; ++j)
      bal += (fP[j] / (fs + 1e-5f)) * (P[j] / (pssum + 1e-5f));
    out[0] = bal;
  }
}

// ---------------- host ----------------
extern "C" void kernel_launch(void* const* d_in, const int* in_sizes, int n_in,
                              void* d_out, int out_size, void* d_ws, size_t ws_size,
                              hipStream_t stream) {
  (void)in_sizes; (void)n_in; (void)out_size; (void)ws_size;
  const float* q_embed  = (const float*)d_in[0];
  const float* qa_embed = (const float*)d_in[1];
  const float* Wq  = (const float*)d_in[2];
  const float* bq  = (const float*)d_in[3];
  const float* Wv  = (const float*)d_in[4];
  const float* bv  = (const float*)d_in[5];
  const float* Wg  = (const float*)d_in[6];
  const float* Wo  = (const float*)d_in[7];
  const float* bo  = (const float*)d_in[8];
  const float* ln1g = (const float*)d_in[9];
  const float* ln1b = (const float*)d_in[10];
  const float* W1  = (const float*)d_in[11];
  const float* b1  = (const float*)d_in[12];
  const float* W2  = (const float*)d_in[13];
  const float* b2  = (const float*)d_in[14];
  const float* ln2g = (const float*)d_in[15];
  const float* ln2b = (const float*)d_in[16];

  char* p = (char*)d_ws;
  auto alloc = [&](size_t bytes) -> char* {
    char* r = p; p += (bytes + 255) & ~(size_t)255; return r;
  };
  const size_t WDE = (size_t)NL * DM * DM;   // stacked weight elems (per tensor)
  const size_t AE  = (size_t)MROWS * DM;     // activation elems
  bf16_t* wall_b = (bf16_t*)alloc(5 * WDE * 2);   // wq|wv|wo|w1|w2 contiguous
  bf16_t* wq_b = wall_b;
  bf16_t* wv_b = wall_b + WDE;
  bf16_t* wo_b = wall_b + 2 * WDE;
  bf16_t* w1_b = wall_b + 3 * WDE;
  bf16_t* w2_b = wall_b + 4 * WDE;
  bf16_t* y_b   = (bf16_t*)alloc(AE * 2);
  bf16_t* x_b   = (bf16_t*)alloc(AE * 2);
  bf16_t* qv_b  = (bf16_t*)alloc((size_t)MROWS * QVLD * 2);  // q|v merged
  bf16_t* ctx_b = (bf16_t*)alloc(AE * 2);
  bf16_t* x1_b  = (bf16_t*)alloc(AE * 2);
  bf16_t* tmp_b = (bf16_t*)alloc(AE * 2);
  bf16_t* ffn1_b = (bf16_t*)alloc(AE * 2);
  float* stats = (float*)alloc(NL * (12 + BSZ * 6) * 4);  // fP[NL][12] | rdyn[NL][32][6]
  float* fPbase = stats;
  float* rdynbase = stats + NL * 12;

  hipMemsetAsync(stats, 0, NL * (12 + BSZ * 6) * 4, stream);

  f2bw_kernel<<<dim3((unsigned)(WDE / 4 / 256), 5), 256, 0, stream>>>(
      Wq, Wv, Wo, W1, W2, wall_b);
  f2b2_kernel<<<dim3((unsigned)(AE / 4 / 256), 2), 256, 0, stream>>>(
      qa_embed, q_embed, y_b, x_b);

  const size_t DD = (size_t)DM * DM;
  dim3 gqv(4, 128), gn5(2, 128), gfa(256, 4);
  float* outx = (float*)d_out;

  auto layer = [&](int i, bf16_t* resb, const bf16_t* xvb, int strict, bool last) {
    float* fP = fPbase + i * 12;
    float* rdyn = rdynbase + i * (BSZ * 6);
    gemm8<4, 512, false><<<gqv, 512, 0, stream>>>(
        resb, xvb, wq_b + i * DD, wv_b + i * DD, bq + i * DM, bv + i * DM, qv_b, QVLD);
    gates_kernel<<<MROWS / 32, 256, 0, stream>>>(qv_b, Wg + (size_t)i * HD_ * DM, rdyn, fP);
    fattn_kernel<<<gfa, 256, 0, stream>>>(qv_b, rdyn, ctx_b, strict);
    gemm8<2, 256, false><<<gn5, 512, 0, stream>>>(
        ctx_b, ctx_b, wo_b + i * DD, wo_b + i * DD, bo + i * DM, bo + i * DM, tmp_b, DM);
    add_ln_kernel<0><<<MROWS / 4, 256, 0, stream>>>(
        resb, tmp_b, ln1g + i * DM, ln1b + i * DM, x1_b, nullptr);
    gemm8<2, 256, true><<<gn5, 512, 0, stream>>>(
        x1_b, x1_b, w1_b + i * DD, w1_b + i * DD, b1 + i * DM, b1 + i * DM, ffn1_b, DM);
    gemm8<2, 256, false><<<gn5, 512, 0, stream>>>(
        ffn1_b, ffn1_b, w2_b + i * DD, w2_b + i * DD, b2 + i * DM, b2 + i * DM, tmp_b, DM);
    if (last)
      add_ln_kernel<1><<<MROWS / 4, 256, 0, stream>>>(
          x1_b, tmp_b, ln2g + i * DM, ln2b + i * DM, nullptr, outx);
    else
      add_ln_kernel<0><<<MROWS / 4, 256, 0, stream>>>(
          x1_b, tmp_b, ln2g + i * DM, ln2b + i * DM, resb, nullptr);
  };

  layer(0, y_b, y_b, 0, false);
  layer(1, y_b, y_b, 0, false);
  layer(2, x_b, x_b, 0, false);
  layer(3, x_b, y_b, 1, false);
  layer(4, x_b, x_b, 0, false);
  layer(5, x_b, y_b, 1, true);
  balance_kernel<<<1, 64, 0, stream>>>(fPbase + 5 * 12, outx + (size_t)MROWS * DM);
}

// Round 11
// 887.687 us; speedup vs baseline: 11.4405x; 1.0137x over previous
//
#include <hip/hip_runtime.h>
#include <cstdint>

// ---------------- constants ----------------
#define BSZ 32
#define SEQ 512
#define DM  512
#define NH  8
#define DK  64
#define HS_ 2
#define HD_ 6
#define NL  6
#define MROWS (BSZ*SEQ)          // 16384
#define QVLD 1024                // row stride of merged q|v buffer
#define SCL 0.18033688011112043f // 0.125 * log2(e)  (exp2 domain)

typedef unsigned short bf16_t;
typedef __attribute__((ext_vector_type(4))) float f32x4;
typedef __attribute__((ext_vector_type(8))) short bf16x8;
typedef __attribute__((ext_vector_type(8))) unsigned short u16x8;

#define DEV static __device__ __forceinline__

DEV float bf2f(bf16_t b) {
  unsigned int u = ((unsigned int)b) << 16;
  float f; __builtin_memcpy(&f, &u, 4); return f;
}
DEV bf16_t f2b(float f) {  // RNE bf16 (finite inputs)
  unsigned int u; __builtin_memcpy(&u, &f, 4);
  unsigned int r = (u + 0x7fffu + ((u >> 16) & 1u)) >> 16;
  return (bf16_t)r;
}
DEV void unp2(unsigned int w, float& a, float& b) {
  unsigned int ua = w << 16, ub = w & 0xffff0000u;
  __builtin_memcpy(&a, &ua, 4); __builtin_memcpy(&b, &ub, 4);
}
DEV unsigned cvtpk(float lo, float hi) {
  unsigned r;
  asm("v_cvt_pk_bf16_f32 %0, %1, %2" : "=v"(r) : "v"(lo), "v"(hi));
  return r;
}

DEV void gload_lds16(const bf16_t* g, bf16_t* l) {
  __builtin_amdgcn_global_load_lds(
      (const __attribute__((address_space(1))) void*)g,
      (__attribute__((address_space(3))) void*)l, 16, 0, 0);
}

// scale a bf16x8 Q fragment by SCL (exp2-domain pre-scale)
DEV bf16x8 scale_q(bf16x8 v) {
  u16x8 u;
  __builtin_memcpy(&u, &v, 16);
  unsigned w[4];
#pragma unroll
  for (int e = 0; e < 4; ++e)
    w[e] = cvtpk(bf2f(u[2 * e]) * SCL, bf2f(u[2 * e + 1]) * SCL);
  bf16x8 r;
  __builtin_memcpy(&r, w, 16);
  return r;
}

// ---------------- f32 -> bf16 converts ----------------
__global__ __launch_bounds__(256) void f2b2_kernel(
    const float* __restrict__ s0, const float* __restrict__ s1,
    bf16_t* __restrict__ d0, bf16_t* __restrict__ d1) {
  const float* s = blockIdx.y ? s1 : s0;
  bf16_t* d = blockIdx.y ? d1 : d0;
  const int i = blockIdx.x * 256 + threadIdx.x;
  float4 v = reinterpret_cast<const float4*>(s)[i];
  ushort4 o;
  o.x = f2b(v.x); o.y = f2b(v.y); o.z = f2b(v.z); o.w = f2b(v.w);
  reinterpret_cast<ushort4*>(d)[i] = o;
}

__global__ __launch_bounds__(256) void f2bw_kernel(
    const float* __restrict__ s0, const float* __restrict__ s1,
    const float* __restrict__ s2, const float* __restrict__ s3,
    const float* __restrict__ s4, bf16_t* __restrict__ dst) {
  const float* srcs[5] = {s0, s1, s2, s3, s4};
  const float* s = srcs[blockIdx.y];
  bf16_t* d = dst + (size_t)blockIdx.y * ((size_t)NL * DM * DM);
  const int i = blockIdx.x * 256 + threadIdx.x;
  float4 v = reinterpret_cast<const float4*>(s)[i];
  ushort4 o;
  o.x = f2b(v.x); o.y = f2b(v.y); o.z = f2b(v.z); o.w = f2b(v.w);
  reinterpret_cast<ushort4*>(d)[i] = o;
}

// ---------------- deep-pipelined MFMA GEMM (128x256 tile, BK=64) ----------------
// 512 thr, 8 waves (2M x 4N). 3 LDS buffers, counted vmcnt(6). See R10 notes.
template <int NB, int NWG, bool RELU>
__global__ __launch_bounds__(512) void gemm8(
    const bf16_t* __restrict__ A0, const bf16_t* __restrict__ A1,
    const bf16_t* __restrict__ W0, const bf16_t* __restrict__ W1,
    const float* __restrict__ b0, const float* __restrict__ b1,
    bf16_t* __restrict__ Yb, int ldy) {
  const int K = 512;
  const int lin = blockIdx.y * NB + blockIdx.x;
  const int cpx = NWG / 8;
  const int swz = (lin & 7) * cpx + (lin >> 3);
  const int bn = swz % NB, bm = swz / NB;
  const int tid = threadIdx.x, wid = tid >> 6, lane = tid & 63;
  const int wr = wid >> 2, wc = wid & 3;        // 2M x 4N waves
  const int lrow = lane & 15, grp = lane >> 4;
  const int l3 = lane >> 3, c3 = lane & 7;

  __shared__ __align__(16) bf16_t Lds[3][24576]; // per buf: A[128][64] | B[256][64]

  const bool hi = (bn * 256) >= 512;
  const bf16_t* Asel = hi ? A1 : A0;
  const bf16_t* Wsel = hi ? (W1 - (size_t)512 * K) : W0;
  const float* bsel = hi ? (b1 - 512) : b0;

  f32x4 acc[4][4];
#pragma unroll
  for (int m = 0; m < 4; ++m)
#pragma unroll
    for (int n = 0; n < 4; ++n) acc[m][n] = f32x4{0.f, 0.f, 0.f, 0.f};

  const char* LB = (const char*)Lds;

  auto stage3 = [&](int kt, int buf, int half) {
#pragma unroll
    for (int cc = 0; cc < 3; ++cc) {
      const int c = wid + (half * 3 + cc) * 8;    // 0..47
      const int colb = ((c3 ^ l3) * 8);           // pre-swizzled 16B col
      if (c < 16) {
        gload_lds16(Asel + (size_t)(bm * 128 + c * 8 + l3) * K + kt * 64 + colb,
                    &Lds[buf][c * 512]);
      } else {
        const int cb = c - 16;
        gload_lds16(Wsel + (size_t)(bn * 256 + cb * 8 + l3) * K + kt * 64 + colb,
                    &Lds[buf][8192 + cb * 512]);
      }
    }
  };
  auto rdA = [&](int buf, int rA, int ks) -> bf16x8 {
    const int off = buf * 49152 + rA * 128 + ((ks * 64 + grp * 16) ^ ((rA & 7) << 4));
    return *reinterpret_cast<const bf16x8*>(LB + off);
  };
  auto rdB = [&](int buf, int rB, int ks) -> bf16x8 {
    const int off = buf * 49152 + 16384 + rB * 128 + ((ks * 64 + grp * 16) ^ ((rB & 7) << 4));
    return *reinterpret_cast<const bf16x8*>(LB + off);
  };

  stage3(0, 0, 0); stage3(0, 0, 1);
  stage3(1, 1, 0); stage3(1, 1, 1);
  asm volatile("s_waitcnt vmcnt(6)" ::: "memory");
  __builtin_amdgcn_s_barrier();

  for (int g = 0; g < 8; ++g) {
    const int bufR = g % 3, bufW = (g + 2) % 3;
    const bool st = g < 6;
    bf16x8 bwv[4][2], afv[2][2];
#pragma unroll
    for (int n = 0; n < 4; ++n)
#pragma unroll
      for (int ks = 0; ks < 2; ++ks)
        bwv[n][ks] = rdB(bufR, wc * 64 + n * 16 + lrow, ks);
#pragma unroll
    for (int m = 0; m < 2; ++m)
#pragma unroll
      for (int ks = 0; ks < 2; ++ks)
        afv[m][ks] = rdA(bufR, wr * 64 + m * 16 + lrow, ks);
    if (st) stage3(g + 2, bufW, 0);
    __builtin_amdgcn_s_barrier();
    asm volatile("s_waitcnt lgkmcnt(0)" ::: "memory");
    __builtin_amdgcn_s_setprio(1);
#pragma unroll
    for (int ks = 0; ks < 2; ++ks)
#pragma unroll
      for (int m = 0; m < 2; ++m)
#pragma unroll
        for (int n = 0; n < 4; ++n)
          acc[m][n] = __builtin_amdgcn_mfma_f32_16x16x32_bf16(afv[m][ks], bwv[n][ks], acc[m][n], 0, 0, 0);
    __builtin_amdgcn_s_setprio(0);
    __builtin_amdgcn_s_barrier();
#pragma unroll
    for (int m = 0; m < 2; ++m)
#pragma unroll
      for (int ks = 0; ks < 2; ++ks)
        afv[m][ks] = rdA(bufR, wr * 64 + 32 + m * 16 + lrow, ks);
    if (st) stage3(g + 2, bufW, 1);
    __builtin_amdgcn_s_barrier();
    asm volatile("s_waitcnt lgkmcnt(0)" ::: "memory");
    __builtin_amdgcn_s_setprio(1);
#pragma unroll
    for (int ks = 0; ks < 2; ++ks)
#pragma unroll
      for (int m = 0; m < 2; ++m)
#pragma unroll
        for (int n = 0; n < 4; ++n)
          acc[2 + m][n] = __builtin_amdgcn_mfma_f32_16x16x32_bf16(afv[m][ks], bwv[n][ks], acc[2 + m][n], 0, 0, 0);
    __builtin_amdgcn_s_setprio(0);
    if (g < 6) {
      asm volatile("s_waitcnt vmcnt(6)" ::: "memory");
    } else if (g == 6) {
      asm volatile("s_waitcnt vmcnt(0)" ::: "memory");
    }
    __builtin_amdgcn_s_barrier();
  }

  const int r0 = bm * 128 + wr * 64 + grp * 4;
  const int c0 = bn * 256 + wc * 64 + lrow;
#pragma unroll
  for (int n = 0; n < 4; ++n) {
    const int col = c0 + n * 16;
    const float bc = bsel[col];
#pragma unroll
    for (int qm = 0; qm < 4; ++qm)
#pragma unroll
      for (int j = 0; j < 4; ++j) {
        float v = acc[qm][n][j] + bc;
        if (RELU) v = fmaxf(v, 0.f);
        Yb[(size_t)(r0 + qm * 16 + j) * ldy + col] = f2b(v);
      }
  }
}

// ---------------- fused GEMM + bias + residual + LayerNorm (64x512 tile) ------
// Out = LN(A @ W^T + bias + Res). 512 thr, 8 waves each owning a 64-col slice;
// block owns 64 FULL rows -> LN stats computed locally (f32 throughout).
// 2 LDS buffers (A 8KB + W 64KB each), m97-style stage(g+1)-during-compute(g).
// OUT=0: bf16 out; OUT=1: f32 out (final layer).
template <int OUT>
__global__ __launch_bounds__(512) void gemm_ln(
    const bf16_t* __restrict__ A, const bf16_t* __restrict__ W,
    const float* __restrict__ bias, const bf16_t* __restrict__ Res,
    const float* __restrict__ gam, const float* __restrict__ bet,
    bf16_t* __restrict__ outb, float* __restrict__ outf) {
  const int K = 512;
  const int bm = blockIdx.x;
  const int tid = threadIdx.x, wid = tid >> 6, lane = tid & 63;
  const int lrow = lane & 15, grp = lane >> 4;
  const int l3 = lane >> 3, c3 = lane & 7;

  __shared__ __align__(16) bf16_t Lds[2][36864];  // per buf: A[64][64] | W[512][64]
  __shared__ float red_s[64][8], red_q[64][8], stat[64][2];

  f32x4 acc[4][4];
#pragma unroll
  for (int m = 0; m < 4; ++m)
#pragma unroll
    for (int n = 0; n < 4; ++n) acc[m][n] = f32x4{0.f, 0.f, 0.f, 0.f};

  const char* LB = (const char*)Lds;

  auto stage = [&](int kt, int buf) {
#pragma unroll
    for (int k = 0; k < 9; ++k) {
      const int c = wid + k * 8;           // 0..71
      const int colb = (c3 ^ l3) * 8;      // pre-swizzled 16B col
      if (c < 8) {                         // A chunk: rows c*8..c*8+7
        gload_lds16(A + (size_t)(bm * 64 + c * 8 + l3) * K + kt * 64 + colb,
                    &Lds[buf][c * 512]);
      } else {                             // W chunk
        const int cb = c - 8;
        gload_lds16(W + (size_t)(cb * 8 + l3) * K + kt * 64 + colb,
                    &Lds[buf][4096 + cb * 512]);
      }
    }
  };
  auto rdA = [&](int buf, int r, int ks) -> bf16x8 {
    const int off = buf * 73728 + r * 128 + ((ks * 64 + grp * 16) ^ ((r & 7) << 4));
    return *reinterpret_cast<const bf16x8*>(LB + off);
  };
  auto rdW = [&](int buf, int r, int ks) -> bf16x8 {
    const int off = buf * 73728 + 8192 + r * 128 + ((ks * 64 + grp * 16) ^ ((r & 7) << 4));
    return *reinterpret_cast<const bf16x8*>(LB + off);
  };

  stage(0, 0);
  __syncthreads();
  for (int g = 0; g < 8; ++g) {
    const int bufR = g & 1;
    if (g < 7) stage(g + 1, bufR ^ 1);
    bf16x8 af[4][2], wf[4][2];
#pragma unroll
    for (int m = 0; m < 4; ++m)
#pragma unroll
      for (int ks = 0; ks < 2; ++ks)
        af[m][ks] = rdA(bufR, m * 16 + lrow, ks);
#pragma unroll
    for (int n = 0; n < 4; ++n)
#pragma unroll
      for (int ks = 0; ks < 2; ++ks)
        wf[n][ks] = rdW(bufR, wid * 64 + n * 16 + lrow, ks);
    __builtin_amdgcn_s_setprio(1);
#pragma unroll
    for (int ks = 0; ks < 2; ++ks)
#pragma unroll
      for (int m = 0; m < 4; ++m)
#pragma unroll
        for (int n = 0; n < 4; ++n)
          acc[m][n] = __builtin_amdgcn_mfma_f32_16x16x32_bf16(af[m][ks], wf[n][ks], acc[m][n], 0, 0, 0);
    __builtin_amdgcn_s_setprio(0);
    __syncthreads();   // drains vmcnt (stage g+1 resident) + lgkm
  }

  // ---- epilogue: z = acc + bias + res; rowwise LN; store ----
  const int cbase = wid * 64;
  float bias_n[4], gam_n[4], bet_n[4];
#pragma unroll
  for (int n = 0; n < 4; ++n) {
    bias_n[n] = bias[cbase + n * 16 + lrow];
    gam_n[n]  = gam[cbase + n * 16 + lrow];
    bet_n[n]  = bet[cbase + n * 16 + lrow];
  }
  const size_t rowg0 = (size_t)bm * 64;
  float ps[4][4], pq[4][4];
#pragma unroll
  for (int m = 0; m < 4; ++m)
#pragma unroll
    for (int j = 0; j < 4; ++j) {
      const int r = m * 16 + grp * 4 + j;
      float s = 0.f, q = 0.f;
#pragma unroll
      for (int n = 0; n < 4; ++n) {
        float z = acc[m][n][j] + bias_n[n] +
                  bf2f(Res[(rowg0 + r) * DM + cbase + n * 16 + lrow]);
        acc[m][n][j] = z;
        s += z; q += z * z;
      }
      ps[m][j] = s; pq[m][j] = q;
    }
#pragma unroll
  for (int m = 0; m < 4; ++m)
#pragma unroll
    for (int j = 0; j < 4; ++j)
#pragma unroll
      for (int off = 1; off <= 8; off <<= 1) {
        ps[m][j] += __shfl_xor(ps[m][j], off);
        pq[m][j] += __shfl_xor(pq[m][j], off);
      }
  if (lrow == 0) {
#pragma unroll
    for (int m = 0; m < 4; ++m)
#pragma unroll
      for (int j = 0; j < 4; ++j) {
        const int r = m * 16 + grp * 4 + j;
        red_s[r][wid] = ps[m][j];
        red_q[r][wid] = pq[m][j];
      }
  }
  __syncthreads();
  if (tid < 64) {
    float s = 0.f, q = 0.f;
#pragma unroll
    for (int w = 0; w < 8; ++w) { s += red_s[tid][w]; q += red_q[tid][w]; }
    const float mean = s * (1.f / 512.f);
    const float var = q * (1.f / 512.f) - mean * mean;
    stat[tid][0] = mean;
    stat[tid][1] = rsqrtf(var + 1e-5f);
  }
  __syncthreads();
#pragma unroll
  for (int m = 0; m < 4; ++m)
#pragma unroll
    for (int j = 0; j < 4; ++j) {
      const int r = m * 16 + grp * 4 + j;
      const float mean = stat[r][0], rstd = stat[r][1];
#pragma unroll
      for (int n = 0; n < 4; ++n) {
        const float o = (acc[m][n][j] - mean) * rstd * gam_n[n] + bet_n[n];
        const size_t off = (rowg0 + r) * DM + cbase + n * 16 + lrow;
        if (OUT == 0) outb[off] = f2b(o);
        else outf[off] = o;
      }
    }
}

// ---------------- gating: softmax(q @ Wg^T), top-4-of-6, fused routing ----------------
__global__ __launch_bounds__(256) void gates_kernel(
    const bf16_t* __restrict__ qv, const float* __restrict__ Wg,
    float* __restrict__ rdyn, float* __restrict__ fP) {
  __shared__ float wg_s[HD_ * DM];
  __shared__ float blk[4][18];
  const int tid = threadIdx.x, wid = tid >> 6, lane = tid & 63;
  for (int i = tid; i < HD_ * DM / 4; i += 256)
    reinterpret_cast<float4*>(wg_s)[i] = reinterpret_cast<const float4*>(Wg)[i];
  __syncthreads();
  const int bb = blockIdx.x >> 4;
  const int t0 = (blockIdx.x & 15) * 32 + wid * 8;
  float fs[6] = {0, 0, 0, 0, 0, 0}, ps[6] = {0, 0, 0, 0, 0, 0}, rs[6] = {0, 0, 0, 0, 0, 0};
  for (int it = 0; it < 8; ++it) {
    const int tok = bb * SEQ + t0 + it;
    uint4 u = reinterpret_cast<const uint4*>(qv + (size_t)tok * QVLD)[lane];
    float x[8];
    unp2(u.x, x[0], x[1]); unp2(u.y, x[2], x[3]);
    unp2(u.z, x[4], x[5]); unp2(u.w, x[6], x[7]);
    float g[6];
#pragma unroll
    for (int j = 0; j < 6; ++j) {
      float p = 0.f;
#pragma unroll
      for (int e = 0; e < 8; ++e) p = fmaf(x[e], wg_s[j * DM + lane * 8 + e], p);
#pragma unroll
      for (int off = 32; off; off >>= 1) p += __shfl_xor(p, off);
      g[j] = p;
    }
    float mx = g[0];
#pragma unroll
    for (int j = 1; j < 6; ++j) mx = fmaxf(mx, g[j]);
    float se = 0.f;
#pragma unroll
    for (int j = 0; j < 6; ++j) { g[j] = __expf(g[j] - mx); se += g[j]; }
    float inv = 1.f / se;
#pragma unroll
    for (int j = 0; j < 6; ++j) g[j] *= inv;
    int d1 = 0;
#pragma unroll
    for (int j = 1; j < 6; ++j)
      if (g[j] < g[d1] || (g[j] == g[d1] && j > d1)) d1 = j;
    int d2 = (d1 == 0) ? 1 : 0;
#pragma unroll
    for (int j = 0; j < 6; ++j) {
      if (j == d1) continue;
      if (g[j] < g[d2] || (g[j] == g[d2] && j > d2)) d2 = j;
    }
#pragma unroll
    for (int j = 0; j < 6; ++j) {
      const bool drop = (j == d1) || (j == d2);
      fs[j] += drop ? 0.f : 1.f;
      ps[j] += g[j];
      rs[j] += drop ? 0.f : g[j];
    }
  }
  if (lane == 0) {
#pragma unroll
    for (int j = 0; j < 6; ++j) {
      blk[wid][j] = fs[j]; blk[wid][6 + j] = ps[j]; blk[wid][12 + j] = rs[j];
    }
  }
  __syncthreads();
  if (tid < 18) {
    float s = blk[0][tid] + blk[1][tid] + blk[2][tid] + blk[3][tid];
    if (tid < 12) atomicAdd(&fP[tid], s);
    else atomicAdd(&rdyn[bb * 6 + (tid - 12)], s * (1.f / 512.f));
  }
}

// ---------------- fused flash attention (MFMA, row0 fused, occupancy grid) ----
__global__ __launch_bounds__(256, 2) void fattn_kernel(
    const bf16_t* __restrict__ qv, const float* __restrict__ rdyn,
    bf16_t* __restrict__ ctx, int strict) {
  const int bh = blockIdx.x, qt = blockIdx.y;
  const int b = bh >> 3, h = bh & 7;
  const int tid = threadIdx.x, wid = tid >> 6, lane = tid & 63;
  const int c0 = lane & 15, grp = lane >> 4;
  const int l3 = lane >> 3, c3 = lane & 7;
  const int kidx = lane & 31, dhalf = lane >> 5;

  __shared__ __align__(16) bf16_t Ks[64 * 64];
  __shared__ __align__(16) bf16_t Vt[64 * 72];
  __shared__ __align__(16) bf16_t Ps[4][32 * 64];
  __shared__ float csum[64];

  const bf16_t* qp = qv;
  const bf16_t* vp = qv + 512;
  const float factor = (h < HS_) ? 1.f : rdyn[b * 6 + (h - HS_)];

  const int qbase = qt * 128 + wid * 32;

  bf16x8 qf[2][2];
#pragma unroll
  for (int nt = 0; nt < 2; ++nt)
#pragma unroll
    for (int ks = 0; ks < 2; ++ks)
      qf[nt][ks] = scale_q(*reinterpret_cast<const bf16x8*>(
          qp + ((size_t)(b * SEQ + qbase + nt * 16 + c0)) * QVLD + h * DK + ks * 32 + grp * 8));

  f32x4 acc[2][4];
#pragma unroll
  for (int m = 0; m < 2; ++m)
#pragma unroll
    for (int d = 0; d < 4; ++d) acc[m][d] = f32x4{0.f, 0.f, 0.f, 0.f};
  float mreg[2] = {-3e38f, -3e38f};
  float lreg[2] = {0.f, 0.f};
  float cs[8] = {0, 0, 0, 0, 0, 0, 0, 0};

  const int lastk = (qbase + 31 - strict) >> 6;
  const int ktmax = 2 * qt + 1;

  for (int kt = 0; kt <= ktmax; ++kt) {
#pragma unroll
    for (int i = 0; i < 2; ++i) {
      int row = i * 32 + wid * 8 + l3;
      int blk = c3 ^ l3;
      gload_lds16(qp + ((size_t)(b * SEQ + kt * 64 + row)) * QVLD + h * DK + blk * 8,
                  Ks + (i * 32 + wid * 8) * 64);
    }
#pragma unroll
    for (int j = 0; j < 2; ++j) {
      const int d0 = (wid * 2 + j) * 8 + dhalf * 4;
      const bf16_t* src = vp + ((size_t)(b * SEQ + kt * 64 + 2 * kidx)) * QVLD + h * DK + d0;
      ushort4 lo = *reinterpret_cast<const ushort4*>(src);
      ushort4 hv = *reinterpret_cast<const ushort4*>(src + QVLD);
      *reinterpret_cast<unsigned*>(&Vt[(d0 + 0) * 72 + 2 * kidx]) = (unsigned)lo.x | ((unsigned)hv.x << 16);
      *reinterpret_cast<unsigned*>(&Vt[(d0 + 1) * 72 + 2 * kidx]) = (unsigned)lo.y | ((unsigned)hv.y << 16);
      *reinterpret_cast<unsigned*>(&Vt[(d0 + 2) * 72 + 2 * kidx]) = (unsigned)lo.z | ((unsigned)hv.z << 16);
      *reinterpret_cast<unsigned*>(&Vt[(d0 + 3) * 72 + 2 * kidx]) = (unsigned)lo.w | ((unsigned)hv.w << 16);
      if (qt == 3) {
        cs[j * 4 + 0] += bf2f(lo.x) + bf2f(hv.x);
        cs[j * 4 + 1] += bf2f(lo.y) + bf2f(hv.y);
        cs[j * 4 + 2] += bf2f(lo.z) + bf2f(hv.z);
        cs[j * 4 + 3] += bf2f(lo.w) + bf2f(hv.w);
      }
    }
    __syncthreads();

    if (kt <= lastk) {
      const char* KsB = (const char*)Ks;
      bf16x8 kf[4][2];
#pragma unroll
      for (int mt = 0; mt < 4; ++mt)
#pragma unroll
        for (int ks = 0; ks < 2; ++ks)
          kf[mt][ks] = *reinterpret_cast<const bf16x8*>(
              KsB + (mt * 16 + c0) * 128 + 16 * ((4 * ks + grp) ^ (c0 & 7)));
      f32x4 s[4][2];
#pragma unroll
      for (int mt = 0; mt < 4; ++mt)
#pragma unroll
        for (int nt = 0; nt < 2; ++nt) s[mt][nt] = f32x4{0.f, 0.f, 0.f, 0.f};
      __builtin_amdgcn_s_setprio(1);
#pragma unroll
      for (int mt = 0; mt < 4; ++mt)
#pragma unroll
        for (int nt = 0; nt < 2; ++nt)
#pragma unroll
          for (int ks = 0; ks < 2; ++ks)
            s[mt][nt] = __builtin_amdgcn_mfma_f32_16x16x32_bf16(
                kf[mt][ks], qf[nt][ks], s[mt][nt], 0, 0, 0);
      __builtin_amdgcn_s_setprio(0);

      const bool masked = (kt == lastk);
      if (masked) {
#pragma unroll
        for (int nt = 0; nt < 2; ++nt) {
          const int q = qbase + nt * 16 + c0;
#pragma unroll
          for (int mt = 0; mt < 4; ++mt)
#pragma unroll
            for (int j = 0; j < 4; ++j) {
              int k = kt * 64 + mt * 16 + grp * 4 + j;
              if (k + strict > q) s[mt][nt][j] = -1e30f;
            }
        }
      }
      float mx[2];
#pragma unroll
      for (int nt = 0; nt < 2; ++nt) {
        float a = fmaxf(s[0][nt][0], s[0][nt][1]);
        a = fmaxf(fmaxf(a, s[0][nt][2]), s[0][nt][3]);
        float bm_ = fmaxf(s[1][nt][0], s[1][nt][1]);
        bm_ = fmaxf(fmaxf(bm_, s[1][nt][2]), s[1][nt][3]);
        float c = fmaxf(s[2][nt][0], s[2][nt][1]);
        c = fmaxf(fmaxf(c, s[2][nt][2]), s[2][nt][3]);
        float d = fmaxf(s[3][nt][0], s[3][nt][1]);
        d = fmaxf(fmaxf(d, s[3][nt][2]), s[3][nt][3]);
        float m_ = fmaxf(fmaxf(a, bm_), fmaxf(c, d));
        m_ = fmaxf(m_, __shfl_xor(m_, 16));
        m_ = fmaxf(m_, __shfl_xor(m_, 32));
        mx[nt] = m_;
      }
      const bool defer = __all((mx[0] - mreg[0] <= 8.f) && (mx[1] - mreg[1] <= 8.f));
      float sc[2];
#pragma unroll
      for (int nt = 0; nt < 2; ++nt) {
        const float mnew = defer ? mreg[nt] : fmaxf(mreg[nt], mx[nt]);
        float ts = 0.f;
#pragma unroll
        for (int mt = 0; mt < 4; ++mt)
#pragma unroll
          for (int j = 0; j < 4; ++j) {
            float pp = exp2f(s[mt][nt][j] - mnew);
            s[mt][nt][j] = pp; ts += pp;
          }
        ts += __shfl_xor(ts, 16);
        ts += __shfl_xor(ts, 32);
        if (defer) {
          lreg[nt] += ts;
        } else {
          sc[nt] = exp2f(mreg[nt] - mnew);
          lreg[nt] = lreg[nt] * sc[nt] + ts;
          mreg[nt] = mnew;
        }
      }
      char* PsB = (char*)(&Ps[wid][0]);
#pragma unroll
      for (int nt = 0; nt < 2; ++nt)
#pragma unroll
        for (int mt = 0; mt < 4; ++mt) {
          uint2 w;
          w.x = cvtpk(s[mt][nt][0], s[mt][nt][1]);
          w.y = cvtpk(s[mt][nt][2], s[mt][nt][3]);
          int row = nt * 16 + c0;
          int off = (row * 128 + mt * 32 + grp * 8) ^ ((c0 & 7) << 4);
          *reinterpret_cast<uint2*>(PsB + off) = w;
        }
      if (!defer) {
#pragma unroll
        for (int mtq = 0; mtq < 2; ++mtq) {
          f32x4 sv;
#pragma unroll
          for (int j = 0; j < 4; ++j) sv[j] = __shfl(sc[mtq], grp * 4 + j);
#pragma unroll
          for (int dt = 0; dt < 4; ++dt) acc[mtq][dt] *= sv;
        }
      }
      bf16x8 pf[2][2], vf2[4][2];
#pragma unroll
      for (int mtq = 0; mtq < 2; ++mtq)
#pragma unroll
        for (int ks = 0; ks < 2; ++ks)
          pf[mtq][ks] = *reinterpret_cast<const bf16x8*>(
              PsB + (mtq * 16 + c0) * 128 + 16 * ((4 * ks + grp) ^ (c0 & 7)));
#pragma unroll
      for (int dt = 0; dt < 4; ++dt)
#pragma unroll
        for (int ks = 0; ks < 2; ++ks)
          vf2[dt][ks] = *reinterpret_cast<const bf16x8*>(
              (const char*)Vt + (dt * 16 + c0) * 144 + ks * 64 + grp * 16);
      __builtin_amdgcn_s_setprio(1);
#pragma unroll
      for (int mtq = 0; mtq < 2; ++mtq)
#pragma unroll
        for (int dt = 0; dt < 4; ++dt)
#pragma unroll
          for (int ks = 0; ks < 2; ++ks)
            acc[mtq][dt] = __builtin_amdgcn_mfma_f32_16x16x32_bf16(
                pf[mtq][ks], vf2[dt][ks], acc[mtq][dt], 0, 0, 0);
      __builtin_amdgcn_s_setprio(0);
    }
    __syncthreads();
  }

  if (qt == 3) {
#pragma unroll
    for (int e = 0; e < 8; ++e)
#pragma unroll
      for (int off = 1; off <= 16; off <<= 1) cs[e] += __shfl_xor(cs[e], off);
    if ((lane & 31) == 0) {
#pragma unroll
      for (int e = 0; e < 8; ++e)
        csum[(wid * 2 + (e >> 2)) * 8 + dhalf * 4 + (e & 3)] = cs[e];
    }
    __syncthreads();
    if (tid < 64)
      ctx[((size_t)(b * SEQ)) * DM + h * DK + tid] = f2b(csum[tid] * (1.f / 512.f) * factor);
  }

#pragma unroll
  for (int mtq = 0; mtq < 2; ++mtq) {
    const float inv = factor / lreg[mtq];
    f32x4 iv;
#pragma unroll
    for (int j = 0; j < 4; ++j) iv[j] = __shfl(inv, grp * 4 + j);
#pragma unroll
    for (int j = 0; j < 4; ++j) {
      const int q = qbase + mtq * 16 + grp * 4 + j;
      if (q == 0) continue;
#pragma unroll
      for (int dt = 0; dt < 4; ++dt)
        ctx[((size_t)(b * SEQ + q)) * DM + h * DK + dt * 16 + c0] =
            f2b(acc[mtq][dt][j] * iv[j]);
    }
  }
}

// ---------------- balance ----------------
__global__ void balance_kernel(const float* __restrict__ fP, float* __restrict__ out) {
  if (threadIdx.x == 0 && blockIdx.x == 0) {
    float fs = 0.f, pssum = 0.f, P[6];
    for (int j = 0; j < 6; ++j) {
      fs += fP[j];
      P[j] = fP[6 + j] * (1.f / (float)MROWS);
      pssum += P[j];
    }
    float bal = 0.f;
    for (int j = 0; j < 6; ++j)
      bal += (fP[j] / (fs + 1e-5f)) * (P[j] / (pssum + 1e-5f));
    out[0] = bal;
  }
}

// ---------------- host ----------------
extern "C" void kernel_launch(void* const* d_in, const int* in_sizes, int n_in,
                              void* d_out, int out_size, void* d_ws, size_t ws_size,
                              hipStream_t stream) {
  (void)in_sizes; (void)n_in; (void)out_size; (void)ws_size;
  const float* q_embed  = (const float*)d_in[0];
  const float* qa_embed = (const float*)d_in[1];
  const float* Wq  = (const float*)d_in[2];
  const float* bq  = (const float*)d_in[3];
  const float* Wv  = (const float*)d_in[4];
  const float* bv  = (const float*)d_in[5];
  const float* Wg  = (const float*)d_in[6];
  const float* Wo  = (const float*)d_in[7];
  const float* bo  = (const float*)d_in[8];
  const float* ln1g = (const float*)d_in[9];
  const float* ln1b = (const float*)d_in[10];
  const float* W1  = (const float*)d_in[11];
  const float* b1  = (const float*)d_in[12];
  const float* W2  = (const float*)d_in[13];
  const float* b2  = (const float*)d_in[14];
  const float* ln2g = (const float*)d_in[15];
  const float* ln2b = (const float*)d_in[16];

  char* p = (char*)d_ws;
  auto alloc = [&](size_t bytes) -> char* {
    char* r = p; p += (bytes + 255) & ~(size_t)255; return r;
  };
  const size_t WDE = (size_t)NL * DM * DM;   // stacked weight elems (per tensor)
  const size_t AE  = (size_t)MROWS * DM;     // activation elems
  bf16_t* wall_b = (bf16_t*)alloc(5 * WDE * 2);   // wq|wv|wo|w1|w2 contiguous
  bf16_t* wq_b = wall_b;
  bf16_t* wv_b = wall_b + WDE;
  bf16_t* wo_b = wall_b + 2 * WDE;
  bf16_t* w1_b = wall_b + 3 * WDE;
  bf16_t* w2_b = wall_b + 4 * WDE;
  bf16_t* y_b   = (bf16_t*)alloc(AE * 2);
  bf16_t* x_b   = (bf16_t*)alloc(AE * 2);
  bf16_t* qv_b  = (bf16_t*)alloc((size_t)MROWS * QVLD * 2);  // q|v merged
  bf16_t* ctx_b = (bf16_t*)alloc(AE * 2);
  bf16_t* x1_b  = (bf16_t*)alloc(AE * 2);
  bf16_t* ffn1_b = (bf16_t*)alloc(AE * 2);
  float* stats = (float*)alloc(NL * (12 + BSZ * 6) * 4);  // fP[NL][12] | rdyn[NL][32][6]
  float* fPbase = stats;
  float* rdynbase = stats + NL * 12;

  hipMemsetAsync(stats, 0, NL * (12 + BSZ * 6) * 4, stream);

  f2bw_kernel<<<dim3((unsigned)(WDE / 4 / 256), 5), 256, 0, stream>>>(
      Wq, Wv, Wo, W1, W2, wall_b);
  f2b2_kernel<<<dim3((unsigned)(AE / 4 / 256), 2), 256, 0, stream>>>(
      qa_embed, q_embed, y_b, x_b);

  const size_t DD = (size_t)DM * DM;
  dim3 gqv(4, 128), gn5(2, 128), gfa(256, 4), gln(256);
  float* outx = (float*)d_out;

  auto layer = [&](int i, bf16_t* resb, const bf16_t* xvb, int strict, bool last) {
    float* fP = fPbase + i * 12;
    float* rdyn = rdynbase + i * (BSZ * 6);
    gemm8<4, 512, false><<<gqv, 512, 0, stream>>>(
        resb, xvb, wq_b + i * DD, wv_b + i * DD, bq + i * DM, bv + i * DM, qv_b, QVLD);
    gates_kernel<<<MROWS / 32, 256, 0, stream>>>(qv_b, Wg + (size_t)i * HD_ * DM, rdyn, fP);
    fattn_kernel<<<gfa, 256, 0, stream>>>(qv_b, rdyn, ctx_b, strict);
    // attn-out projection + residual + LN1 fused
    gemm_ln<0><<<gln, 512, 0, stream>>>(
        ctx_b, wo_b + i * DD, bo + i * DM, resb, ln1g + i * DM, ln1b + i * DM,
        x1_b, nullptr);
    gemm8<2, 256, true><<<gn5, 512, 0, stream>>>(
        x1_b, x1_b, w1_b + i * DD, w1_b + i * DD, b1 + i * DM, b1 + i * DM, ffn1_b, DM);
    // FFN2 + residual + LN2 fused
    if (last)
      gemm_ln<1><<<gln, 512, 0, stream>>>(
          ffn1_b, w2_b + i * DD, b2 + i * DM, x1_b, ln2g + i * DM, ln2b + i * DM,
          nullptr, outx);
    else
      gemm_ln<0><<<gln, 512, 0, stream>>>(
          ffn1_b, w2_b + i * DD, b2 + i * DM, x1_b, ln2g + i * DM, ln2b + i * DM,
          resb, nullptr);
  };

  layer(0, y_b, y_b, 0, false);
  layer(1, y_b, y_b, 0, false);
  layer(2, x_b, x_b, 0, false);
  layer(3, x_b, y_b, 1, false);
  layer(4, x_b, x_b, 0, false);
  layer(5, x_b, y_b, 1, true);
  balance_kernel<<<1, 64, 0, stream>>>(fPbase + 5 * 12, outx + (size_t)MROWS * DM);
}